// Round 7
// baseline (2773.498 us; speedup 1.0000x reference)
//
#include <hip/hip_runtime.h>
#include <math.h>

#define SRF 16000.0f
#define HOP 256
#define FRM 626
#define BB 8
#define TLEN 160000
#define NFRM (BB*FRM)
#define NCONV 262144
#define ACCLEN 161024

// ---------------- workspace layout (float offsets) ----------------
constexpr size_t oWIN   = 0;                       // 1024
constexpr size_t oTW    = oWIN + 1024;             // 1024 (512 complex, angle -2pi r/1024)
constexpr size_t oDIAG  = oTW + 1024;              // 16 (unused)
constexpr size_t oTWF   = oDIAG + 16;              // 1024 (512 complex, angle -2pi r/262144)
constexpr size_t oTWC   = oTWF + 1024;             // 1024 (512 complex, angle -2pi r/512)
constexpr size_t oAW    = oTWC + 1024;             // 513
constexpr size_t oMELFB = oAW + 513;               // 41040
constexpr size_t oWSQI  = oMELFB + 513*80;         // 161024
constexpr size_t oWIHT  = oWSQI + ACCLEN;          // 61440
constexpr size_t oW0T   = oWIHT + 80*768;          // 10752
constexpr size_t oW1T   = oW0T + 21*512;           // 262144
constexpr size_t oW2T   = oW1T + 512*512;          // 262144
constexpr size_t oVTT   = oW2T + 512*512;          // 33280
constexpr size_t oNFT   = oVTT + 512*65;           // 33280
constexpr size_t oF0    = oNFT + 512*65;           // 5008
constexpr size_t oLOUD  = oF0 + NFRM;              // 5008
constexpr size_t oOQ    = oLOUD + NFRM;            // 5008
constexpr size_t oVT    = oOQ + NFRM;              // 325520
constexpr size_t oNF    = oVT + (size_t)NFRM*65;   // 325520
constexpr size_t oGLOT  = oNF + (size_t)NFRM*65;   // 1280000
constexpr size_t oNOISE = oGLOT + (size_t)BB*TLEN; // 1280000
constexpr size_t oACC   = oNOISE + (size_t)BB*TLEN;// 1288192
constexpr size_t oCONVA = oACC + (size_t)BB*ACCLEN;// 4718592
constexpr size_t oEND   = oCONVA + (size_t)9*NCONV*2;
constexpr size_t oXP    = oEND;                    // NFRM*768 dedicated (no overlay) -> 55.8 MB total
constexpr size_t oEND2  = oXP + (size_t)NFRM*768;
// overlays (lifetime-checked):
constexpr size_t oCONVB = oWSQI;                      // conv scratch; WSQI..ACC dead at conv time
constexpr size_t oMEL = oCONVA;                       // dead before k_dry packs CONVA
constexpr size_t oHS  = oMEL + (size_t)NFRM*80;       // ends 7066673 < ir slot 9578289

// init task counts
constexpr long R_WIN=1024, R_TW=512, R_TWF=512, R_TWC=512, R_AW=513, R_MELFB=41040,
  R_WSQI=161024, R_WIHT=61440, R_W0T=10752, R_W1T=262144, R_W2T=262144,
  R_VTT=33280, R_NFT=33280, R_IR=NCONV;
constexpr long INIT_TOTAL = R_WIN+R_TW+R_TWF+R_TWC+R_AW+R_MELFB+R_WSQI+R_WIHT+R_W0T+
  R_W1T+R_W2T+R_VTT+R_NFT+R_IR;

// mega-kernel block roles
constexpr int NOISEB = 313;   // 313*4096 >= 1,280,000
constexpr int ZACCB  = 315;   // 315*4096 >= 1,288,192
constexpr int MEGA_BLOCKS = 1 + NFRM + NOISEB + ZACCB;

typedef float f32x4 __attribute__((ext_vector_type(4)));
typedef __bf16 bf16x8 __attribute__((ext_vector_type(8)));
typedef short short8 __attribute__((ext_vector_type(8)));
#define MFMA_BF16 __builtin_amdgcn_mfma_f32_16x16x32_bf16

// raw barrier: LDS-only protection (no vmcnt drain — global loads/stores keep flying)
#define LDS_BARRIER() do { \
  asm volatile("s_waitcnt lgkmcnt(0)" ::: "memory"); \
  __builtin_amdgcn_sched_barrier(0); \
  __builtin_amdgcn_s_barrier(); \
  __builtin_amdgcn_sched_barrier(0); \
} while (0)

// ---------------- helpers ----------------
__device__ inline int mirror_idx(int j) {
  if (j < 0) j = -j;
  if (j >= TLEN) j = 2*TLEN - 2 - j;
  return j;
}
__device__ inline float sigm(float x) { return 1.0f/(1.0f + expf(-x)); }
__device__ inline unsigned short f2bf(float x) {
  unsigned u = __float_as_uint(x);
  return (unsigned short)((u + 0x7FFFu + ((u >> 16) & 1u)) >> 16);
}
__device__ inline float tanh_fast(float x) {
  return 1.0f - 2.0f/(__expf(2.0f*x) + 1.0f);
}

__device__ inline float interpF(const float* v, int i) {
  float pos = ((float)i + 0.5f) * (626.0f/160000.0f) - 0.5f;
  pos = fminf(fmaxf(pos, 0.0f), 625.0f);
  int lo = (int)floorf(pos);
  int hi = min(lo + 1, 625);
  float w = pos - (float)lo;
  return v[lo]*(1.0f - w) + v[hi]*w;
}
__device__ inline float interp65(const float* v, int k) {
  float pos = ((float)k + 0.5f) * (65.0f/513.0f) - 0.5f;
  pos = fminf(fmaxf(pos, 0.0f), 64.0f);
  int lo = (int)floorf(pos);
  int hi = min(lo + 1, 64);
  float w = pos - (float)lo;
  return v[lo]*(1.0f - w) + v[hi]*w;
}

// radix-2 DIT FFT in LDS on interleaved complex; input at bit-reversed positions.
template<int LOGN, int TS>
__device__ inline void fft2(float2* c, const float2* tw, int tid, int nthr, bool inv) {
  constexpr int N = 1 << LOGN;
  for (int s = 1; s <= LOGN; ++s) {
    const int half = 1 << (s-1);
    const int tstep = (N >> s) * TS;
    for (int bf = tid; bf < (N>>1); bf += nthr) {
      int jj = bf & (half-1);
      int i0 = ((bf >> (s-1)) << s) + jj;
      int i1 = i0 + half;
      float2 wv = tw[jj*tstep];
      float wi = inv ? -wv.y : wv.y;
      float2 u = c[i0], v = c[i1];
      float tr  = v.x*wv.x - v.y*wi;
      float tci = v.x*wi  + v.y*wv.x;
      c[i0] = make_float2(u.x + tr, u.y + tci);
      c[i1] = make_float2(u.x - tr, u.y - tci);
    }
    __syncthreads();
  }
}

// threefry2x32, canonical 20-round schedule
__device__ inline void threefry2x32(unsigned k0, unsigned k1, unsigned x0, unsigned x1,
                                    unsigned& o0, unsigned& o1) {
  unsigned ks2 = k0 ^ k1 ^ 0x1BD11BDAu;
  x0 += k0; x1 += k1;
#define TF_R(r) { x0 += x1; x1 = (x1<<(r)) | (x1>>(32-(r))); x1 ^= x0; }
  TF_R(13) TF_R(15) TF_R(26) TF_R(6)
  x0 += k1; x1 += ks2 + 1u;
  TF_R(17) TF_R(29) TF_R(16) TF_R(24)
  x0 += ks2; x1 += k0 + 2u;
  TF_R(13) TF_R(15) TF_R(26) TF_R(6)
  x0 += k0; x1 += k1 + 3u;
  TF_R(17) TF_R(29) TF_R(16) TF_R(24)
  x0 += k1; x1 += ks2 + 4u;
  TF_R(13) TF_R(15) TF_R(26) TF_R(6)
  x0 += ks2; x1 += k0 + 5u;
#undef TF_R
  o0 = x0; o1 = x1;
}

__device__ inline float erfinv_f(float x) { // XLA f32 ErfInv (Giles)
  float w = -log1pf(-x*x);
  float p;
  if (w < 5.0f) {
    w = w - 2.5f;
    p = 2.81022636e-08f;
    p = fmaf(p, w, 3.43273939e-07f);
    p = fmaf(p, w, -3.5233877e-06f);
    p = fmaf(p, w, -4.39150654e-06f);
    p = fmaf(p, w, 0.00021858087f);
    p = fmaf(p, w, -0.00125372503f);
    p = fmaf(p, w, -0.00417768164f);
    p = fmaf(p, w, 0.246640727f);
    p = fmaf(p, w, 1.50140941f);
  } else {
    w = sqrtf(w) - 3.0f;
    p = -0.000200214257f;
    p = fmaf(p, w, 0.000100950558f);
    p = fmaf(p, w, 0.00134934322f);
    p = fmaf(p, w, -0.00367342844f);
    p = fmaf(p, w, 0.00573950773f);
    p = fmaf(p, w, -0.0076224613f);
    p = fmaf(p, w, 0.00943887047f);
    p = fmaf(p, w, 1.00167406f);
    p = fmaf(p, w, 2.83297682f);
  }
  return p*x;
}
__device__ inline float normal_from_bits(unsigned bits) {
  float f = __uint_as_float((bits >> 9) | 0x3F800000u) - 1.0f;
  float x = fmaxf(-0.99999994f, fmaf(f, 1.99999994f, -0.99999994f));
  return 1.41421356237f * erfinv_f(x);
}

__device__ inline double mel_fpt(int j) {
  double mmax = 2595.0 * log10(1.0 + 8000.0/700.0);
  return 700.0 * (pow(10.0, (mmax * (double)j / 81.0) / 2595.0) - 1.0);
}

// ---------------- init ----------------
__global__ void k_init(float* W, const float* wih, const float* w0,
                       const float* w1, const float* w2, const float* vtw, const float* nfw,
                       const float* ir) {
  long id = (long)blockIdx.x*256 + threadIdx.x;
  if (id < R_WIN) {
    double w = 0.5 - 0.5*cos(2.0*M_PI*(double)id/1024.0);
    W[oWIN+id] = (float)w; return;
  } id -= R_WIN;
  if (id < R_TW) {
    double a = -2.0*M_PI*(double)id/1024.0;
    W[oTW+2*id] = (float)cos(a); W[oTW+2*id+1] = (float)sin(a); return;
  } id -= R_TW;
  if (id < R_TWF) {
    double a = -2.0*M_PI*(double)id/262144.0;
    W[oTWF+2*id] = (float)cos(a); W[oTWF+2*id+1] = (float)sin(a); return;
  } id -= R_TWF;
  if (id < R_TWC) {
    double a = -2.0*M_PI*(double)id/512.0;
    W[oTWC+2*id] = (float)cos(a); W[oTWC+2*id+1] = (float)sin(a); return;
  } id -= R_TWC;
  if (id < R_AW) {
    double fr = (double)id*(8000.0/512.0); double fsq = fr*fr;
    double num = 12194.217*12194.217*fsq*fsq;
    double den = (fsq+20.6*20.6)*(fsq+107.7*107.7)*(fsq+737.9*737.9)*sqrt(fsq+12194.217*12194.217) + 1e-8;
    W[oAW+id] = (float)(num/den); return;
  } id -= R_AW;
  if (id < R_MELFB) {
    int k = (int)(id/80), m = (int)(id%80);
    double fk = (double)k*(8000.0/512.0);
    double f0p = mel_fpt(m), f1p = mel_fpt(m+1), f2p = mel_fpt(m+2);
    double lower = (fk - f0p)/(f1p - f0p);
    double upper = (f2p - fk)/(f2p - f1p);
    double v = fmax(0.0, fmin(lower, upper));
    W[oMELFB+id] = (float)v; return;
  } id -= R_MELFB;
  if (id < R_WSQI) {
    int t = (int)id;
    int n1 = t/256; if (n1 > 625) n1 = 625;
    int n0t = t - 1023 + 255; int n0 = (n0t > 0) ? n0t/256 : 0;
    double s = 0.0;
    for (int n = n0; n <= n1; ++n) {
      int o = t - n*256;
      double wv = 0.5 - 0.5*cos(2.0*M_PI*(double)o/1024.0);
      s += wv*wv;
    }
    float sf = (float)s;
    W[oWSQI+t] = (sf > 1e-11f) ? (1.0f/sf) : 1.0f; return;
  } id -= R_WSQI;
  if (id < R_WIHT) { long k = id/768, g = id%768; W[oWIHT+id] = wih[g*80+k];  return; } id -= R_WIHT;
  if (id < R_W0T)  { long d = id/512, j = id%512; W[oW0T+id] = w0[j*21+d];   return; } id -= R_W0T;
  if (id < R_W1T)  { long k = id/512, j = id%512; W[oW1T+id] = w1[j*512+k];  return; } id -= R_W1T;
  if (id < R_W2T)  { long k = id/512, j = id%512; W[oW2T+id] = w2[j*512+k];  return; } id -= R_W2T;
  if (id < R_VTT)  { long k = id/65,  m = id%65;  W[oVTT+id] = vtw[m*512+k]; return; } id -= R_VTT;
  if (id < R_NFT)  { long k = id/65,  m = id%65;  W[oNFT+id] = nfw[m*512+k]; return; } id -= R_NFT;
  if (id < R_IR) {
    size_t base = oCONVA + 2*((size_t)8*NCONV + id);
    W[base] = (id < 8000) ? ir[id] : 0.0f; W[base+1] = 0.0f; return;
  }
}

// ---------------- STFT of audio + loud + mel ----------------
__global__ __launch_bounds__(256) void k_stft_mel(const float* audio, float* W) {
  int blk = blockIdx.x; int b = blk/FRM, f = blk%FRM; int tid = threadIdx.x;
  __shared__ float2 cb[1024];
  __shared__ float spec[513];
  __shared__ float redbuf[4];
  const float* arow = audio + (size_t)b*TLEN;
  const float2* tw = (const float2*)(W + oTW);
  for (int i = tid; i < 1024; i += 256) {
    float v = arow[mirror_idx(f*256 + i - 512)] * W[oWIN + i];
    int pos = __brev((unsigned)i) >> 22;
    cb[pos] = make_float2(v, 0.f);
  }
  __syncthreads();
  fft2<10,1>(cb, tw, tid, 256, false);
  for (int k = tid; k < 513; k += 256) { float2 z = cb[k]; spec[k] = z.x*z.x + z.y*z.y; }
  __syncthreads();
  float part = 0.f;
  for (int k = tid; k < 513; k += 256) part += (spec[k] + 1e-8f) * W[oAW + k];
  for (int off = 32; off; off >>= 1) part += __shfl_down(part, off, 64);
  if ((tid & 63) == 0) redbuf[tid >> 6] = part;
  __syncthreads();
  if (tid == 0) {
    float s = redbuf[0]+redbuf[1]+redbuf[2]+redbuf[3];
    W[oLOUD + blk] = 10.0f * log10f(s / 513.0f);
  }
  for (int m = tid; m < 80; m += 256) {
    float s = 0.f;
    for (int k = 0; k < 513; ++k) s += spec[k]*W[oMELFB + (size_t)k*80 + m];
    W[oMEL + (size_t)blk*80 + m] = logf(s + 1e-5f);
  }
}

// ---------------- mel normalization over time ----------------
__global__ void k_melnorm(float* W) {
  int id = blockIdx.x*256 + threadIdx.x;
  if (id >= BB*80) return;
  int b = id/80, m = id%80;
  double s = 0.0, ss = 0.0;
  for (int f = 0; f < FRM; ++f) {
    double v = W[oMEL + ((size_t)b*FRM + f)*80 + m];
    s += v; ss += v*v;
  }
  double mean = s/FRM;
  double var = ss/FRM - mean*mean;
  float mu = (float)mean;
  float rstd = (float)(1.0/sqrt(var + 1e-5));
  for (int f = 0; f < FRM; ++f) {
    size_t idx = oMEL + ((size_t)b*FRM + f)*80 + m;
    W[idx] = (W[idx] - mu)*rstd;
  }
}

// ---------------- GRU input precompute ----------------
__global__ void k_xp(float* W, const float* bih) {
  size_t id = (size_t)blockIdx.x*256 + threadIdx.x;
  if (id >= (size_t)NFRM*768) return;
  int g = (int)(id % 768);
  size_t q = id / 768;
  const float* mrow = W + oMEL + q*80;
  float acc = bih[g];
  for (int k = 0; k < 80; ++k) acc = fmaf(mrow[k], W[oWIHT + (size_t)k*768 + g], acc);
  W[oXP + q*768 + g] = acc;
}

// ================ MEGA kernel: GRU (block 0) + f0 + noise + zacc ================
// GRU: wave w owns output tiles 6w..6w+5 (8 waves, 48 tiles = 768 cols).
// Tiles 0..4 in registers, tile 5 in LDS. Raw LDS-only barriers; xp double-buffered.
__global__ __launch_bounds__(512, 2) void k_mega(float* W, const float* audio,
                                                 const float* whh, const float* bhh) {
  __shared__ unsigned short sB[32768];   // 64 KB
  __shared__ unsigned short sA[4096];    // 8 KB
  __shared__ float sGH[6144];            // 24 KB
  __shared__ float fr4[4][1032];         // 16.5 KB (f0 role)
  __shared__ float wpow[8];
  __shared__ float wmax[8];
  __shared__ int   wmaxi[8];
  int tid = threadIdx.x;
  int blk = blockIdx.x;

  if (blk == 0) {
    // ---------------- GRU role ----------------
    int w = tid >> 6, l = tid & 63;
    const float* XP = W + oXP;
    float* HS = W + oHS;

    for (int idx = tid; idx < 32768; idx += 512) {
      int lcol = idx >> 8, k = idx & 255;
      int gcol = 96*(lcol >> 4) + 80 + (lcol & 15);
      sB[lcol*256 + (k ^ ((lcol & 7) << 3))] = f2bf(whh[(size_t)gcol*256 + k]);
    }
    for (int idx = tid; idx < 4096; idx += 512) sA[idx] = 0;

    int cl = l & 15, khalf = (l >> 4) * 8;
    bf16x8 bw[40];
    #pragma unroll
    for (int t2 = 0; t2 < 5; ++t2) {
      int col = (6*w + t2)*16 + cl;
      #pragma unroll
      for (int kk = 0; kk < 8; ++kk) {
        const float* src = whh + (size_t)col*256 + kk*32 + khalf;
        short8 tmp;
        #pragma unroll
        for (int j = 0; j < 8; ++j) tmp[j] = (short)f2bf(src[j]);
        bw[t2*8 + kk] = __builtin_bit_cast(bf16x8, tmp);
      }
    }

    int g = tid & 255, bbase = tid >> 8;
    float bh_r = bhh[g], bh_z = bhh[256 + g], bh_n = bhh[512 + g];
    float hprev[4] = {0.f, 0.f, 0.f, 0.f};
    int aXor = (cl & 7) << 3;
    int lcol5 = w*16 + cl;

    // prologue: xp(0) into A set
    float xrA[4], xzA[4], xnA[4];
    #pragma unroll
    for (int j = 0; j < 4; ++j) {
      const float* xpp = XP + ((size_t)(bbase + 2*j)*FRM + 0)*768 + g;
      xrA[j] = xpp[0]; xzA[j] = xpp[256]; xnA[j] = xpp[512];
    }

    __syncthreads();

#define LDA(kk) (*(const bf16x8*)&sA[(cl)*256 + (((kk)*32 + khalf) ^ aXor)])
#define LDB(kk) (*(const bf16x8*)&sB[(lcol5)*256 + (((kk)*32 + khalf) ^ aXor)])
#define STEPK(A_, kk) \
      c0 = MFMA_BF16(A_, bw[0*8+(kk)], c0, 0, 0, 0); \
      c1 = MFMA_BF16(A_, bw[1*8+(kk)], c1, 0, 0, 0); \
      c2 = MFMA_BF16(A_, bw[2*8+(kk)], c2, 0, 0, 0); \
      c3 = MFMA_BF16(A_, bw[3*8+(kk)], c3, 0, 0, 0); \
      c4 = MFMA_BF16(A_, bw[4*8+(kk)], c4, 0, 0, 0); \
      c5 = MFMA_BF16(A_, LDB(kk), c5, 0, 0, 0);

    for (int t = 0; t < FRM; ++t) {
      // issue xp(t+1) loads (consumed at end of step; hidden under MFMA+gate)
      float xrB[4], xzB[4], xnB[4];
      int tn = (t + 1 < FRM) ? t + 1 : t;
      #pragma unroll
      for (int j = 0; j < 4; ++j) {
        const float* xpp = XP + ((size_t)(bbase + 2*j)*FRM + tn)*768 + g;
        xrB[j] = xpp[0]; xzB[j] = xpp[256]; xnB[j] = xpp[512];
      }
      f32x4 c0 = {0,0,0,0}, c1 = {0,0,0,0}, c2 = {0,0,0,0};
      f32x4 c3 = {0,0,0,0}, c4 = {0,0,0,0}, c5 = {0,0,0,0};
      bf16x8 a0 = LDA(0), a1 = LDA(1), a2 = LDA(2), a3 = LDA(3);
      STEPK(a0, 0) STEPK(a1, 1) STEPK(a2, 2) STEPK(a3, 3)
      a0 = LDA(4); a1 = LDA(5); a2 = LDA(6); a3 = LDA(7);
      STEPK(a0, 4) STEPK(a1, 5) STEPK(a2, 6) STEPK(a3, 7)
      int rowg = l >> 4;
      if (rowg < 2) {
        #pragma unroll
        for (int j = 0; j < 4; ++j) {
          int row = rowg*4 + j;
          sGH[row*768 + (6*w + 0)*16 + cl] = c0[j];
          sGH[row*768 + (6*w + 1)*16 + cl] = c1[j];
          sGH[row*768 + (6*w + 2)*16 + cl] = c2[j];
          sGH[row*768 + (6*w + 3)*16 + cl] = c3[j];
          sGH[row*768 + (6*w + 4)*16 + cl] = c4[j];
          sGH[row*768 + (6*w + 5)*16 + cl] = c5[j];
        }
      }
      LDS_BARRIER();
      #pragma unroll
      for (int j = 0; j < 4; ++j) {
        int bb = bbase + 2*j;
        float ghr = sGH[bb*768 + g];
        float ghz = sGH[bb*768 + 256 + g];
        float ghn = sGH[bb*768 + 512 + g];
        float r = 1.0f/(1.0f + __expf(-(xrA[j] + ghr + bh_r)));
        float z = 1.0f/(1.0f + __expf(-(xzA[j] + ghz + bh_z)));
        float nn = tanh_fast(xnA[j] + r*(ghn + bh_n));
        float h = (1.0f - z)*nn + z*hprev[j];
        hprev[j] = h;
        HS[((size_t)bb*FRM + t)*256 + g] = h;
        sA[bb*256 + (g ^ ((bb & 7) << 3))] = f2bf(h);
      }
      LDS_BARRIER();
      #pragma unroll
      for (int j = 0; j < 4; ++j) { xrA[j] = xrB[j]; xzA[j] = xzB[j]; xnA[j] = xnB[j]; }
    }
#undef LDA
#undef LDB
#undef STEPK
    return;
  }
  blk -= 1;

  if (blk < NFRM) {
    // ---------------- f0 role (one frame per block, 512 threads) ----------------
    int b = blk/FRM, f = blk%FRM;
    const float* arow = audio + (size_t)b*TLEN;
    for (int idx = tid; idx < 4*1032; idx += 512) {
      int s = idx/1032, i = idx - s*1032;
      int j = i + s;
      fr4[s][i] = (j < 1024) ? arow[mirror_idx(f*256 + j - 512)] : 0.f;
    }
    __syncthreads();
    int lane = tid & 63, wv = tid >> 6;
    float p = 0.f;
    for (int i = tid; i < 1024; i += 512) { float x = fr4[0][i]; p += x*x; }
    for (int off = 32; off; off >>= 1) p += __shfl_down(p, off, 64);
    if (lane == 0) wpow[wv] = p;
    float vbest = -1e30f; int ibest = tid;
    if (tid < 304) {
      int lag = 16 + tid;
      int s = lag & 3, base = lag - s;
      int qmax = (1023 - lag) >> 2;
      float acc = 0.f;
      for (int q = 0; q <= qmax; ++q) {
        float4 u = *(const float4*)&fr4[0][4*q];
        float4 v = *(const float4*)&fr4[s][base + 4*q];
        acc += u.x*v.x + u.y*v.y + u.z*v.z + u.w*v.w;
      }
      vbest = acc;
    }
    for (int off = 32; off; off >>= 1) {
      float v2 = __shfl_down(vbest, off, 64);
      int i2 = __shfl_down(ibest, off, 64);
      if (v2 > vbest || (v2 == vbest && i2 < ibest)) { vbest = v2; ibest = i2; }
    }
    if (lane == 0) { wmax[wv] = vbest; wmaxi[wv] = ibest; }
    __syncthreads();
    if (tid == 0) {
      float ac0 = 0.f;
      #pragma unroll
      for (int q = 0; q < 8; ++q) ac0 += wpow[q];
      float bv = wmax[0]; int bi = wmaxi[0];
      #pragma unroll
      for (int q = 1; q < 8; ++q) {
        if (wmax[q] > bv || (wmax[q] == bv && wmaxi[q] < bi)) { bv = wmax[q]; bi = wmaxi[q]; }
      }
      float inv = 1.0f/(ac0 + 1e-8f);
      float best = bv*inv;
      W[oF0 + (size_t)blk] = (best < 0.3f) ? 0.0f : (SRF/(float)(bi + 16));
    }
    return;
  }
  blk -= NFRM;

  if (blk < NOISEB) {
    // ---------------- noise role ----------------
    size_t base = (size_t)blk*4096 + (size_t)tid*8;
    #pragma unroll
    for (int j = 0; j < 8; ++j) {
      size_t p = base + j;
      if (p < (size_t)BB*TLEN) {
        unsigned o0, o1;
        threefry2x32(0u, 42u, 0u, (unsigned)p, o0, o1);
        W[oNOISE + p] = normal_from_bits(o0 ^ o1);
      }
    }
    return;
  }
  blk -= NOISEB;

  // ---------------- zacc role ----------------
  {
    size_t base = (size_t)blk*4096 + (size_t)tid*8;
    #pragma unroll
    for (int j = 0; j < 8; ++j) {
      size_t p = base + j;
      if (p < (size_t)BB*ACCLEN) W[oACC + p] = 0.0f;
    }
  }
}

// ---------------- MLP + heads (proj fused) ----------------
__device__ inline void ln_lrelu(float acc[8], float gj, float ej, float out[8][512],
                                float wred[8][8][2], float stat[8][2],
                                int tid, int lane, int wv, int j) {
  #pragma unroll
  for (int i = 0; i < 8; ++i) {
    float s = acc[i], ss = acc[i]*acc[i];
    for (int off = 32; off; off >>= 1) { s += __shfl_down(s, off, 64); ss += __shfl_down(ss, off, 64); }
    if (lane == 0) { wred[i][wv][0] = s; wred[i][wv][1] = ss; }
  }
  __syncthreads();
  if (tid < 8) {
    float s = 0.f, ss = 0.f;
    #pragma unroll
    for (int w = 0; w < 8; ++w) { s += wred[tid][w][0]; ss += wred[tid][w][1]; }
    float mean = s/512.0f;
    float var = ss/512.0f - mean*mean;
    stat[tid][0] = mean;
    stat[tid][1] = 1.0f/sqrtf(var + 1e-5f);
  }
  __syncthreads();
  #pragma unroll
  for (int i = 0; i < 8; ++i) {
    float v = (acc[i] - stat[i][0])*stat[i][1]*gj + ej;
    out[i][j] = (v >= 0.f) ? v : 0.1f*v;
  }
}

__global__ __launch_bounds__(512) void k_mlp(float* W, const float* gender, const float* age,
    const float* projw, const float* projb,
    const float* b0, const float* g0, const float* e0,
    const float* b1, const float* g1, const float* e1,
    const float* b2, const float* g2, const float* e2,
    const float* oqw, const float* oqb, const float* vtb, const float* nfb) {
  __shared__ float hbuf[8][256];
  __shared__ float in0[8][21];
  __shared__ float actA[8][512];
  __shared__ float actB[8][512];
  __shared__ float wred[8][8][2];
  __shared__ float stat[8][2];
  int tid = threadIdx.x; int q0 = blockIdx.x*8;
  // stage 8 h rows
  for (int x = tid; x < 2048; x += 512) {
    int i = x >> 8, k = x & 255;
    hbuf[i][k] = W[oHS + ((size_t)(q0 + i))*256 + k];
  }
  __syncthreads();
  // z = h @ projw^T + projb (tid<128), plus scalar features (tid 128..167)
  if (tid < 128) {
    int i = tid >> 4, zi = tid & 15;
    float a = projb[zi];
    for (int k = 0; k < 256; ++k) a = fmaf(hbuf[i][k], projw[zi*256 + k], a);
    in0[i][zi] = a;
  } else if (tid < 168) {
    int x = tid - 128; int i = x/5, d = 16 + x%5;
    int q = q0 + i; int b = q/FRM;
    float v;
    if (d == 16) v = (logf(W[oF0 + q] + 1e-5f) - 4.0f)*0.25f;
    else if (d == 17) v = W[oLOUD + q]/100.0f + 1.0f;
    else if (d == 18) v = gender[b*2];
    else if (d == 19) v = gender[b*2 + 1];
    else v = age[b];
    in0[i][d] = v;
  }
  __syncthreads();
  int j = tid, lane = tid & 63, wv = tid >> 6;
  float acc[8];
  #pragma unroll
  for (int i = 0; i < 8; ++i) acc[i] = b0[j];
  for (int d = 0; d < 21; ++d) {
    float w = W[oW0T + (size_t)d*512 + j];
    #pragma unroll
    for (int i = 0; i < 8; ++i) acc[i] = fmaf(in0[i][d], w, acc[i]);
  }
  ln_lrelu(acc, g0[j], e0[j], actA, wred, stat, tid, lane, wv, j);
  __syncthreads();
  #pragma unroll
  for (int i = 0; i < 8; ++i) acc[i] = b1[j];
  for (int k = 0; k < 512; ++k) {
    float w = W[oW1T + (size_t)k*512 + j];
    #pragma unroll
    for (int i = 0; i < 8; ++i) acc[i] = fmaf(actA[i][k], w, acc[i]);
  }
  ln_lrelu(acc, g1[j], e1[j], actB, wred, stat, tid, lane, wv, j);
  __syncthreads();
  #pragma unroll
  for (int i = 0; i < 8; ++i) acc[i] = b2[j];
  for (int k = 0; k < 512; ++k) {
    float w = W[oW2T + (size_t)k*512 + j];
    #pragma unroll
    for (int i = 0; i < 8; ++i) acc[i] = fmaf(actB[i][k], w, acc[i]);
  }
  ln_lrelu(acc, g2[j], e2[j], actA, wred, stat, tid, lane, wv, j);
  __syncthreads();
  for (int x = tid; x < 520; x += 512) {
    int i = x/65, m = x%65;
    float a = vtb[m], a2 = nfb[m];
    for (int k = 0; k < 512; ++k) {
      float h = actA[i][k];
      a  = fmaf(h, W[oVTT + (size_t)k*65 + m], a);
      a2 = fmaf(h, W[oNFT + (size_t)k*65 + m], a2);
    }
    W[oVT + (size_t)(q0+i)*65 + m] = sigm(a);
    W[oNF + (size_t)(q0+i)*65 + m] = sigm(a2);
  }
  if (tid < 8) {
    float a = oqb[0];
    for (int k = 0; k < 512; ++k) a = fmaf(actA[tid][k], oqw[k], a);
    W[oOQ + q0 + tid] = sigm(a);
  }
}

// ---------------- glottal: 4 samples/thread, 157 chunks ----------------
__global__ __launch_bounds__(256) void k_glottal(float* W) {
  int b = blockIdx.x; int tid = threadIdx.x;
  __shared__ float wsums[4];
  __shared__ float lastg[256];
  __shared__ double carry_sh;
  __shared__ float gprev_sh, ctot_sh;
  const float* f0r = W + oF0 + (size_t)b*FRM;
  const float* oqr = W + oOQ + (size_t)b*FRM;
  float* grow = W + oGLOT + (size_t)b*TLEN;
  if (tid == 0) { carry_sh = 0.0; gprev_sh = 0.f; }
  __syncthreads();
  int lane = tid & 63, wv = tid >> 6;
  for (int c = 0; c < 157; ++c) {
    int i0 = c*1024 + tid*4;
    float v[4]; float sum4 = 0.f;
    #pragma unroll
    for (int j = 0; j < 4; ++j) {
      int i = i0 + j;
      float x = (i < TLEN) ? interpF(f0r, i)*(1.0f/SRF) : 0.f;
      v[j] = x; sum4 += x;
    }
    float s = sum4;
    #pragma unroll
    for (int off = 1; off < 64; off <<= 1) {
      float o = __shfl_up(s, off, 64);
      if (lane >= off) s += o;
    }
    if (lane == 63) wsums[wv] = s;
    __syncthreads();
    float wpre = 0.f;
    for (int ww = 0; ww < wv; ++ww) wpre += wsums[ww];
    double ph0 = carry_sh + (double)(wpre + s - sum4);
    float run = 0.f; float gq[4];
    #pragma unroll
    for (int j = 0; j < 4; ++j) {
      int i = i0 + j;
      run += v[j];
      float ph = (float)(ph0 + (double)run);
      float p = ph - floorf(ph);
      float oqu = interpF(oqr, i);
      float oqc = fminf(fmaxf(oqu, 0.1f), 0.9f);
      float pulse = 0.5f*(1.0f - cosf(3.14159265358979f * p / (oqc + 1e-8f)));
      float gs = 1.0f/(1.0f + __expf(-(oqc - p)*100.0f));
      gq[j] = pulse*gs;
    }
    lastg[tid] = gq[3];
    if (tid == 255) ctot_sh = wpre + s;
    __syncthreads();
    float prevg = (tid == 0) ? gprev_sh : lastg[tid-1];
    #pragma unroll
    for (int j = 0; j < 4; ++j) {
      int i = i0 + j;
      if (i < TLEN) {
        float gl = (j == 0) ? prevg : gq[j-1];
        grow[i] = (i == 0) ? 0.f : (gq[j] - gl);
      }
    }
    __syncthreads();
    if (tid == 0) { carry_sh += (double)ctot_sh; gprev_sh = lastg[255]; }
  }
}

// ---------------- fused STFT->filter->ISTFT OLA ----------------
__global__ __launch_bounds__(256) void k_filtsynth(float* W) {
  int blk = blockIdx.x; int b = blk/FRM, f = blk%FRM; int tid = threadIdx.x;
  __shared__ float2 cG[1024], cN[1024];
  __shared__ float fvt[65], fnf[65];
  const float* grow = W + oGLOT + (size_t)b*TLEN;
  const float* nrow = W + oNOISE + (size_t)b*TLEN;
  const float2* tw = (const float2*)(W + oTW);
  for (int i = tid; i < 1024; i += 256) {
    int si = mirror_idx(f*256 + i - 512);
    float wv = W[oWIN + i];
    int pos = __brev((unsigned)i) >> 22;
    cG[pos] = make_float2(grow[si]*wv, 0.f);
    cN[pos] = make_float2(nrow[si]*wv, 0.f);
  }
  if (tid < 65) {
    fvt[tid] = W[oVT + ((size_t)b*FRM + f)*65 + tid];
    fnf[tid] = W[oNF + ((size_t)b*FRM + f)*65 + tid];
  }
  __syncthreads();
  fft2<10,1>(cG, tw, tid, 256, false);
  fft2<10,1>(cN, tw, tid, 256, false);
  for (int k = tid; k < 1024; k += 256) {
    int kp = min(k, 1024 - k);
    float fv = interp65(fvt, kp);
    float fn = interp65(fnf, kp);
    float2 zg = cG[k], zn = cN[k];
    cG[k] = make_float2(zg.x*fv + zn.x*fn, zg.y*fv + zn.y*fn);
  }
  __syncthreads();
  for (int i = tid; i < 1024; i += 256) {
    int jj = __brev((unsigned)i) >> 22;
    if (jj > i) { float2 t2 = cG[i]; cG[i] = cG[jj]; cG[jj] = t2; }
  }
  __syncthreads();
  fft2<10,1>(cG, tw, tid, 256, true);
  float* arow = W + oACC + (size_t)b*ACCLEN + (size_t)f*256;
  for (int i = tid; i < 1024; i += 256) {
    float xv = cG[i].x*(1.0f/1024.0f)*W[oWIN + i];
    atomicAdd(arow + i, xv);
  }
}

// ---------------- dry ----------------
__global__ void k_dry(float* W, float* dout) {
  size_t id = (size_t)blockIdx.x*256 + threadIdx.x;
  if (id >= (size_t)BB*NCONV) return;
  int b = (int)(id / NCONV);
  int n = (int)(id % NCONV);
  float dv = 0.f;
  if (n < TLEN) {
    float val = W[oACC + (size_t)b*ACCLEN + 512 + n] * W[oWSQI + 512 + n];
    const float* lrow = W + oLOUD + (size_t)b*FRM;
    float pos = ((float)n + 0.5f) * (626.0f/160000.0f) - 0.5f;
    pos = fminf(fmaxf(pos, 0.0f), 625.0f);
    int lo = (int)floorf(pos);
    int hi = min(lo + 1, 625);
    float w = pos - (float)lo;
    float a0 = exp10f(lrow[lo]*0.05f);
    float a1 = exp10f(lrow[hi]*0.05f);
    float ampu = a0*(1.0f - w) + a1*w;
    dv = val*ampu;
    dout[(size_t)BB*TLEN + (size_t)b*TLEN + n] = dv;
  }
  ((float2*)(W + oCONVA))[id] = make_float2(dv, 0.f);
}

// ---------------- four-step FFT (N = 512*512) ----------------
__global__ __launch_bounds__(256) void k_conv_f1(const float* in, float* out,
                                                 const float* tw, const float* twf,
                                                 const float* twc) {
  int blk = blockIdx.x; int t = blk >> 9; int bcol = blk & 511; int tid = threadIdx.x;
  __shared__ float2 cb[512];
  const float2* src = (const float2*)in + (size_t)t*NCONV;
  for (int a = tid; a < 512; a += 256) {
    int pos = __brev((unsigned)a) >> 23;
    cb[pos] = src[(size_t)a*512 + bcol];
  }
  __syncthreads();
  fft2<9,2>(cb, (const float2*)tw, tid, 256, false);
  float2* dst = (float2*)out + (size_t)t*NCONV + (size_t)bcol*512;
  for (int k1 = tid; k1 < 512; k1 += 256) {
    unsigned m = (unsigned)bcol * (unsigned)k1;   // < 262144
    float2 tc = ((const float2*)twc)[m >> 9];
    float2 tf = ((const float2*)twf)[m & 511];
    float wr = tc.x*tf.x - tc.y*tf.y;
    float wi = tc.x*tf.y + tc.y*tf.x;
    float2 v = cb[k1];
    dst[k1] = make_float2(v.x*wr - v.y*wi, v.x*wi + v.y*wr);
  }
}

__global__ __launch_bounds__(256) void k_conv_f2(const float* in, float* out, const float* tw) {
  int blk = blockIdx.x; int t = blk >> 9; int k1 = blk & 511; int tid = threadIdx.x;
  __shared__ float2 cb[512];
  const float2* src = (const float2*)in + (size_t)t*NCONV;
  for (int bb2 = tid; bb2 < 512; bb2 += 256) {
    int pos = __brev((unsigned)bb2) >> 23;
    cb[pos] = src[(size_t)bb2*512 + k1];
  }
  __syncthreads();
  fft2<9,2>(cb, (const float2*)tw, tid, 256, false);
  float2* dst = (float2*)out + (size_t)t*NCONV;
  for (int k2 = tid; k2 < 512; k2 += 256) {
    dst[(size_t)k1 + 512*(size_t)k2] = cb[k2];
  }
}

__global__ void k_mul(float* W) {
  size_t id = (size_t)blockIdx.x*256 + threadIdx.x;
  if (id >= (size_t)BB*NCONV) return;
  size_t k = id % NCONV;
  float2* A = (float2*)(W + oCONVA);
  float2 a = A[id];
  float2 c = A[(size_t)8*NCONV + k];
  float pr = a.x*c.x - a.y*c.y;
  float pi = a.x*c.y + a.y*c.x;
  A[id] = make_float2(pr, -pi);
}

__global__ void k_wet(const float* W, float* dout) {
  size_t id = (size_t)blockIdx.x*256 + threadIdx.x;
  if (id >= (size_t)BB*TLEN) return;
  size_t b = id / TLEN, n = id % TLEN;
  dout[id] = ((const float2*)(W + oCONVA))[b*NCONV + n].x * (1.0f/262144.0f);
}

// ---------------- launch ----------------
extern "C" void kernel_launch(void* const* d_in, const int* in_sizes, int n_in,
                              void* d_out, int out_size, void* d_ws, size_t ws_size,
                              hipStream_t stream) {
  (void)in_sizes; (void)n_in; (void)out_size; (void)ws_size;
  const float* audio  = (const float*)d_in[0];
  const float* gender = (const float*)d_in[1];
  const float* age    = (const float*)d_in[2];
  const float* wih    = (const float*)d_in[3];
  const float* whh    = (const float*)d_in[4];
  const float* bih    = (const float*)d_in[5];
  const float* bhh    = (const float*)d_in[6];
  const float* projw  = (const float*)d_in[7];
  const float* projb  = (const float*)d_in[8];
  const float* w0     = (const float*)d_in[9];
  const float* b0     = (const float*)d_in[10];
  const float* g0     = (const float*)d_in[11];
  const float* e0     = (const float*)d_in[12];
  const float* w1     = (const float*)d_in[13];
  const float* b1     = (const float*)d_in[14];
  const float* g1     = (const float*)d_in[15];
  const float* e1     = (const float*)d_in[16];
  const float* w2     = (const float*)d_in[17];
  const float* b2     = (const float*)d_in[18];
  const float* g2     = (const float*)d_in[19];
  const float* e2     = (const float*)d_in[20];
  const float* oqw    = (const float*)d_in[21];
  const float* oqb    = (const float*)d_in[22];
  const float* vtw    = (const float*)d_in[23];
  const float* vtb    = (const float*)d_in[24];
  const float* nfw    = (const float*)d_in[25];
  const float* nfb    = (const float*)d_in[26];
  const float* ir     = (const float*)d_in[27];
  float* W = (float*)d_ws;
  float* dout = (float*)d_out;

  k_init<<<(int)((INIT_TOTAL + 255)/256), 256, 0, stream>>>(W, wih, w0, w1, w2, vtw, nfw, ir);
  k_stft_mel<<<NFRM, 256, 0, stream>>>(audio, W);
  k_melnorm<<<3, 256, 0, stream>>>(W);
  k_xp<<<(int)(((size_t)NFRM*768 + 255)/256), 256, 0, stream>>>(W, bih);
  k_mega<<<MEGA_BLOCKS, 512, 0, stream>>>(W, audio, whh, bhh);
  k_mlp<<<NFRM/8, 512, 0, stream>>>(W, gender, age, projw, projb,
                                    b0, g0, e0, b1, g1, e1, b2, g2, e2, oqw, oqb, vtb, nfb);
  k_glottal<<<BB, 256, 0, stream>>>(W);
  k_filtsynth<<<NFRM, 256, 0, stream>>>(W);
  k_dry<<<(int)(((size_t)BB*NCONV + 255)/256), 256, 0, stream>>>(W, dout);
  k_conv_f1<<<9*512, 256, 0, stream>>>(W + oCONVA, W + oCONVB, W + oTW, W + oTWF, W + oTWC);
  k_conv_f2<<<9*512, 256, 0, stream>>>(W + oCONVB, W + oCONVA, W + oTW);
  k_mul<<<(int)(((size_t)BB*NCONV + 255)/256), 256, 0, stream>>>(W);
  k_conv_f1<<<8*512, 256, 0, stream>>>(W + oCONVA, W + oCONVB, W + oTW, W + oTWF, W + oTWC);
  k_conv_f2<<<8*512, 256, 0, stream>>>(W + oCONVB, W + oCONVA, W + oTW);
  k_wet<<<(int)(((size_t)BB*TLEN + 255)/256), 256, 0, stream>>>(W, dout);
}

// Round 8
// 2461.645 us; speedup vs baseline: 1.1267x; 1.1267x over previous
//
#include <hip/hip_runtime.h>
#include <math.h>

#define SRF 16000.0f
#define HOP 256
#define FRM 626
#define BB 8
#define TLEN 160000
#define NFRM (BB*FRM)
#define NCONV 262144
#define ACCLEN 161024
#define GCH 40            // glottal chunks per batch (40*4096 >= 160000)

// ---------------- workspace layout (float offsets) ----------------
constexpr size_t oWIN   = 0;                       // 1024
constexpr size_t oTW    = oWIN + 1024;             // 1024 (512 complex, angle -2pi r/1024)
constexpr size_t oDIAG  = oTW + 1024;              // 16 (unused)
constexpr size_t oTWF   = oDIAG + 16;              // 1024 (512 complex, angle -2pi r/262144)
constexpr size_t oTWC   = oTWF + 1024;             // 1024 (512 complex, angle -2pi r/512)
constexpr size_t oAW    = oTWC + 1024;             // 513
constexpr size_t oMELFB = oAW + 513;               // 41040
constexpr size_t oWSQI  = oMELFB + 513*80;         // 161024
constexpr size_t oWIHT  = oWSQI + ACCLEN;          // 61440
constexpr size_t oW0T   = oWIHT + 80*768;          // 10752
constexpr size_t oW1T   = oW0T + 21*512;           // 262144
constexpr size_t oW2T   = oW1T + 512*512;          // 262144
constexpr size_t oVTT   = oW2T + 512*512;          // 33280
constexpr size_t oNFT   = oVTT + 512*65;           // 33280
constexpr size_t oF0    = oNFT + 512*65;           // 5008
constexpr size_t oLOUD  = oF0 + NFRM;              // 5008
constexpr size_t oOQ    = oLOUD + NFRM;            // 5008
constexpr size_t oVT    = oOQ + NFRM;              // 325520
constexpr size_t oNF    = oVT + (size_t)NFRM*65;   // 325520
constexpr size_t oGLOT  = oNF + (size_t)NFRM*65;   // 1280000
constexpr size_t oNOISE = oGLOT + (size_t)BB*TLEN; // 1280000
constexpr size_t oACC   = oNOISE + (size_t)BB*TLEN;// 1288192
constexpr size_t oCONVA = oACC + (size_t)BB*ACCLEN;// 4718592
constexpr size_t oEND   = oCONVA + (size_t)9*NCONV*2;
constexpr size_t oXP    = oEND;                    // NFRM*768 dedicated
constexpr size_t oGSUM  = oXP + (size_t)NFRM*768;  // BB*GCH
constexpr size_t oGPRE  = oGSUM + 320;             // BB*GCH doubles (640 floats, 8B aligned)
constexpr size_t oEND2  = oGPRE + 640;
// overlays (lifetime-checked):
constexpr size_t oCONVB = oWSQI;                      // conv scratch; WSQI..ACC dead at conv time
constexpr size_t oMEL = oCONVA;                       // dead before k_dry packs CONVA
constexpr size_t oHS  = oMEL + (size_t)NFRM*80;       // ends well below ir slot

// init task counts
constexpr long R_WIN=1024, R_TW=512, R_TWF=512, R_TWC=512, R_AW=513, R_MELFB=41040,
  R_WSQI=161024, R_WIHT=61440, R_W0T=10752, R_W1T=262144, R_W2T=262144,
  R_VTT=33280, R_NFT=33280, R_IR=NCONV;
constexpr long INIT_TOTAL = R_WIN+R_TW+R_TWF+R_TWC+R_AW+R_MELFB+R_WSQI+R_WIHT+R_W0T+
  R_W1T+R_W2T+R_VTT+R_NFT+R_IR;

// mega-kernel block roles
constexpr int NOISEB = 313;   // 313*4096 >= 1,280,000
constexpr int ZACCB  = 315;   // 315*4096 >= 1,288,192
constexpr int MEGA_BLOCKS = 1 + NFRM + NOISEB + ZACCB;

typedef float f32x4 __attribute__((ext_vector_type(4)));
typedef __bf16 bf16x8 __attribute__((ext_vector_type(8)));
typedef short short8 __attribute__((ext_vector_type(8)));
#define MFMA_BF16 __builtin_amdgcn_mfma_f32_16x16x32_bf16

// ---------------- helpers ----------------
__device__ inline int mirror_idx(int j) {
  if (j < 0) j = -j;
  if (j >= TLEN) j = 2*TLEN - 2 - j;
  return j;
}
__device__ inline float sigm(float x) { return 1.0f/(1.0f + expf(-x)); }
__device__ inline unsigned short f2bf(float x) {
  unsigned u = __float_as_uint(x);
  return (unsigned short)((u + 0x7FFFu + ((u >> 16) & 1u)) >> 16);
}
__device__ inline float tanh_fast(float x) {
  return 1.0f - 2.0f/(__expf(2.0f*x) + 1.0f);
}

__device__ inline float interpF(const float* v, int i) {
  float pos = ((float)i + 0.5f) * (626.0f/160000.0f) - 0.5f;
  pos = fminf(fmaxf(pos, 0.0f), 625.0f);
  int lo = (int)floorf(pos);
  int hi = min(lo + 1, 625);
  float w = pos - (float)lo;
  return v[lo]*(1.0f - w) + v[hi]*w;
}
__device__ inline float interp65(const float* v, int k) {
  float pos = ((float)k + 0.5f) * (65.0f/513.0f) - 0.5f;
  pos = fminf(fmaxf(pos, 0.0f), 64.0f);
  int lo = (int)floorf(pos);
  int hi = min(lo + 1, 64);
  float w = pos - (float)lo;
  return v[lo]*(1.0f - w) + v[hi]*w;
}
// glottal waveform at sample i given inclusive phase ph
__device__ inline float gwave(float ph, float oqu) {
  float p = ph - floorf(ph);
  float oqc = fminf(fmaxf(oqu, 0.1f), 0.9f);
  float pulse = 0.5f*(1.0f - cosf(3.14159265358979f * p / (oqc + 1e-8f)));
  float gs = 1.0f/(1.0f + __expf(-(oqc - p)*100.0f));
  return pulse*gs;
}

// radix-2 DIT FFT in LDS on interleaved complex; input at bit-reversed positions.
template<int LOGN, int TS>
__device__ inline void fft2(float2* c, const float2* tw, int tid, int nthr, bool inv) {
  constexpr int N = 1 << LOGN;
  for (int s = 1; s <= LOGN; ++s) {
    const int half = 1 << (s-1);
    const int tstep = (N >> s) * TS;
    for (int bf = tid; bf < (N>>1); bf += nthr) {
      int jj = bf & (half-1);
      int i0 = ((bf >> (s-1)) << s) + jj;
      int i1 = i0 + half;
      float2 wv = tw[jj*tstep];
      float wi = inv ? -wv.y : wv.y;
      float2 u = c[i0], v = c[i1];
      float tr  = v.x*wv.x - v.y*wi;
      float tci = v.x*wi  + v.y*wv.x;
      c[i0] = make_float2(u.x + tr, u.y + tci);
      c[i1] = make_float2(u.x - tr, u.y - tci);
    }
    __syncthreads();
  }
}

// threefry2x32, canonical 20-round schedule
__device__ inline void threefry2x32(unsigned k0, unsigned k1, unsigned x0, unsigned x1,
                                    unsigned& o0, unsigned& o1) {
  unsigned ks2 = k0 ^ k1 ^ 0x1BD11BDAu;
  x0 += k0; x1 += k1;
#define TF_R(r) { x0 += x1; x1 = (x1<<(r)) | (x1>>(32-(r))); x1 ^= x0; }
  TF_R(13) TF_R(15) TF_R(26) TF_R(6)
  x0 += k1; x1 += ks2 + 1u;
  TF_R(17) TF_R(29) TF_R(16) TF_R(24)
  x0 += ks2; x1 += k0 + 2u;
  TF_R(13) TF_R(15) TF_R(26) TF_R(6)
  x0 += k0; x1 += k1 + 3u;
  TF_R(17) TF_R(29) TF_R(16) TF_R(24)
  x0 += k1; x1 += ks2 + 4u;
  TF_R(13) TF_R(15) TF_R(26) TF_R(6)
  x0 += ks2; x1 += k0 + 5u;
#undef TF_R
  o0 = x0; o1 = x1;
}

__device__ inline float erfinv_f(float x) { // XLA f32 ErfInv (Giles)
  float w = -log1pf(-x*x);
  float p;
  if (w < 5.0f) {
    w = w - 2.5f;
    p = 2.81022636e-08f;
    p = fmaf(p, w, 3.43273939e-07f);
    p = fmaf(p, w, -3.5233877e-06f);
    p = fmaf(p, w, -4.39150654e-06f);
    p = fmaf(p, w, 0.00021858087f);
    p = fmaf(p, w, -0.00125372503f);
    p = fmaf(p, w, -0.00417768164f);
    p = fmaf(p, w, 0.246640727f);
    p = fmaf(p, w, 1.50140941f);
  } else {
    w = sqrtf(w) - 3.0f;
    p = -0.000200214257f;
    p = fmaf(p, w, 0.000100950558f);
    p = fmaf(p, w, 0.00134934322f);
    p = fmaf(p, w, -0.00367342844f);
    p = fmaf(p, w, 0.00573950773f);
    p = fmaf(p, w, -0.0076224613f);
    p = fmaf(p, w, 0.00943887047f);
    p = fmaf(p, w, 1.00167406f);
    p = fmaf(p, w, 2.83297682f);
  }
  return p*x;
}
__device__ inline float normal_from_bits(unsigned bits) {
  float f = __uint_as_float((bits >> 9) | 0x3F800000u) - 1.0f;
  float x = fmaxf(-0.99999994f, fmaf(f, 1.99999994f, -0.99999994f));
  return 1.41421356237f * erfinv_f(x);
}

__device__ inline double mel_fpt(int j) {
  double mmax = 2595.0 * log10(1.0 + 8000.0/700.0);
  return 700.0 * (pow(10.0, (mmax * (double)j / 81.0) / 2595.0) - 1.0);
}

// ---------------- init ----------------
__global__ void k_init(float* W, const float* wih, const float* w0,
                       const float* w1, const float* w2, const float* vtw, const float* nfw,
                       const float* ir) {
  long id = (long)blockIdx.x*256 + threadIdx.x;
  if (id < R_WIN) {
    double w = 0.5 - 0.5*cos(2.0*M_PI*(double)id/1024.0);
    W[oWIN+id] = (float)w; return;
  } id -= R_WIN;
  if (id < R_TW) {
    double a = -2.0*M_PI*(double)id/1024.0;
    W[oTW+2*id] = (float)cos(a); W[oTW+2*id+1] = (float)sin(a); return;
  } id -= R_TW;
  if (id < R_TWF) {
    double a = -2.0*M_PI*(double)id/262144.0;
    W[oTWF+2*id] = (float)cos(a); W[oTWF+2*id+1] = (float)sin(a); return;
  } id -= R_TWF;
  if (id < R_TWC) {
    double a = -2.0*M_PI*(double)id/512.0;
    W[oTWC+2*id] = (float)cos(a); W[oTWC+2*id+1] = (float)sin(a); return;
  } id -= R_TWC;
  if (id < R_AW) {
    double fr = (double)id*(8000.0/512.0); double fsq = fr*fr;
    double num = 12194.217*12194.217*fsq*fsq;
    double den = (fsq+20.6*20.6)*(fsq+107.7*107.7)*(fsq+737.9*737.9)*sqrt(fsq+12194.217*12194.217) + 1e-8;
    W[oAW+id] = (float)(num/den); return;
  } id -= R_AW;
  if (id < R_MELFB) {
    int k = (int)(id/80), m = (int)(id%80);
    double fk = (double)k*(8000.0/512.0);
    double f0p = mel_fpt(m), f1p = mel_fpt(m+1), f2p = mel_fpt(m+2);
    double lower = (fk - f0p)/(f1p - f0p);
    double upper = (f2p - fk)/(f2p - f1p);
    double v = fmax(0.0, fmin(lower, upper));
    W[oMELFB+id] = (float)v; return;
  } id -= R_MELFB;
  if (id < R_WSQI) {
    int t = (int)id;
    int n1 = t/256; if (n1 > 625) n1 = 625;
    int n0t = t - 1023 + 255; int n0 = (n0t > 0) ? n0t/256 : 0;
    double s = 0.0;
    for (int n = n0; n <= n1; ++n) {
      int o = t - n*256;
      double wv = 0.5 - 0.5*cos(2.0*M_PI*(double)o/1024.0);
      s += wv*wv;
    }
    float sf = (float)s;
    W[oWSQI+t] = (sf > 1e-11f) ? (1.0f/sf) : 1.0f; return;
  } id -= R_WSQI;
  if (id < R_WIHT) { long k = id/768, g = id%768; W[oWIHT+id] = wih[g*80+k];  return; } id -= R_WIHT;
  if (id < R_W0T)  { long d = id/512, j = id%512; W[oW0T+id] = w0[j*21+d];   return; } id -= R_W0T;
  if (id < R_W1T)  { long k = id/512, j = id%512; W[oW1T+id] = w1[j*512+k];  return; } id -= R_W1T;
  if (id < R_W2T)  { long k = id/512, j = id%512; W[oW2T+id] = w2[j*512+k];  return; } id -= R_W2T;
  if (id < R_VTT)  { long k = id/65,  m = id%65;  W[oVTT+id] = vtw[m*512+k]; return; } id -= R_VTT;
  if (id < R_NFT)  { long k = id/65,  m = id%65;  W[oNFT+id] = nfw[m*512+k]; return; } id -= R_NFT;
  if (id < R_IR) {
    size_t base = oCONVA + 2*((size_t)8*NCONV + id);
    W[base] = (id < 8000) ? ir[id] : 0.0f; W[base+1] = 0.0f; return;
  }
}

// ---------------- STFT of audio + loud + mel ----------------
__global__ __launch_bounds__(256) void k_stft_mel(const float* audio, float* W) {
  int blk = blockIdx.x; int b = blk/FRM, f = blk%FRM; int tid = threadIdx.x;
  __shared__ float2 cb[1024];
  __shared__ float spec[513];
  __shared__ float redbuf[4];
  const float* arow = audio + (size_t)b*TLEN;
  const float2* tw = (const float2*)(W + oTW);
  for (int i = tid; i < 1024; i += 256) {
    float v = arow[mirror_idx(f*256 + i - 512)] * W[oWIN + i];
    int pos = __brev((unsigned)i) >> 22;
    cb[pos] = make_float2(v, 0.f);
  }
  __syncthreads();
  fft2<10,1>(cb, tw, tid, 256, false);
  for (int k = tid; k < 513; k += 256) { float2 z = cb[k]; spec[k] = z.x*z.x + z.y*z.y; }
  __syncthreads();
  float part = 0.f;
  for (int k = tid; k < 513; k += 256) part += (spec[k] + 1e-8f) * W[oAW + k];
  for (int off = 32; off; off >>= 1) part += __shfl_down(part, off, 64);
  if ((tid & 63) == 0) redbuf[tid >> 6] = part;
  __syncthreads();
  if (tid == 0) {
    float s = redbuf[0]+redbuf[1]+redbuf[2]+redbuf[3];
    W[oLOUD + blk] = 10.0f * log10f(s / 513.0f);
  }
  for (int m = tid; m < 80; m += 256) {
    float s = 0.f;
    for (int k = 0; k < 513; ++k) s += spec[k]*W[oMELFB + (size_t)k*80 + m];
    W[oMEL + (size_t)blk*80 + m] = logf(s + 1e-5f);
  }
}

// ---------------- mel normalization over time ----------------
__global__ void k_melnorm(float* W) {
  int id = blockIdx.x*256 + threadIdx.x;
  if (id >= BB*80) return;
  int b = id/80, m = id%80;
  double s = 0.0, ss = 0.0;
  for (int f = 0; f < FRM; ++f) {
    double v = W[oMEL + ((size_t)b*FRM + f)*80 + m];
    s += v; ss += v*v;
  }
  double mean = s/FRM;
  double var = ss/FRM - mean*mean;
  float mu = (float)mean;
  float rstd = (float)(1.0/sqrt(var + 1e-5));
  for (int f = 0; f < FRM; ++f) {
    size_t idx = oMEL + ((size_t)b*FRM + f)*80 + m;
    W[idx] = (W[idx] - mu)*rstd;
  }
}

// ---------------- GRU input precompute ----------------
__global__ void k_xp(float* W, const float* bih) {
  size_t id = (size_t)blockIdx.x*256 + threadIdx.x;
  if (id >= (size_t)NFRM*768) return;
  int g = (int)(id % 768);
  size_t q = id / 768;
  const float* mrow = W + oMEL + q*80;
  float acc = bih[g];
  for (int k = 0; k < 80; ++k) acc = fmaf(mrow[k], W[oWIHT + (size_t)k*768 + g], acc);
  W[oXP + q*768 + g] = acc;
}

// ================ MEGA kernel: GRU (block 0) + f0 + noise + zacc ================
__global__ __launch_bounds__(512, 2) void k_mega(float* W, const float* audio,
                                                 const float* whh, const float* bhh) {
  __shared__ unsigned short sB[32768];   // 64 KB
  __shared__ unsigned short sA[4096];    // 8 KB
  __shared__ float sGH[6144];            // 24 KB
  __shared__ float fr4[4][1032];         // 16.5 KB (f0 role)
  __shared__ float wpow[8];
  __shared__ float wmax[8];
  __shared__ int   wmaxi[8];
  int tid = threadIdx.x;
  int blk = blockIdx.x;

  if (blk == 0) {
    // ---------------- GRU role ----------------
    int w = tid >> 6, l = tid & 63;
    const float* XP = W + oXP;
    float* HS = W + oHS;

    for (int idx = tid; idx < 32768; idx += 512) {
      int lcol = idx >> 8, k = idx & 255;
      int gcol = 96*(lcol >> 4) + 80 + (lcol & 15);
      sB[lcol*256 + (k ^ ((lcol & 7) << 3))] = f2bf(whh[(size_t)gcol*256 + k]);
    }
    for (int idx = tid; idx < 4096; idx += 512) sA[idx] = 0;

    int cl = l & 15, khalf = (l >> 4) * 8;
    bf16x8 bw[40];
    #pragma unroll
    for (int t2 = 0; t2 < 5; ++t2) {
      int col = (6*w + t2)*16 + cl;
      #pragma unroll
      for (int kk = 0; kk < 8; ++kk) {
        const float* src = whh + (size_t)col*256 + kk*32 + khalf;
        short8 tmp;
        #pragma unroll
        for (int j = 0; j < 8; ++j) tmp[j] = (short)f2bf(src[j]);
        bw[t2*8 + kk] = __builtin_bit_cast(bf16x8, tmp);
      }
    }

    int g = tid & 255, bbase = tid >> 8;
    float bh_r = bhh[g], bh_z = bhh[256 + g], bh_n = bhh[512 + g];
    float hprev[4] = {0.f, 0.f, 0.f, 0.f};
    int aXor = (cl & 7) << 3;
    int lcol5 = w*16 + cl;

    // prologue: xp(0)
    float xrA[4], xzA[4], xnA[4];
    #pragma unroll
    for (int j = 0; j < 4; ++j) {
      const float* xpp = XP + ((size_t)(bbase + 2*j)*FRM + 0)*768 + g;
      xrA[j] = xpp[0]; xzA[j] = xpp[256]; xnA[j] = xpp[512];
    }

    __syncthreads();

#define LDA(kk) (*(const bf16x8*)&sA[(cl)*256 + (((kk)*32 + khalf) ^ aXor)])
#define LDB(kk) (*(const bf16x8*)&sB[(lcol5)*256 + (((kk)*32 + khalf) ^ aXor)])
#define STEPK(A_, kk) \
      c0 = MFMA_BF16(A_, bw[0*8+(kk)], c0, 0, 0, 0); \
      c1 = MFMA_BF16(A_, bw[1*8+(kk)], c1, 0, 0, 0); \
      c2 = MFMA_BF16(A_, bw[2*8+(kk)], c2, 0, 0, 0); \
      c3 = MFMA_BF16(A_, bw[3*8+(kk)], c3, 0, 0, 0); \
      c4 = MFMA_BF16(A_, bw[4*8+(kk)], c4, 0, 0, 0); \
      c5 = MFMA_BF16(A_, LDB(kk), c5, 0, 0, 0);

    for (int t = 0; t < FRM; ++t) {
      // prefetch xp(t+1); consumed next iteration
      float xrB[4], xzB[4], xnB[4];
      int tn = (t + 1 < FRM) ? t + 1 : t;
      #pragma unroll
      for (int j = 0; j < 4; ++j) {
        const float* xpp = XP + ((size_t)(bbase + 2*j)*FRM + tn)*768 + g;
        xrB[j] = xpp[0]; xzB[j] = xpp[256]; xnB[j] = xpp[512];
      }
      f32x4 c0 = {0,0,0,0}, c1 = {0,0,0,0}, c2 = {0,0,0,0};
      f32x4 c3 = {0,0,0,0}, c4 = {0,0,0,0}, c5 = {0,0,0,0};
      bf16x8 a0 = LDA(0), a1 = LDA(1), a2 = LDA(2), a3 = LDA(3);
      STEPK(a0, 0) STEPK(a1, 1) STEPK(a2, 2) STEPK(a3, 3)
      a0 = LDA(4); a1 = LDA(5); a2 = LDA(6); a3 = LDA(7);
      STEPK(a0, 4) STEPK(a1, 5) STEPK(a2, 6) STEPK(a3, 7)
      int rowg = l >> 4;
      if (rowg < 2) {
        #pragma unroll
        for (int j = 0; j < 4; ++j) {
          int row = rowg*4 + j;
          sGH[row*768 + (6*w + 0)*16 + cl] = c0[j];
          sGH[row*768 + (6*w + 1)*16 + cl] = c1[j];
          sGH[row*768 + (6*w + 2)*16 + cl] = c2[j];
          sGH[row*768 + (6*w + 3)*16 + cl] = c3[j];
          sGH[row*768 + (6*w + 4)*16 + cl] = c4[j];
          sGH[row*768 + (6*w + 5)*16 + cl] = c5[j];
        }
      }
      __syncthreads();
      #pragma unroll
      for (int j = 0; j < 4; ++j) {
        int bb = bbase + 2*j;
        float ghr = sGH[bb*768 + g];
        float ghz = sGH[bb*768 + 256 + g];
        float ghn = sGH[bb*768 + 512 + g];
        float r = 1.0f/(1.0f + __expf(-(xrA[j] + ghr + bh_r)));
        float z = 1.0f/(1.0f + __expf(-(xzA[j] + ghz + bh_z)));
        float nn = tanh_fast(xnA[j] + r*(ghn + bh_n));
        float h = (1.0f - z)*nn + z*hprev[j];
        hprev[j] = h;
        HS[((size_t)bb*FRM + t)*256 + g] = h;
        sA[bb*256 + (g ^ ((bb & 7) << 3))] = f2bf(h);
      }
      __syncthreads();
      #pragma unroll
      for (int j = 0; j < 4; ++j) { xrA[j] = xrB[j]; xzA[j] = xzB[j]; xnA[j] = xnB[j]; }
    }
#undef LDA
#undef LDB
#undef STEPK
    return;
  }
  blk -= 1;

  if (blk < NFRM) {
    // ---------------- f0 role ----------------
    int b = blk/FRM, f = blk%FRM;
    const float* arow = audio + (size_t)b*TLEN;
    for (int idx = tid; idx < 4*1032; idx += 512) {
      int s = idx/1032, i = idx - s*1032;
      int j = i + s;
      fr4[s][i] = (j < 1024) ? arow[mirror_idx(f*256 + j - 512)] : 0.f;
    }
    __syncthreads();
    int lane = tid & 63, wv = tid >> 6;
    float p = 0.f;
    for (int i = tid; i < 1024; i += 512) { float x = fr4[0][i]; p += x*x; }
    for (int off = 32; off; off >>= 1) p += __shfl_down(p, off, 64);
    if (lane == 0) wpow[wv] = p;
    float vbest = -1e30f; int ibest = tid;
    if (tid < 304) {
      int lag = 16 + tid;
      int s = lag & 3, base = lag - s;
      int qmax = (1023 - lag) >> 2;
      float acc = 0.f;
      for (int q = 0; q <= qmax; ++q) {
        float4 u = *(const float4*)&fr4[0][4*q];
        float4 v = *(const float4*)&fr4[s][base + 4*q];
        acc += u.x*v.x + u.y*v.y + u.z*v.z + u.w*v.w;
      }
      vbest = acc;
    }
    for (int off = 32; off; off >>= 1) {
      float v2 = __shfl_down(vbest, off, 64);
      int i2 = __shfl_down(ibest, off, 64);
      if (v2 > vbest || (v2 == vbest && i2 < ibest)) { vbest = v2; ibest = i2; }
    }
    if (lane == 0) { wmax[wv] = vbest; wmaxi[wv] = ibest; }
    __syncthreads();
    if (tid == 0) {
      float ac0 = 0.f;
      #pragma unroll
      for (int q = 0; q < 8; ++q) ac0 += wpow[q];
      float bv = wmax[0]; int bi = wmaxi[0];
      #pragma unroll
      for (int q = 1; q < 8; ++q) {
        if (wmax[q] > bv || (wmax[q] == bv && wmaxi[q] < bi)) { bv = wmax[q]; bi = wmaxi[q]; }
      }
      float inv = 1.0f/(ac0 + 1e-8f);
      float best = bv*inv;
      W[oF0 + (size_t)blk] = (best < 0.3f) ? 0.0f : (SRF/(float)(bi + 16));
    }
    return;
  }
  blk -= NFRM;

  if (blk < NOISEB) {
    // ---------------- noise role (coalesced) ----------------
    size_t base = (size_t)blk*4096;
    #pragma unroll
    for (int j = 0; j < 8; ++j) {
      size_t p = base + (size_t)j*512 + tid;
      if (p < (size_t)BB*TLEN) {
        unsigned o0, o1;
        threefry2x32(0u, 42u, 0u, (unsigned)p, o0, o1);
        W[oNOISE + p] = normal_from_bits(o0 ^ o1);
      }
    }
    return;
  }
  blk -= NOISEB;

  // ---------------- zacc role (coalesced) ----------------
  {
    size_t base = (size_t)blk*4096;
    #pragma unroll
    for (int j = 0; j < 8; ++j) {
      size_t p = base + (size_t)j*512 + tid;
      if (p < (size_t)BB*ACCLEN) W[oACC + p] = 0.0f;
    }
  }
}

// ---------------- MLP + heads (proj fused) ----------------
__device__ inline void ln_lrelu(float acc[8], float gj, float ej, float out[8][512],
                                float wred[8][8][2], float stat[8][2],
                                int tid, int lane, int wv, int j) {
  #pragma unroll
  for (int i = 0; i < 8; ++i) {
    float s = acc[i], ss = acc[i]*acc[i];
    for (int off = 32; off; off >>= 1) { s += __shfl_down(s, off, 64); ss += __shfl_down(ss, off, 64); }
    if (lane == 0) { wred[i][wv][0] = s; wred[i][wv][1] = ss; }
  }
  __syncthreads();
  if (tid < 8) {
    float s = 0.f, ss = 0.f;
    #pragma unroll
    for (int w = 0; w < 8; ++w) { s += wred[tid][w][0]; ss += wred[tid][w][1]; }
    float mean = s/512.0f;
    float var = ss/512.0f - mean*mean;
    stat[tid][0] = mean;
    stat[tid][1] = 1.0f/sqrtf(var + 1e-5f);
  }
  __syncthreads();
  #pragma unroll
  for (int i = 0; i < 8; ++i) {
    float v = (acc[i] - stat[i][0])*stat[i][1]*gj + ej;
    out[i][j] = (v >= 0.f) ? v : 0.1f*v;
  }
}

__global__ __launch_bounds__(512) void k_mlp(float* W, const float* gender, const float* age,
    const float* projw, const float* projb,
    const float* b0, const float* g0, const float* e0,
    const float* b1, const float* g1, const float* e1,
    const float* b2, const float* g2, const float* e2,
    const float* oqw, const float* oqb, const float* vtb, const float* nfb) {
  __shared__ float hbuf[8][256];
  __shared__ float in0[8][21];
  __shared__ float actA[8][512];
  __shared__ float actB[8][512];
  __shared__ float wred[8][8][2];
  __shared__ float stat[8][2];
  int tid = threadIdx.x; int q0 = blockIdx.x*8;
  for (int x = tid; x < 2048; x += 512) {
    int i = x >> 8, k = x & 255;
    hbuf[i][k] = W[oHS + ((size_t)(q0 + i))*256 + k];
  }
  __syncthreads();
  if (tid < 128) {
    int i = tid >> 4, zi = tid & 15;
    float a = projb[zi];
    for (int k = 0; k < 256; ++k) a = fmaf(hbuf[i][k], projw[zi*256 + k], a);
    in0[i][zi] = a;
  } else if (tid < 168) {
    int x = tid - 128; int i = x/5, d = 16 + x%5;
    int q = q0 + i; int b = q/FRM;
    float v;
    if (d == 16) v = (logf(W[oF0 + q] + 1e-5f) - 4.0f)*0.25f;
    else if (d == 17) v = W[oLOUD + q]/100.0f + 1.0f;
    else if (d == 18) v = gender[b*2];
    else if (d == 19) v = gender[b*2 + 1];
    else v = age[b];
    in0[i][d] = v;
  }
  __syncthreads();
  int j = tid, lane = tid & 63, wv = tid >> 6;
  float acc[8];
  #pragma unroll
  for (int i = 0; i < 8; ++i) acc[i] = b0[j];
  for (int d = 0; d < 21; ++d) {
    float w = W[oW0T + (size_t)d*512 + j];
    #pragma unroll
    for (int i = 0; i < 8; ++i) acc[i] = fmaf(in0[i][d], w, acc[i]);
  }
  ln_lrelu(acc, g0[j], e0[j], actA, wred, stat, tid, lane, wv, j);
  __syncthreads();
  #pragma unroll
  for (int i = 0; i < 8; ++i) acc[i] = b1[j];
  for (int k = 0; k < 512; ++k) {
    float w = W[oW1T + (size_t)k*512 + j];
    #pragma unroll
    for (int i = 0; i < 8; ++i) acc[i] = fmaf(actA[i][k], w, acc[i]);
  }
  ln_lrelu(acc, g1[j], e1[j], actB, wred, stat, tid, lane, wv, j);
  __syncthreads();
  #pragma unroll
  for (int i = 0; i < 8; ++i) acc[i] = b2[j];
  for (int k = 0; k < 512; ++k) {
    float w = W[oW2T + (size_t)k*512 + j];
    #pragma unroll
    for (int i = 0; i < 8; ++i) acc[i] = fmaf(actB[i][k], w, acc[i]);
  }
  ln_lrelu(acc, g2[j], e2[j], actA, wred, stat, tid, lane, wv, j);
  __syncthreads();
  for (int x = tid; x < 520; x += 512) {
    int i = x/65, m = x%65;
    float a = vtb[m], a2 = nfb[m];
    for (int k = 0; k < 512; ++k) {
      float h = actA[i][k];
      a  = fmaf(h, W[oVTT + (size_t)k*65 + m], a);
      a2 = fmaf(h, W[oNFT + (size_t)k*65 + m], a2);
    }
    W[oVT + (size_t)(q0+i)*65 + m] = sigm(a);
    W[oNF + (size_t)(q0+i)*65 + m] = sigm(a2);
  }
  if (tid < 8) {
    float a = oqb[0];
    for (int k = 0; k < 512; ++k) a = fmaf(actA[tid][k], oqw[k], a);
    W[oOQ + q0 + tid] = sigm(a);
  }
}

// ---------------- glottal: parallel 3-phase (chunk sums -> scan -> apply) ----------------
__global__ __launch_bounds__(256) void k_gsum(float* W) {
  int blk = blockIdx.x; int b = blk/GCH, c = blk%GCH; int tid = threadIdx.x;
  __shared__ float ws[4];
  const float* f0r = W + oF0 + (size_t)b*FRM;
  int i0 = c*4096 + tid*16;
  float s = 0.f;
  #pragma unroll
  for (int j = 0; j < 16; ++j) {
    int i = i0 + j;
    if (i < TLEN) s += interpF(f0r, i)*(1.0f/SRF);
  }
  for (int off = 32; off; off >>= 1) s += __shfl_down(s, off, 64);
  if ((tid & 63) == 0) ws[tid >> 6] = s;
  __syncthreads();
  if (tid == 0) W[oGSUM + (size_t)b*GCH + c] = ws[0]+ws[1]+ws[2]+ws[3];
}

__global__ void k_gscan(float* W) {
  if (blockIdx.x == 0 && threadIdx.x == 0) {
    double* P = (double*)(W + oGPRE);
    for (int b = 0; b < BB; ++b) {
      double a = 0.0;
      for (int c = 0; c < GCH; ++c) {
        P[b*GCH + c] = a;
        a += (double)W[oGSUM + (size_t)b*GCH + c];
      }
    }
  }
}

__global__ __launch_bounds__(256) void k_gapply(float* W) {
  int blk = blockIdx.x; int b = blk/GCH, c = blk%GCH; int tid = threadIdx.x;
  __shared__ float wss[4];
  __shared__ float lastw[4];
  const float* f0r = W + oF0 + (size_t)b*FRM;
  const float* oqr = W + oOQ + (size_t)b*FRM;
  float* grow = W + oGLOT + (size_t)b*TLEN;
  double P = ((const double*)(W + oGPRE))[b*GCH + c];
  int i0 = c*4096 + tid*16;
  int lane = tid & 63, wv = tid >> 6;
  float v[16]; float ts = 0.f;
  #pragma unroll
  for (int j = 0; j < 16; ++j) {
    int i = i0 + j;
    float x = (i < TLEN) ? interpF(f0r, i)*(1.0f/SRF) : 0.f;
    v[j] = x; ts += x;
  }
  // inclusive scan of ts across the block
  float sc = ts;
  #pragma unroll
  for (int off = 1; off < 64; off <<= 1) {
    float o = __shfl_up(sc, off, 64);
    if (lane >= off) sc += o;
  }
  if (lane == 63) wss[wv] = sc;
  __syncthreads();
  float wpre = 0.f;
  for (int q = 0; q < wv; ++q) wpre += wss[q];
  double ph0 = P + (double)(wpre + sc - ts);   // exclusive prefix for this thread
  float run = 0.f; float gq[16];
  #pragma unroll
  for (int j = 0; j < 16; ++j) {
    int i = i0 + j;
    run += v[j];
    float ph = (float)(ph0 + (double)run);
    gq[j] = gwave(ph, interpF(oqr, min(i, TLEN-1)));
  }
  // previous sample's g
  float prev = __shfl_up(gq[15], 1, 64);
  if (lane == 63) lastw[wv] = gq[15];
  __syncthreads();
  if (lane == 0) {
    if (wv > 0) prev = lastw[wv - 1];
    else if (i0 > 0) prev = gwave((float)P, interpF(oqr, i0 - 1));
    else prev = 0.f;
  }
  #pragma unroll
  for (int j = 0; j < 16; ++j) {
    int i = i0 + j;
    if (i < TLEN) {
      float gl = (j == 0) ? prev : gq[j-1];
      grow[i] = (i == 0) ? 0.f : (gq[j] - gl);
    }
  }
}

// ---------------- fused STFT->filter->ISTFT OLA ----------------
__global__ __launch_bounds__(256) void k_filtsynth(float* W) {
  int blk = blockIdx.x; int b = blk/FRM, f = blk%FRM; int tid = threadIdx.x;
  __shared__ float2 cG[1024], cN[1024];
  __shared__ float fvt[65], fnf[65];
  const float* grow = W + oGLOT + (size_t)b*TLEN;
  const float* nrow = W + oNOISE + (size_t)b*TLEN;
  const float2* tw = (const float2*)(W + oTW);
  for (int i = tid; i < 1024; i += 256) {
    int si = mirror_idx(f*256 + i - 512);
    float wv = W[oWIN + i];
    int pos = __brev((unsigned)i) >> 22;
    cG[pos] = make_float2(grow[si]*wv, 0.f);
    cN[pos] = make_float2(nrow[si]*wv, 0.f);
  }
  if (tid < 65) {
    fvt[tid] = W[oVT + ((size_t)b*FRM + f)*65 + tid];
    fnf[tid] = W[oNF + ((size_t)b*FRM + f)*65 + tid];
  }
  __syncthreads();
  fft2<10,1>(cG, tw, tid, 256, false);
  fft2<10,1>(cN, tw, tid, 256, false);
  for (int k = tid; k < 1024; k += 256) {
    int kp = min(k, 1024 - k);
    float fv = interp65(fvt, kp);
    float fn = interp65(fnf, kp);
    float2 zg = cG[k], zn = cN[k];
    cG[k] = make_float2(zg.x*fv + zn.x*fn, zg.y*fv + zn.y*fn);
  }
  __syncthreads();
  for (int i = tid; i < 1024; i += 256) {
    int jj = __brev((unsigned)i) >> 22;
    if (jj > i) { float2 t2 = cG[i]; cG[i] = cG[jj]; cG[jj] = t2; }
  }
  __syncthreads();
  fft2<10,1>(cG, tw, tid, 256, true);
  float* arow = W + oACC + (size_t)b*ACCLEN + (size_t)f*256;
  for (int i = tid; i < 1024; i += 256) {
    float xv = cG[i].x*(1.0f/1024.0f)*W[oWIN + i];
    atomicAdd(arow + i, xv);
  }
}

// ---------------- dry ----------------
__global__ void k_dry(float* W, float* dout) {
  size_t id = (size_t)blockIdx.x*256 + threadIdx.x;
  if (id >= (size_t)BB*NCONV) return;
  int b = (int)(id / NCONV);
  int n = (int)(id % NCONV);
  float dv = 0.f;
  if (n < TLEN) {
    float val = W[oACC + (size_t)b*ACCLEN + 512 + n] * W[oWSQI + 512 + n];
    const float* lrow = W + oLOUD + (size_t)b*FRM;
    float pos = ((float)n + 0.5f) * (626.0f/160000.0f) - 0.5f;
    pos = fminf(fmaxf(pos, 0.0f), 625.0f);
    int lo = (int)floorf(pos);
    int hi = min(lo + 1, 625);
    float w = pos - (float)lo;
    float a0 = exp10f(lrow[lo]*0.05f);
    float a1 = exp10f(lrow[hi]*0.05f);
    float ampu = a0*(1.0f - w) + a1*w;
    dv = val*ampu;
    dout[(size_t)BB*TLEN + (size_t)b*TLEN + n] = dv;
  }
  ((float2*)(W + oCONVA))[id] = make_float2(dv, 0.f);
}

// ---------------- four-step FFT (N = 512*512) ----------------
__global__ __launch_bounds__(256) void k_conv_f1(const float* in, float* out,
                                                 const float* tw, const float* twf,
                                                 const float* twc) {
  int blk = blockIdx.x; int t = blk >> 9; int bcol = blk & 511; int tid = threadIdx.x;
  __shared__ float2 cb[512];
  const float2* src = (const float2*)in + (size_t)t*NCONV;
  for (int a = tid; a < 512; a += 256) {
    int pos = __brev((unsigned)a) >> 23;
    cb[pos] = src[(size_t)a*512 + bcol];
  }
  __syncthreads();
  fft2<9,2>(cb, (const float2*)tw, tid, 256, false);
  float2* dst = (float2*)out + (size_t)t*NCONV + (size_t)bcol*512;
  for (int k1 = tid; k1 < 512; k1 += 256) {
    unsigned m = (unsigned)bcol * (unsigned)k1;   // < 262144
    float2 tc = ((const float2*)twc)[m >> 9];
    float2 tf = ((const float2*)twf)[m & 511];
    float wr = tc.x*tf.x - tc.y*tf.y;
    float wi = tc.x*tf.y + tc.y*tf.x;
    float2 v = cb[k1];
    dst[k1] = make_float2(v.x*wr - v.y*wi, v.x*wi + v.y*wr);
  }
}

__global__ __launch_bounds__(256) void k_conv_f2(const float* in, float* out, const float* tw) {
  int blk = blockIdx.x; int t = blk >> 9; int k1 = blk & 511; int tid = threadIdx.x;
  __shared__ float2 cb[512];
  const float2* src = (const float2*)in + (size_t)t*NCONV;
  for (int bb2 = tid; bb2 < 512; bb2 += 256) {
    int pos = __brev((unsigned)bb2) >> 23;
    cb[pos] = src[(size_t)bb2*512 + k1];
  }
  __syncthreads();
  fft2<9,2>(cb, (const float2*)tw, tid, 256, false);
  float2* dst = (float2*)out + (size_t)t*NCONV;
  for (int k2 = tid; k2 < 512; k2 += 256) {
    dst[(size_t)k1 + 512*(size_t)k2] = cb[k2];
  }
}

__global__ void k_mul(float* W) {
  size_t id = (size_t)blockIdx.x*256 + threadIdx.x;
  if (id >= (size_t)BB*NCONV) return;
  size_t k = id % NCONV;
  float2* A = (float2*)(W + oCONVA);
  float2 a = A[id];
  float2 c = A[(size_t)8*NCONV + k];
  float pr = a.x*c.x - a.y*c.y;
  float pi = a.x*c.y + a.y*c.x;
  A[id] = make_float2(pr, -pi);
}

__global__ void k_wet(const float* W, float* dout) {
  size_t id = (size_t)blockIdx.x*256 + threadIdx.x;
  if (id >= (size_t)BB*TLEN) return;
  size_t b = id / TLEN, n = id % TLEN;
  dout[id] = ((const float2*)(W + oCONVA))[b*NCONV + n].x * (1.0f/262144.0f);
}

// ---------------- launch ----------------
extern "C" void kernel_launch(void* const* d_in, const int* in_sizes, int n_in,
                              void* d_out, int out_size, void* d_ws, size_t ws_size,
                              hipStream_t stream) {
  (void)in_sizes; (void)n_in; (void)out_size; (void)ws_size;
  const float* audio  = (const float*)d_in[0];
  const float* gender = (const float*)d_in[1];
  const float* age    = (const float*)d_in[2];
  const float* wih    = (const float*)d_in[3];
  const float* whh    = (const float*)d_in[4];
  const float* bih    = (const float*)d_in[5];
  const float* bhh    = (const float*)d_in[6];
  const float* projw  = (const float*)d_in[7];
  const float* projb  = (const float*)d_in[8];
  const float* w0     = (const float*)d_in[9];
  const float* b0     = (const float*)d_in[10];
  const float* g0     = (const float*)d_in[11];
  const float* e0     = (const float*)d_in[12];
  const float* w1     = (const float*)d_in[13];
  const float* b1     = (const float*)d_in[14];
  const float* g1     = (const float*)d_in[15];
  const float* e1     = (const float*)d_in[16];
  const float* w2     = (const float*)d_in[17];
  const float* b2     = (const float*)d_in[18];
  const float* g2     = (const float*)d_in[19];
  const float* e2     = (const float*)d_in[20];
  const float* oqw    = (const float*)d_in[21];
  const float* oqb    = (const float*)d_in[22];
  const float* vtw    = (const float*)d_in[23];
  const float* vtb    = (const float*)d_in[24];
  const float* nfw    = (const float*)d_in[25];
  const float* nfb    = (const float*)d_in[26];
  const float* ir     = (const float*)d_in[27];
  float* W = (float*)d_ws;
  float* dout = (float*)d_out;

  k_init<<<(int)((INIT_TOTAL + 255)/256), 256, 0, stream>>>(W, wih, w0, w1, w2, vtw, nfw, ir);
  k_stft_mel<<<NFRM, 256, 0, stream>>>(audio, W);
  k_melnorm<<<3, 256, 0, stream>>>(W);
  k_xp<<<(int)(((size_t)NFRM*768 + 255)/256), 256, 0, stream>>>(W, bih);
  k_mega<<<MEGA_BLOCKS, 512, 0, stream>>>(W, audio, whh, bhh);
  k_mlp<<<NFRM/8, 512, 0, stream>>>(W, gender, age, projw, projb,
                                    b0, g0, e0, b1, g1, e1, b2, g2, e2, oqw, oqb, vtb, nfb);
  k_gsum<<<BB*GCH, 256, 0, stream>>>(W);
  k_gscan<<<1, 64, 0, stream>>>(W);
  k_gapply<<<BB*GCH, 256, 0, stream>>>(W);
  k_filtsynth<<<NFRM, 256, 0, stream>>>(W);
  k_dry<<<(int)(((size_t)BB*NCONV + 255)/256), 256, 0, stream>>>(W, dout);
  k_conv_f1<<<9*512, 256, 0, stream>>>(W + oCONVA, W + oCONVB, W + oTW, W + oTWF, W + oTWC);
  k_conv_f2<<<9*512, 256, 0, stream>>>(W + oCONVB, W + oCONVA, W + oTW);
  k_mul<<<(int)(((size_t)BB*NCONV + 255)/256), 256, 0, stream>>>(W);
  k_conv_f1<<<8*512, 256, 0, stream>>>(W + oCONVA, W + oCONVB, W + oTW, W + oTWF, W + oTWC);
  k_conv_f2<<<8*512, 256, 0, stream>>>(W + oCONVB, W + oCONVA, W + oTW);
  k_wet<<<(int)(((size_t)BB*TLEN + 255)/256), 256, 0, stream>>>(W, dout);
}

// Round 9
// 2229.496 us; speedup vs baseline: 1.2440x; 1.1041x over previous
//
#include <hip/hip_runtime.h>
#include <math.h>

#define SRF 16000.0f
#define HOP 256
#define FRM 626
#define BB 8
#define TLEN 160000
#define NFRM (BB*FRM)
#define NCONV 262144
#define ACCLEN 161024
#define GCH 40            // glottal chunks per batch (40*4096 >= 160000)

// ---------------- workspace layout (float offsets) ----------------
constexpr size_t oWIN   = 0;                       // 1024
constexpr size_t oTW    = oWIN + 1024;             // 1024 (512 complex, angle -2pi r/1024)
constexpr size_t oDIAG  = oTW + 1024;              // 16 (unused)
constexpr size_t oTWF   = oDIAG + 16;              // 1024 (512 complex, angle -2pi r/262144)
constexpr size_t oTWC   = oTWF + 1024;             // 1024 (512 complex, angle -2pi r/512)
constexpr size_t oAW    = oTWC + 1024;             // 513
constexpr size_t oMELFB = oAW + 513;               // 41040
constexpr size_t oWSQI  = oMELFB + 513*80;         // 161024
constexpr size_t oWIHT  = oWSQI + ACCLEN;          // 61440
constexpr size_t oW0T   = oWIHT + 80*768;          // 10752
constexpr size_t oW1T   = oW0T + 21*512;           // 262144
constexpr size_t oW2T   = oW1T + 512*512;          // 262144
constexpr size_t oVTT   = oW2T + 512*512;          // 33280
constexpr size_t oNFT   = oVTT + 512*65;           // 33280
constexpr size_t oF0    = oNFT + 512*65;           // 5008
constexpr size_t oLOUD  = oF0 + NFRM;              // 5008
constexpr size_t oOQ    = oLOUD + NFRM;            // 5008
constexpr size_t oVT    = oOQ + NFRM;              // 325520
constexpr size_t oNF    = oVT + (size_t)NFRM*65;   // 325520
constexpr size_t oGLOT  = oNF + (size_t)NFRM*65;   // 1280000
constexpr size_t oNOISE = oGLOT + (size_t)BB*TLEN; // 1280000
constexpr size_t oACC   = oNOISE + (size_t)BB*TLEN;// 1288192
constexpr size_t oCONVA = oACC + (size_t)BB*ACCLEN;// 4718592
constexpr size_t oEND   = oCONVA + (size_t)9*NCONV*2;
constexpr size_t oXP    = oEND;                    // NFRM*768 dedicated
constexpr size_t oGSUM  = oXP + (size_t)NFRM*768;  // BB*GCH
constexpr size_t oGPRE  = oGSUM + 320;             // BB*GCH doubles
constexpr size_t oEND2  = oGPRE + 640;
// overlays (lifetime-checked):
constexpr size_t oCONVB = oWSQI;                      // conv scratch; WSQI..ACC dead at conv time
constexpr size_t oMEL = oCONVA;                       // dead before k_dry packs CONVA
constexpr size_t oHS  = oMEL + (size_t)NFRM*80;       // ends well below ir slot

// init task counts
constexpr long R_WIN=1024, R_TW=512, R_TWF=512, R_TWC=512, R_AW=513, R_MELFB=41040,
  R_WSQI=161024, R_WIHT=61440, R_W0T=10752, R_W1T=262144, R_W2T=262144,
  R_VTT=33280, R_NFT=33280, R_IR=NCONV;
constexpr long INIT_TOTAL = R_WIN+R_TW+R_TWF+R_TWC+R_AW+R_MELFB+R_WSQI+R_WIHT+R_W0T+
  R_W1T+R_W2T+R_VTT+R_NFT+R_IR;

// mega-kernel block roles
constexpr int NOISEB = 313;
constexpr int ZACCB  = 315;
constexpr int MEGA_BLOCKS = 1 + NFRM + NOISEB + ZACCB;

typedef float f32x4 __attribute__((ext_vector_type(4)));
typedef __bf16 bf16x8 __attribute__((ext_vector_type(8)));
typedef short short8 __attribute__((ext_vector_type(8)));
#define MFMA_BF16 __builtin_amdgcn_mfma_f32_16x16x32_bf16

// ---------------- helpers ----------------
__device__ inline int mirror_idx(int j) {
  if (j < 0) j = -j;
  if (j >= TLEN) j = 2*TLEN - 2 - j;
  return j;
}
__device__ inline float sigm(float x) { return 1.0f/(1.0f + expf(-x)); }
__device__ inline unsigned short f2bf(float x) {
  unsigned u = __float_as_uint(x);
  return (unsigned short)((u + 0x7FFFu + ((u >> 16) & 1u)) >> 16);
}
__device__ inline float tanh_fast(float x) {
  return 1.0f - 2.0f/(__expf(2.0f*x) + 1.0f);
}

__device__ inline float interpF(const float* v, int i) {
  float pos = ((float)i + 0.5f) * (626.0f/160000.0f) - 0.5f;
  pos = fminf(fmaxf(pos, 0.0f), 625.0f);
  int lo = (int)floorf(pos);
  int hi = min(lo + 1, 625);
  float w = pos - (float)lo;
  return v[lo]*(1.0f - w) + v[hi]*w;
}
__device__ inline float interp65(const float* v, int k) {
  float pos = ((float)k + 0.5f) * (65.0f/513.0f) - 0.5f;
  pos = fminf(fmaxf(pos, 0.0f), 64.0f);
  int lo = (int)floorf(pos);
  int hi = min(lo + 1, 64);
  float w = pos - (float)lo;
  return v[lo]*(1.0f - w) + v[hi]*w;
}
__device__ inline float gwave(float ph, float oqu) {
  float p = ph - floorf(ph);
  float oqc = fminf(fmaxf(oqu, 0.1f), 0.9f);
  float pulse = 0.5f*(1.0f - cosf(3.14159265358979f * p / (oqc + 1e-8f)));
  float gs = 1.0f/(1.0f + __expf(-(oqc - p)*100.0f));
  return pulse*gs;
}

// radix-2 DIT FFT in LDS on interleaved complex; input at bit-reversed positions.
template<int LOGN, int TS>
__device__ inline void fft2(float2* c, const float2* tw, int tid, int nthr, bool inv) {
  constexpr int N = 1 << LOGN;
  for (int s = 1; s <= LOGN; ++s) {
    const int half = 1 << (s-1);
    const int tstep = (N >> s) * TS;
    for (int bf = tid; bf < (N>>1); bf += nthr) {
      int jj = bf & (half-1);
      int i0 = ((bf >> (s-1)) << s) + jj;
      int i1 = i0 + half;
      float2 wv = tw[jj*tstep];
      float wi = inv ? -wv.y : wv.y;
      float2 u = c[i0], v = c[i1];
      float tr  = v.x*wv.x - v.y*wi;
      float tci = v.x*wi  + v.y*wv.x;
      c[i0] = make_float2(u.x + tr, u.y + tci);
      c[i1] = make_float2(u.x - tr, u.y - tci);
    }
    __syncthreads();
  }
}

// threefry2x32, canonical 20-round schedule
__device__ inline void threefry2x32(unsigned k0, unsigned k1, unsigned x0, unsigned x1,
                                    unsigned& o0, unsigned& o1) {
  unsigned ks2 = k0 ^ k1 ^ 0x1BD11BDAu;
  x0 += k0; x1 += k1;
#define TF_R(r) { x0 += x1; x1 = (x1<<(r)) | (x1>>(32-(r))); x1 ^= x0; }
  TF_R(13) TF_R(15) TF_R(26) TF_R(6)
  x0 += k1; x1 += ks2 + 1u;
  TF_R(17) TF_R(29) TF_R(16) TF_R(24)
  x0 += ks2; x1 += k0 + 2u;
  TF_R(13) TF_R(15) TF_R(26) TF_R(6)
  x0 += k0; x1 += k1 + 3u;
  TF_R(17) TF_R(29) TF_R(16) TF_R(24)
  x0 += k1; x1 += ks2 + 4u;
  TF_R(13) TF_R(15) TF_R(26) TF_R(6)
  x0 += ks2; x1 += k0 + 5u;
#undef TF_R
  o0 = x0; o1 = x1;
}

__device__ inline float erfinv_f(float x) { // XLA f32 ErfInv (Giles)
  float w = -log1pf(-x*x);
  float p;
  if (w < 5.0f) {
    w = w - 2.5f;
    p = 2.81022636e-08f;
    p = fmaf(p, w, 3.43273939e-07f);
    p = fmaf(p, w, -3.5233877e-06f);
    p = fmaf(p, w, -4.39150654e-06f);
    p = fmaf(p, w, 0.00021858087f);
    p = fmaf(p, w, -0.00125372503f);
    p = fmaf(p, w, -0.00417768164f);
    p = fmaf(p, w, 0.246640727f);
    p = fmaf(p, w, 1.50140941f);
  } else {
    w = sqrtf(w) - 3.0f;
    p = -0.000200214257f;
    p = fmaf(p, w, 0.000100950558f);
    p = fmaf(p, w, 0.00134934322f);
    p = fmaf(p, w, -0.00367342844f);
    p = fmaf(p, w, 0.00573950773f);
    p = fmaf(p, w, -0.0076224613f);
    p = fmaf(p, w, 0.00943887047f);
    p = fmaf(p, w, 1.00167406f);
    p = fmaf(p, w, 2.83297682f);
  }
  return p*x;
}
__device__ inline float normal_from_bits(unsigned bits) {
  float f = __uint_as_float((bits >> 9) | 0x3F800000u) - 1.0f;
  float x = fmaxf(-0.99999994f, fmaf(f, 1.99999994f, -0.99999994f));
  return 1.41421356237f * erfinv_f(x);
}

__device__ inline double mel_fpt(int j) {
  double mmax = 2595.0 * log10(1.0 + 8000.0/700.0);
  return 700.0 * (pow(10.0, (mmax * (double)j / 81.0) / 2595.0) - 1.0);
}

// ---------------- init ----------------
__global__ void k_init(float* W, const float* wih, const float* w0,
                       const float* w1, const float* w2, const float* vtw, const float* nfw,
                       const float* ir) {
  long id = (long)blockIdx.x*256 + threadIdx.x;
  if (id < R_WIN) {
    double w = 0.5 - 0.5*cos(2.0*M_PI*(double)id/1024.0);
    W[oWIN+id] = (float)w; return;
  } id -= R_WIN;
  if (id < R_TW) {
    double a = -2.0*M_PI*(double)id/1024.0;
    W[oTW+2*id] = (float)cos(a); W[oTW+2*id+1] = (float)sin(a); return;
  } id -= R_TW;
  if (id < R_TWF) {
    double a = -2.0*M_PI*(double)id/262144.0;
    W[oTWF+2*id] = (float)cos(a); W[oTWF+2*id+1] = (float)sin(a); return;
  } id -= R_TWF;
  if (id < R_TWC) {
    double a = -2.0*M_PI*(double)id/512.0;
    W[oTWC+2*id] = (float)cos(a); W[oTWC+2*id+1] = (float)sin(a); return;
  } id -= R_TWC;
  if (id < R_AW) {
    double fr = (double)id*(8000.0/512.0); double fsq = fr*fr;
    double num = 12194.217*12194.217*fsq*fsq;
    double den = (fsq+20.6*20.6)*(fsq+107.7*107.7)*(fsq+737.9*737.9)*sqrt(fsq+12194.217*12194.217) + 1e-8;
    W[oAW+id] = (float)(num/den); return;
  } id -= R_AW;
  if (id < R_MELFB) {
    int k = (int)(id/80), m = (int)(id%80);
    double fk = (double)k*(8000.0/512.0);
    double f0p = mel_fpt(m), f1p = mel_fpt(m+1), f2p = mel_fpt(m+2);
    double lower = (fk - f0p)/(f1p - f0p);
    double upper = (f2p - fk)/(f2p - f1p);
    double v = fmax(0.0, fmin(lower, upper));
    W[oMELFB+id] = (float)v; return;
  } id -= R_MELFB;
  if (id < R_WSQI) {
    int t = (int)id;
    int n1 = t/256; if (n1 > 625) n1 = 625;
    int n0t = t - 1023 + 255; int n0 = (n0t > 0) ? n0t/256 : 0;
    double s = 0.0;
    for (int n = n0; n <= n1; ++n) {
      int o = t - n*256;
      double wv = 0.5 - 0.5*cos(2.0*M_PI*(double)o/1024.0);
      s += wv*wv;
    }
    float sf = (float)s;
    W[oWSQI+t] = (sf > 1e-11f) ? (1.0f/sf) : 1.0f; return;
  } id -= R_WSQI;
  if (id < R_WIHT) { long k = id/768, g = id%768; W[oWIHT+id] = wih[g*80+k];  return; } id -= R_WIHT;
  if (id < R_W0T)  { long d = id/512, j = id%512; W[oW0T+id] = w0[j*21+d];   return; } id -= R_W0T;
  if (id < R_W1T)  { long k = id/512, j = id%512; W[oW1T+id] = w1[j*512+k];  return; } id -= R_W1T;
  if (id < R_W2T)  { long k = id/512, j = id%512; W[oW2T+id] = w2[j*512+k];  return; } id -= R_W2T;
  if (id < R_VTT)  { long k = id/65,  m = id%65;  W[oVTT+id] = vtw[m*512+k]; return; } id -= R_VTT;
  if (id < R_NFT)  { long k = id/65,  m = id%65;  W[oNFT+id] = nfw[m*512+k]; return; } id -= R_NFT;
  if (id < R_IR) {
    size_t base = oCONVA + 2*((size_t)8*NCONV + id);
    W[base] = (id < 8000) ? ir[id] : 0.0f; W[base+1] = 0.0f; return;
  }
}

// ---------------- STFT of audio + loud + mel (sparse mel) ----------------
__global__ __launch_bounds__(256) void k_stft_mel(const float* audio, float* W) {
  int blk = blockIdx.x; int b = blk/FRM, f = blk%FRM; int tid = threadIdx.x;
  __shared__ float2 cb[1024];
  __shared__ float spec[513];
  __shared__ float redbuf[4];
  const float* arow = audio + (size_t)b*TLEN;
  const float2* tw = (const float2*)(W + oTW);
  for (int i = tid; i < 1024; i += 256) {
    float v = arow[mirror_idx(f*256 + i - 512)] * W[oWIN + i];
    int pos = __brev((unsigned)i) >> 22;
    cb[pos] = make_float2(v, 0.f);
  }
  __syncthreads();
  fft2<10,1>(cb, tw, tid, 256, false);
  for (int k = tid; k < 513; k += 256) { float2 z = cb[k]; spec[k] = z.x*z.x + z.y*z.y; }
  __syncthreads();
  float part = 0.f;
  for (int k = tid; k < 513; k += 256) part += (spec[k] + 1e-8f) * W[oAW + k];
  for (int off = 32; off; off >>= 1) part += __shfl_down(part, off, 64);
  if ((tid & 63) == 0) redbuf[tid >> 6] = part;
  __syncthreads();
  if (tid == 0) {
    float s = redbuf[0]+redbuf[1]+redbuf[2]+redbuf[3];
    W[oLOUD + blk] = 10.0f * log10f(s / 513.0f);
  }
  for (int m = tid; m < 80; m += 256) {
    // sparse band: melfb[m] nonzero only strictly inside (f0p, f2p); zero-weight bins
    // contribute exactly 0.0f so restricting the sum is bit-identical.
    double f0p = mel_fpt(m), f2p = mel_fpt(m + 2);
    int klo = (int)(f0p * (512.0/8000.0)); if (klo < 0) klo = 0;
    int khi = (int)(f2p * (512.0/8000.0)) + 1; if (khi > 512) khi = 512;
    float s = 0.f;
    for (int k = klo; k <= khi; ++k) s += spec[k]*W[oMELFB + (size_t)k*80 + m];
    W[oMEL + (size_t)blk*80 + m] = logf(s + 1e-5f);
  }
}

// ---------------- mel normalization over time ----------------
__global__ void k_melnorm(float* W) {
  int id = blockIdx.x*256 + threadIdx.x;
  if (id >= BB*80) return;
  int b = id/80, m = id%80;
  double s = 0.0, ss = 0.0;
  for (int f = 0; f < FRM; ++f) {
    double v = W[oMEL + ((size_t)b*FRM + f)*80 + m];
    s += v; ss += v*v;
  }
  double mean = s/FRM;
  double var = ss/FRM - mean*mean;
  float mu = (float)mean;
  float rstd = (float)(1.0/sqrt(var + 1e-5));
  for (int f = 0; f < FRM; ++f) {
    size_t idx = oMEL + ((size_t)b*FRM + f)*80 + m;
    W[idx] = (W[idx] - mu)*rstd;
  }
}

// ---------------- GRU input precompute ----------------
__global__ void k_xp(float* W, const float* bih) {
  size_t id = (size_t)blockIdx.x*256 + threadIdx.x;
  if (id >= (size_t)NFRM*768) return;
  int g = (int)(id % 768);
  size_t q = id / 768;
  const float* mrow = W + oMEL + q*80;
  float acc = bih[g];
  for (int k = 0; k < 80; ++k) acc = fmaf(mrow[k], W[oWIHT + (size_t)k*768 + g], acc);
  W[oXP + q*768 + g] = acc;
}

// ================ MEGA kernel: GRU (block 0) + f0 + noise + zacc ================
// GRU: wave w owns cols 96w..96w+95 (tiles 6w..6w+5); tiles 0..4 in regs, 5 in LDS.
// Gate exchange via TRANSPOSED sGT[768][12]: b128 writes (4 rows/lane) + b128 reads
// (4 batches/thread; batch mapping 4*bbase+j).
__global__ __launch_bounds__(512, 2) void k_mega(float* W, const float* audio,
                                                 const float* whh, const float* bhh) {
  __shared__ unsigned short sB[32768];   // 64 KB
  __shared__ unsigned short sA[4096];    // 8 KB
  __shared__ float sGT[9216];            // 36 KB transposed gate buf [col][12]
  __shared__ float fr4[4][1032];         // 16.5 KB (f0 role)
  __shared__ float wpow[8];
  __shared__ float wmax[8];
  __shared__ int   wmaxi[8];
  int tid = threadIdx.x;
  int blk = blockIdx.x;

  if (blk == 0) {
    // ---------------- GRU role ----------------
    int w = tid >> 6, l = tid & 63;
    const float* XP = W + oXP;
    float* HS = W + oHS;

    for (int idx = tid; idx < 32768; idx += 512) {
      int lcol = idx >> 8, k = idx & 255;
      int gcol = 96*(lcol >> 4) + 80 + (lcol & 15);
      sB[lcol*256 + (k ^ ((lcol & 7) << 3))] = f2bf(whh[(size_t)gcol*256 + k]);
    }
    for (int idx = tid; idx < 4096; idx += 512) sA[idx] = 0;

    int cl = l & 15, khalf = (l >> 4) * 8;
    bf16x8 bw[40];
    #pragma unroll
    for (int t2 = 0; t2 < 5; ++t2) {
      int col = 96*w + 16*t2 + cl;
      #pragma unroll
      for (int kk = 0; kk < 8; ++kk) {
        const float* src = whh + (size_t)col*256 + kk*32 + khalf;
        short8 tmp;
        #pragma unroll
        for (int j = 0; j < 8; ++j) tmp[j] = (short)f2bf(src[j]);
        bw[t2*8 + kk] = __builtin_bit_cast(bf16x8, tmp);
      }
    }

    int g = tid & 255, bbase = tid >> 8;   // batches 4*bbase + j
    float bh_r = bhh[g], bh_z = bhh[256 + g], bh_n = bhh[512 + g];
    float hprev[4] = {0.f, 0.f, 0.f, 0.f};
    int aXor = (cl & 7) << 3;
    int lcol5 = w*16 + cl;
    int rowg = l >> 4;
    int colb = 96*w + cl;          // tile-0 col for this lane
    int gtw = colb*12 + rowg*4;    // write base (tile t: + t*16*12)
    int gtr0 = g*12 + 4*bbase;     // read bases
    int gtr1 = (256 + g)*12 + 4*bbase;
    int gtr2 = (512 + g)*12 + 4*bbase;

    __syncthreads();

#define LDA(kk) (*(const bf16x8*)&sA[(cl)*256 + (((kk)*32 + khalf) ^ aXor)])
#define LDB(kk) (*(const bf16x8*)&sB[(lcol5)*256 + (((kk)*32 + khalf) ^ aXor)])
#define STEPK(A_, kk) \
      c0 = MFMA_BF16(A_, bw[0*8+(kk)], c0, 0, 0, 0); \
      c1 = MFMA_BF16(A_, bw[1*8+(kk)], c1, 0, 0, 0); \
      c2 = MFMA_BF16(A_, bw[2*8+(kk)], c2, 0, 0, 0); \
      c3 = MFMA_BF16(A_, bw[3*8+(kk)], c3, 0, 0, 0); \
      c4 = MFMA_BF16(A_, bw[4*8+(kk)], c4, 0, 0, 0); \
      c5 = MFMA_BF16(A_, LDB(kk), c5, 0, 0, 0);

    for (int t = 0; t < FRM; ++t) {
      // xp loads issued at top, consumed after barrier (hidden under MFMA)
      float xr[4], xz[4], xn[4];
      #pragma unroll
      for (int j = 0; j < 4; ++j) {
        const float* xpp = XP + ((size_t)(4*bbase + j)*FRM + t)*768 + g;
        xr[j] = xpp[0]; xz[j] = xpp[256]; xn[j] = xpp[512];
      }
      f32x4 c0 = {0,0,0,0}, c1 = {0,0,0,0}, c2 = {0,0,0,0};
      f32x4 c3 = {0,0,0,0}, c4 = {0,0,0,0}, c5 = {0,0,0,0};
      bf16x8 a0 = LDA(0), a1 = LDA(1), a2 = LDA(2), a3 = LDA(3);
      STEPK(a0, 0) STEPK(a1, 1) STEPK(a2, 2) STEPK(a3, 3)
      a0 = LDA(4); a1 = LDA(5); a2 = LDA(6); a3 = LDA(7);
      STEPK(a0, 4) STEPK(a1, 5) STEPK(a2, 6) STEPK(a3, 7)
      // transposed b128 writes: lane covers rows rowg*4..rowg*4+3 of its col.
      // rowg 0,1 = batches 0..7 (needed); rowg 2 = zero rows into pad slots; rowg 3 skipped.
      if (rowg < 3) {
        *(f32x4*)&sGT[gtw + 0*192]  = c0;
        *(f32x4*)&sGT[gtw + 1*192]  = c1;
        *(f32x4*)&sGT[gtw + 2*192]  = c2;
        *(f32x4*)&sGT[gtw + 3*192]  = c3;
        *(f32x4*)&sGT[gtw + 4*192]  = c4;
        *(f32x4*)&sGT[gtw + 5*192]  = c5;
      }
      __syncthreads();
      f32x4 rv = *(const f32x4*)&sGT[gtr0];
      f32x4 zv = *(const f32x4*)&sGT[gtr1];
      f32x4 nv = *(const f32x4*)&sGT[gtr2];
      #pragma unroll
      for (int j = 0; j < 4; ++j) {
        int bb = 4*bbase + j;
        float r = 1.0f/(1.0f + __expf(-(xr[j] + rv[j] + bh_r)));
        float z = 1.0f/(1.0f + __expf(-(xz[j] + zv[j] + bh_z)));
        float nn = tanh_fast(xn[j] + r*(nv[j] + bh_n));
        float h = (1.0f - z)*nn + z*hprev[j];
        hprev[j] = h;
        HS[((size_t)bb*FRM + t)*256 + g] = h;
        sA[bb*256 + (g ^ ((bb & 7) << 3))] = f2bf(h);
      }
      __syncthreads();
    }
#undef LDA
#undef LDB
#undef STEPK
    return;
  }
  blk -= 1;

  if (blk < NFRM) {
    // ---------------- f0 role ----------------
    int b = blk/FRM, f = blk%FRM;
    const float* arow = audio + (size_t)b*TLEN;
    for (int idx = tid; idx < 4*1032; idx += 512) {
      int s = idx/1032, i = idx - s*1032;
      int j = i + s;
      fr4[s][i] = (j < 1024) ? arow[mirror_idx(f*256 + j - 512)] : 0.f;
    }
    __syncthreads();
    int lane = tid & 63, wv = tid >> 6;
    float p = 0.f;
    for (int i = tid; i < 1024; i += 512) { float x = fr4[0][i]; p += x*x; }
    for (int off = 32; off; off >>= 1) p += __shfl_down(p, off, 64);
    if (lane == 0) wpow[wv] = p;
    float vbest = -1e30f; int ibest = tid;
    if (tid < 304) {
      int lag = 16 + tid;
      int s = lag & 3, base = lag - s;
      int qmax = (1023 - lag) >> 2;
      float acc = 0.f;
      for (int q = 0; q <= qmax; ++q) {
        float4 u = *(const float4*)&fr4[0][4*q];
        float4 v = *(const float4*)&fr4[s][base + 4*q];
        acc += u.x*v.x + u.y*v.y + u.z*v.z + u.w*v.w;
      }
      vbest = acc;
    }
    for (int off = 32; off; off >>= 1) {
      float v2 = __shfl_down(vbest, off, 64);
      int i2 = __shfl_down(ibest, off, 64);
      if (v2 > vbest || (v2 == vbest && i2 < ibest)) { vbest = v2; ibest = i2; }
    }
    if (lane == 0) { wmax[wv] = vbest; wmaxi[wv] = ibest; }
    __syncthreads();
    if (tid == 0) {
      float ac0 = 0.f;
      #pragma unroll
      for (int q = 0; q < 8; ++q) ac0 += wpow[q];
      float bv = wmax[0]; int bi = wmaxi[0];
      #pragma unroll
      for (int q = 1; q < 8; ++q) {
        if (wmax[q] > bv || (wmax[q] == bv && wmaxi[q] < bi)) { bv = wmax[q]; bi = wmaxi[q]; }
      }
      float inv = 1.0f/(ac0 + 1e-8f);
      float best = bv*inv;
      W[oF0 + (size_t)blk] = (best < 0.3f) ? 0.0f : (SRF/(float)(bi + 16));
    }
    return;
  }
  blk -= NFRM;

  if (blk < NOISEB) {
    size_t base = (size_t)blk*4096;
    #pragma unroll
    for (int j = 0; j < 8; ++j) {
      size_t p = base + (size_t)j*512 + tid;
      if (p < (size_t)BB*TLEN) {
        unsigned o0, o1;
        threefry2x32(0u, 42u, 0u, (unsigned)p, o0, o1);
        W[oNOISE + p] = normal_from_bits(o0 ^ o1);
      }
    }
    return;
  }
  blk -= NOISEB;

  {
    size_t base = (size_t)blk*4096;
    #pragma unroll
    for (int j = 0; j < 8; ++j) {
      size_t p = base + (size_t)j*512 + tid;
      if (p < (size_t)BB*ACCLEN) W[oACC + p] = 0.0f;
    }
  }
}

// ---------------- MLP + heads (proj fused) ----------------
__device__ inline void ln_lrelu(float acc[8], float gj, float ej, float out[8][512],
                                float wred[8][8][2], float stat[8][2],
                                int tid, int lane, int wv, int j) {
  #pragma unroll
  for (int i = 0; i < 8; ++i) {
    float s = acc[i], ss = acc[i]*acc[i];
    for (int off = 32; off; off >>= 1) { s += __shfl_down(s, off, 64); ss += __shfl_down(ss, off, 64); }
    if (lane == 0) { wred[i][wv][0] = s; wred[i][wv][1] = ss; }
  }
  __syncthreads();
  if (tid < 8) {
    float s = 0.f, ss = 0.f;
    #pragma unroll
    for (int w = 0; w < 8; ++w) { s += wred[tid][w][0]; ss += wred[tid][w][1]; }
    float mean = s/512.0f;
    float var = ss/512.0f - mean*mean;
    stat[tid][0] = mean;
    stat[tid][1] = 1.0f/sqrtf(var + 1e-5f);
  }
  __syncthreads();
  #pragma unroll
  for (int i = 0; i < 8; ++i) {
    float v = (acc[i] - stat[i][0])*stat[i][1]*gj + ej;
    out[i][j] = (v >= 0.f) ? v : 0.1f*v;
  }
}

__global__ __launch_bounds__(512) void k_mlp(float* W, const float* gender, const float* age,
    const float* projw, const float* projb,
    const float* b0, const float* g0, const float* e0,
    const float* b1, const float* g1, const float* e1,
    const float* b2, const float* g2, const float* e2,
    const float* oqw, const float* oqb, const float* vtb, const float* nfb) {
  __shared__ float hbuf[8][256];
  __shared__ float in0[8][21];
  __shared__ float actA[8][512];
  __shared__ float actB[8][512];
  __shared__ float wred[8][8][2];
  __shared__ float stat[8][2];
  int tid = threadIdx.x; int q0 = blockIdx.x*8;
  for (int x = tid; x < 2048; x += 512) {
    int i = x >> 8, k = x & 255;
    hbuf[i][k] = W[oHS + ((size_t)(q0 + i))*256 + k];
  }
  __syncthreads();
  if (tid < 128) {
    int i = tid >> 4, zi = tid & 15;
    float a = projb[zi];
    for (int k = 0; k < 256; ++k) a = fmaf(hbuf[i][k], projw[zi*256 + k], a);
    in0[i][zi] = a;
  } else if (tid < 168) {
    int x = tid - 128; int i = x/5, d = 16 + x%5;
    int q = q0 + i; int b = q/FRM;
    float v;
    if (d == 16) v = (logf(W[oF0 + q] + 1e-5f) - 4.0f)*0.25f;
    else if (d == 17) v = W[oLOUD + q]/100.0f + 1.0f;
    else if (d == 18) v = gender[b*2];
    else if (d == 19) v = gender[b*2 + 1];
    else v = age[b];
    in0[i][d] = v;
  }
  __syncthreads();
  int j = tid, lane = tid & 63, wv = tid >> 6;
  float acc[8];
  #pragma unroll
  for (int i = 0; i < 8; ++i) acc[i] = b0[j];
  for (int d = 0; d < 21; ++d) {
    float w = W[oW0T + (size_t)d*512 + j];
    #pragma unroll
    for (int i = 0; i < 8; ++i) acc[i] = fmaf(in0[i][d], w, acc[i]);
  }
  ln_lrelu(acc, g0[j], e0[j], actA, wred, stat, tid, lane, wv, j);
  __syncthreads();
  #pragma unroll
  for (int i = 0; i < 8; ++i) acc[i] = b1[j];
  for (int k = 0; k < 512; ++k) {
    float w = W[oW1T + (size_t)k*512 + j];
    #pragma unroll
    for (int i = 0; i < 8; ++i) acc[i] = fmaf(actA[i][k], w, acc[i]);
  }
  ln_lrelu(acc, g1[j], e1[j], actB, wred, stat, tid, lane, wv, j);
  __syncthreads();
  #pragma unroll
  for (int i = 0; i < 8; ++i) acc[i] = b2[j];
  for (int k = 0; k < 512; ++k) {
    float w = W[oW2T + (size_t)k*512 + j];
    #pragma unroll
    for (int i = 0; i < 8; ++i) acc[i] = fmaf(actB[i][k], w, acc[i]);
  }
  ln_lrelu(acc, g2[j], e2[j], actA, wred, stat, tid, lane, wv, j);
  __syncthreads();
  for (int x = tid; x < 520; x += 512) {
    int i = x/65, m = x%65;
    float a = vtb[m], a2 = nfb[m];
    for (int k = 0; k < 512; ++k) {
      float h = actA[i][k];
      a  = fmaf(h, W[oVTT + (size_t)k*65 + m], a);
      a2 = fmaf(h, W[oNFT + (size_t)k*65 + m], a2);
    }
    W[oVT + (size_t)(q0+i)*65 + m] = sigm(a);
    W[oNF + (size_t)(q0+i)*65 + m] = sigm(a2);
  }
  if (tid < 8) {
    float a = oqb[0];
    for (int k = 0; k < 512; ++k) a = fmaf(actA[tid][k], oqw[k], a);
    W[oOQ + q0 + tid] = sigm(a);
  }
}

// ---------------- glottal: parallel 3-phase ----------------
__global__ __launch_bounds__(256) void k_gsum(float* W) {
  int blk = blockIdx.x; int b = blk/GCH, c = blk%GCH; int tid = threadIdx.x;
  __shared__ float ws[4];
  const float* f0r = W + oF0 + (size_t)b*FRM;
  int i0 = c*4096 + tid*16;
  float s = 0.f;
  #pragma unroll
  for (int j = 0; j < 16; ++j) {
    int i = i0 + j;
    if (i < TLEN) s += interpF(f0r, i)*(1.0f/SRF);
  }
  for (int off = 32; off; off >>= 1) s += __shfl_down(s, off, 64);
  if ((tid & 63) == 0) ws[tid >> 6] = s;
  __syncthreads();
  if (tid == 0) W[oGSUM + (size_t)b*GCH + c] = ws[0]+ws[1]+ws[2]+ws[3];
}

__global__ void k_gscan(float* W) {
  if (blockIdx.x == 0 && threadIdx.x == 0) {
    double* P = (double*)(W + oGPRE);
    for (int b = 0; b < BB; ++b) {
      double a = 0.0;
      for (int c = 0; c < GCH; ++c) {
        P[b*GCH + c] = a;
        a += (double)W[oGSUM + (size_t)b*GCH + c];
      }
    }
  }
}

__global__ __launch_bounds__(256) void k_gapply(float* W) {
  int blk = blockIdx.x; int b = blk/GCH, c = blk%GCH; int tid = threadIdx.x;
  __shared__ float wss[4];
  __shared__ float lastw[4];
  const float* f0r = W + oF0 + (size_t)b*FRM;
  const float* oqr = W + oOQ + (size_t)b*FRM;
  float* grow = W + oGLOT + (size_t)b*TLEN;
  double P = ((const double*)(W + oGPRE))[b*GCH + c];
  int i0 = c*4096 + tid*16;
  int lane = tid & 63, wv = tid >> 6;
  float v[16]; float ts = 0.f;
  #pragma unroll
  for (int j = 0; j < 16; ++j) {
    int i = i0 + j;
    float x = (i < TLEN) ? interpF(f0r, i)*(1.0f/SRF) : 0.f;
    v[j] = x; ts += x;
  }
  float sc = ts;
  #pragma unroll
  for (int off = 1; off < 64; off <<= 1) {
    float o = __shfl_up(sc, off, 64);
    if (lane >= off) sc += o;
  }
  if (lane == 63) wss[wv] = sc;
  __syncthreads();
  float wpre = 0.f;
  for (int q = 0; q < wv; ++q) wpre += wss[q];
  double ph0 = P + (double)(wpre + sc - ts);
  float run = 0.f; float gq[16];
  #pragma unroll
  for (int j = 0; j < 16; ++j) {
    int i = i0 + j;
    run += v[j];
    float ph = (float)(ph0 + (double)run);
    gq[j] = gwave(ph, interpF(oqr, min(i, TLEN-1)));
  }
  float prev = __shfl_up(gq[15], 1, 64);
  if (lane == 63) lastw[wv] = gq[15];
  __syncthreads();
  if (lane == 0) {
    if (wv > 0) prev = lastw[wv - 1];
    else if (i0 > 0) prev = gwave((float)P, interpF(oqr, i0 - 1));
    else prev = 0.f;
  }
  #pragma unroll
  for (int j = 0; j < 16; ++j) {
    int i = i0 + j;
    if (i < TLEN) {
      float gl = (j == 0) ? prev : gq[j-1];
      grow[i] = (i == 0) ? 0.f : (gq[j] - gl);
    }
  }
}

// ---------------- fused STFT->filter->ISTFT OLA ----------------
__global__ __launch_bounds__(256) void k_filtsynth(float* W) {
  int blk = blockIdx.x; int b = blk/FRM, f = blk%FRM; int tid = threadIdx.x;
  __shared__ float2 cG[1024], cN[1024];
  __shared__ float fvt[65], fnf[65];
  const float* grow = W + oGLOT + (size_t)b*TLEN;
  const float* nrow = W + oNOISE + (size_t)b*TLEN;
  const float2* tw = (const float2*)(W + oTW);
  for (int i = tid; i < 1024; i += 256) {
    int si = mirror_idx(f*256 + i - 512);
    float wv = W[oWIN + i];
    int pos = __brev((unsigned)i) >> 22;
    cG[pos] = make_float2(grow[si]*wv, 0.f);
    cN[pos] = make_float2(nrow[si]*wv, 0.f);
  }
  if (tid < 65) {
    fvt[tid] = W[oVT + ((size_t)b*FRM + f)*65 + tid];
    fnf[tid] = W[oNF + ((size_t)b*FRM + f)*65 + tid];
  }
  __syncthreads();
  fft2<10,1>(cG, tw, tid, 256, false);
  fft2<10,1>(cN, tw, tid, 256, false);
  for (int k = tid; k < 1024; k += 256) {
    int kp = min(k, 1024 - k);
    float fv = interp65(fvt, kp);
    float fn = interp65(fnf, kp);
    float2 zg = cG[k], zn = cN[k];
    cG[k] = make_float2(zg.x*fv + zn.x*fn, zg.y*fv + zn.y*fn);
  }
  __syncthreads();
  for (int i = tid; i < 1024; i += 256) {
    int jj = __brev((unsigned)i) >> 22;
    if (jj > i) { float2 t2 = cG[i]; cG[i] = cG[jj]; cG[jj] = t2; }
  }
  __syncthreads();
  fft2<10,1>(cG, tw, tid, 256, true);
  float* arow = W + oACC + (size_t)b*ACCLEN + (size_t)f*256;
  for (int i = tid; i < 1024; i += 256) {
    float xv = cG[i].x*(1.0f/1024.0f)*W[oWIN + i];
    atomicAdd(arow + i, xv);
  }
}

// ---------------- dry ----------------
__global__ void k_dry(float* W, float* dout) {
  size_t id = (size_t)blockIdx.x*256 + threadIdx.x;
  if (id >= (size_t)BB*NCONV) return;
  int b = (int)(id / NCONV);
  int n = (int)(id % NCONV);
  float dv = 0.f;
  if (n < TLEN) {
    float val = W[oACC + (size_t)b*ACCLEN + 512 + n] * W[oWSQI + 512 + n];
    const float* lrow = W + oLOUD + (size_t)b*FRM;
    float pos = ((float)n + 0.5f) * (626.0f/160000.0f) - 0.5f;
    pos = fminf(fmaxf(pos, 0.0f), 625.0f);
    int lo = (int)floorf(pos);
    int hi = min(lo + 1, 625);
    float w = pos - (float)lo;
    float a0 = exp10f(lrow[lo]*0.05f);
    float a1 = exp10f(lrow[hi]*0.05f);
    float ampu = a0*(1.0f - w) + a1*w;
    dv = val*ampu;
    dout[(size_t)BB*TLEN + (size_t)b*TLEN + n] = dv;
  }
  ((float2*)(W + oCONVA))[id] = make_float2(dv, 0.f);
}

// ---------------- four-step FFT (N = 512*512) ----------------
__global__ __launch_bounds__(256) void k_conv_f1(const float* in, float* out,
                                                 const float* tw, const float* twf,
                                                 const float* twc) {
  int blk = blockIdx.x; int t = blk >> 9; int bcol = blk & 511; int tid = threadIdx.x;
  __shared__ float2 cb[512];
  const float2* src = (const float2*)in + (size_t)t*NCONV;
  for (int a = tid; a < 512; a += 256) {
    int pos = __brev((unsigned)a) >> 23;
    cb[pos] = src[(size_t)a*512 + bcol];
  }
  __syncthreads();
  fft2<9,2>(cb, (const float2*)tw, tid, 256, false);
  float2* dst = (float2*)out + (size_t)t*NCONV + (size_t)bcol*512;
  for (int k1 = tid; k1 < 512; k1 += 256) {
    unsigned m = (unsigned)bcol * (unsigned)k1;   // < 262144
    float2 tc = ((const float2*)twc)[m >> 9];
    float2 tf = ((const float2*)twf)[m & 511];
    float wr = tc.x*tf.x - tc.y*tf.y;
    float wi = tc.x*tf.y + tc.y*tf.x;
    float2 v = cb[k1];
    dst[k1] = make_float2(v.x*wr - v.y*wi, v.x*wi + v.y*wr);
  }
}

__global__ __launch_bounds__(256) void k_conv_f2(const float* in, float* out, const float* tw) {
  int blk = blockIdx.x; int t = blk >> 9; int k1 = blk & 511; int tid = threadIdx.x;
  __shared__ float2 cb[512];
  const float2* src = (const float2*)in + (size_t)t*NCONV;
  for (int bb2 = tid; bb2 < 512; bb2 += 256) {
    int pos = __brev((unsigned)bb2) >> 23;
    cb[pos] = src[(size_t)bb2*512 + k1];
  }
  __syncthreads();
  fft2<9,2>(cb, (const float2*)tw, tid, 256, false);
  float2* dst = (float2*)out + (size_t)t*NCONV;
  for (int k2 = tid; k2 < 512; k2 += 256) {
    dst[(size_t)k1 + 512*(size_t)k2] = cb[k2];
  }
}

__global__ void k_mul(float* W) {
  size_t id = (size_t)blockIdx.x*256 + threadIdx.x;
  if (id >= (size_t)BB*NCONV) return;
  size_t k = id % NCONV;
  float2* A = (float2*)(W + oCONVA);
  float2 a = A[id];
  float2 c = A[(size_t)8*NCONV + k];
  float pr = a.x*c.x - a.y*c.y;
  float pi = a.x*c.y + a.y*c.x;
  A[id] = make_float2(pr, -pi);
}

__global__ void k_wet(const float* W, float* dout) {
  size_t id = (size_t)blockIdx.x*256 + threadIdx.x;
  if (id >= (size_t)BB*TLEN) return;
  size_t b = id / TLEN, n = id % TLEN;
  dout[id] = ((const float2*)(W + oCONVA))[b*NCONV + n].x * (1.0f/262144.0f);
}

// ---------------- launch ----------------
extern "C" void kernel_launch(void* const* d_in, const int* in_sizes, int n_in,
                              void* d_out, int out_size, void* d_ws, size_t ws_size,
                              hipStream_t stream) {
  (void)in_sizes; (void)n_in; (void)out_size; (void)ws_size;
  const float* audio  = (const float*)d_in[0];
  const float* gender = (const float*)d_in[1];
  const float* age    = (const float*)d_in[2];
  const float* wih    = (const float*)d_in[3];
  const float* whh    = (const float*)d_in[4];
  const float* bih    = (const float*)d_in[5];
  const float* bhh    = (const float*)d_in[6];
  const float* projw  = (const float*)d_in[7];
  const float* projb  = (const float*)d_in[8];
  const float* w0     = (const float*)d_in[9];
  const float* b0     = (const float*)d_in[10];
  const float* g0     = (const float*)d_in[11];
  const float* e0     = (const float*)d_in[12];
  const float* w1     = (const float*)d_in[13];
  const float* b1     = (const float*)d_in[14];
  const float* g1     = (const float*)d_in[15];
  const float* e1     = (const float*)d_in[16];
  const float* w2     = (const float*)d_in[17];
  const float* b2     = (const float*)d_in[18];
  const float* g2     = (const float*)d_in[19];
  const float* e2     = (const float*)d_in[20];
  const float* oqw    = (const float*)d_in[21];
  const float* oqb    = (const float*)d_in[22];
  const float* vtw    = (const float*)d_in[23];
  const float* vtb    = (const float*)d_in[24];
  const float* nfw    = (const float*)d_in[25];
  const float* nfb    = (const float*)d_in[26];
  const float* ir     = (const float*)d_in[27];
  float* W = (float*)d_ws;
  float* dout = (float*)d_out;

  k_init<<<(int)((INIT_TOTAL + 255)/256), 256, 0, stream>>>(W, wih, w0, w1, w2, vtw, nfw, ir);
  k_stft_mel<<<NFRM, 256, 0, stream>>>(audio, W);
  k_melnorm<<<3, 256, 0, stream>>>(W);
  k_xp<<<(int)(((size_t)NFRM*768 + 255)/256), 256, 0, stream>>>(W, bih);
  k_mega<<<MEGA_BLOCKS, 512, 0, stream>>>(W, audio, whh, bhh);
  k_mlp<<<NFRM/8, 512, 0, stream>>>(W, gender, age, projw, projb,
                                    b0, g0, e0, b1, g1, e1, b2, g2, e2, oqw, oqb, vtb, nfb);
  k_gsum<<<BB*GCH, 256, 0, stream>>>(W);
  k_gscan<<<1, 64, 0, stream>>>(W);
  k_gapply<<<BB*GCH, 256, 0, stream>>>(W);
  k_filtsynth<<<NFRM, 256, 0, stream>>>(W);
  k_dry<<<(int)(((size_t)BB*NCONV + 255)/256), 256, 0, stream>>>(W, dout);
  k_conv_f1<<<9*512, 256, 0, stream>>>(W + oCONVA, W + oCONVB, W + oTW, W + oTWF, W + oTWC);
  k_conv_f2<<<9*512, 256, 0, stream>>>(W + oCONVB, W + oCONVA, W + oTW);
  k_mul<<<(int)(((size_t)BB*NCONV + 255)/256), 256, 0, stream>>>(W);
  k_conv_f1<<<8*512, 256, 0, stream>>>(W + oCONVA, W + oCONVB, W + oTW, W + oTWF, W + oTWC);
  k_conv_f2<<<8*512, 256, 0, stream>>>(W + oCONVB, W + oCONVA, W + oTW);
  k_wet<<<(int)(((size_t)BB*TLEN + 255)/256), 256, 0, stream>>>(W, dout);
}

// Round 10
// 2198.717 us; speedup vs baseline: 1.2614x; 1.0140x over previous
//
#include <hip/hip_runtime.h>
#include <math.h>

#define SRF 16000.0f
#define HOP 256
#define FRM 626
#define BB 8
#define TLEN 160000
#define NFRM (BB*FRM)
#define NCONV 262144
#define ACCLEN 161024
#define GCH 40            // glottal chunks per batch (40*4096 >= 160000)

// ---------------- workspace layout (float offsets) ----------------
constexpr size_t oWIN   = 0;                       // 1024
constexpr size_t oTW    = oWIN + 1024;             // 1024 (512 complex, angle -2pi r/1024)
constexpr size_t oDIAG  = oTW + 1024;              // 16 (unused)
constexpr size_t oTWF   = oDIAG + 16;              // 1024 (512 complex, angle -2pi r/262144)
constexpr size_t oTWC   = oTWF + 1024;             // 1024 (512 complex, angle -2pi r/512)
constexpr size_t oAW    = oTWC + 1024;             // 513
constexpr size_t oMELFB = oAW + 513;               // 41040
constexpr size_t oWSQI  = oMELFB + 513*80;         // 161024
constexpr size_t oWIHT  = oWSQI + ACCLEN;          // 61440
constexpr size_t oW0T   = oWIHT + 80*768;          // 10752
constexpr size_t oW1T   = oW0T + 21*512;           // 262144
constexpr size_t oW2T   = oW1T + 512*512;          // 262144
constexpr size_t oVTT   = oW2T + 512*512;          // 33280
constexpr size_t oNFT   = oVTT + 512*65;           // 33280
constexpr size_t oF0    = oNFT + 512*65;           // 5008
constexpr size_t oLOUD  = oF0 + NFRM;              // 5008
constexpr size_t oOQ    = oLOUD + NFRM;            // 5008
constexpr size_t oVT    = oOQ + NFRM;              // 325520
constexpr size_t oNF    = oVT + (size_t)NFRM*65;   // 325520
constexpr size_t oGLOT  = oNF + (size_t)NFRM*65;   // 1280000
constexpr size_t oNOISE = oGLOT + (size_t)BB*TLEN; // 1280000
constexpr size_t oACC   = oNOISE + (size_t)BB*TLEN;// 1288192
constexpr size_t oCONVA = oACC + (size_t)BB*ACCLEN;// 5 complex signals: 4 packed dry + ir
constexpr size_t oEND   = oCONVA + (size_t)5*NCONV*2;
constexpr size_t oXP    = oEND;                    // NFRM*768 dedicated
constexpr size_t oGSUM  = oXP + (size_t)NFRM*768;  // BB*GCH
constexpr size_t oGPRE  = oGSUM + 320;             // BB*GCH doubles
constexpr size_t oEND2  = oGPRE + 640;
// overlays (lifetime-checked):
constexpr size_t oCONVB = oWSQI;                      // conv scratch; WSQI..ACC dead at conv time
constexpr size_t oMEL = oCONVA;                       // dead before k_dry packs CONVA
constexpr size_t oHS  = oMEL + (size_t)NFRM*80;       // ends 1.68M < ir slot at 2.10M floats

// init task counts
constexpr long R_WIN=1024, R_TW=512, R_TWF=512, R_TWC=512, R_AW=513, R_MELFB=41040,
  R_WSQI=161024, R_WIHT=61440, R_W0T=10752, R_W1T=262144, R_W2T=262144,
  R_VTT=33280, R_NFT=33280, R_IR=NCONV;
constexpr long INIT_TOTAL = R_WIN+R_TW+R_TWF+R_TWC+R_AW+R_MELFB+R_WSQI+R_WIHT+R_W0T+
  R_W1T+R_W2T+R_VTT+R_NFT+R_IR;

// mega-kernel block roles
constexpr int NOISEB = 313;
constexpr int ZACCB  = 315;
constexpr int MEGA_BLOCKS = 1 + NFRM + NOISEB + ZACCB;

typedef float f32x4 __attribute__((ext_vector_type(4)));
typedef __bf16 bf16x8 __attribute__((ext_vector_type(8)));
typedef short short8 __attribute__((ext_vector_type(8)));
#define MFMA_BF16 __builtin_amdgcn_mfma_f32_16x16x32_bf16

// ---------------- helpers ----------------
__device__ inline int mirror_idx(int j) {
  if (j < 0) j = -j;
  if (j >= TLEN) j = 2*TLEN - 2 - j;
  return j;
}
__device__ inline float sigm(float x) { return 1.0f/(1.0f + expf(-x)); }
__device__ inline unsigned short f2bf(float x) {
  unsigned u = __float_as_uint(x);
  return (unsigned short)((u + 0x7FFFu + ((u >> 16) & 1u)) >> 16);
}
__device__ inline float tanh_fast(float x) {
  return 1.0f - 2.0f/(__expf(2.0f*x) + 1.0f);
}

__device__ inline float interpF(const float* v, int i) {
  float pos = ((float)i + 0.5f) * (626.0f/160000.0f) - 0.5f;
  pos = fminf(fmaxf(pos, 0.0f), 625.0f);
  int lo = (int)floorf(pos);
  int hi = min(lo + 1, 625);
  float w = pos - (float)lo;
  return v[lo]*(1.0f - w) + v[hi]*w;
}
__device__ inline float interp65(const float* v, int k) {
  float pos = ((float)k + 0.5f) * (65.0f/513.0f) - 0.5f;
  pos = fminf(fmaxf(pos, 0.0f), 64.0f);
  int lo = (int)floorf(pos);
  int hi = min(lo + 1, 64);
  float w = pos - (float)lo;
  return v[lo]*(1.0f - w) + v[hi]*w;
}
__device__ inline float gwave(float ph, float oqu) {
  float p = ph - floorf(ph);
  float oqc = fminf(fmaxf(oqu, 0.1f), 0.9f);
  float pulse = 0.5f*(1.0f - cosf(3.14159265358979f * p / (oqc + 1e-8f)));
  float gs = 1.0f/(1.0f + __expf(-(oqc - p)*100.0f));
  return pulse*gs;
}

// radix-2 DIT FFT in LDS on interleaved complex; input at bit-reversed positions.
template<int LOGN, int TS>
__device__ inline void fft2(float2* c, const float2* tw, int tid, int nthr, bool inv) {
  constexpr int N = 1 << LOGN;
  for (int s = 1; s <= LOGN; ++s) {
    const int half = 1 << (s-1);
    const int tstep = (N >> s) * TS;
    for (int bf = tid; bf < (N>>1); bf += nthr) {
      int jj = bf & (half-1);
      int i0 = ((bf >> (s-1)) << s) + jj;
      int i1 = i0 + half;
      float2 wv = tw[jj*tstep];
      float wi = inv ? -wv.y : wv.y;
      float2 u = c[i0], v = c[i1];
      float tr  = v.x*wv.x - v.y*wi;
      float tci = v.x*wi  + v.y*wv.x;
      c[i0] = make_float2(u.x + tr, u.y + tci);
      c[i1] = make_float2(u.x - tr, u.y - tci);
    }
    __syncthreads();
  }
}

// threefry2x32, canonical 20-round schedule
__device__ inline void threefry2x32(unsigned k0, unsigned k1, unsigned x0, unsigned x1,
                                    unsigned& o0, unsigned& o1) {
  unsigned ks2 = k0 ^ k1 ^ 0x1BD11BDAu;
  x0 += k0; x1 += k1;
#define TF_R(r) { x0 += x1; x1 = (x1<<(r)) | (x1>>(32-(r))); x1 ^= x0; }
  TF_R(13) TF_R(15) TF_R(26) TF_R(6)
  x0 += k1; x1 += ks2 + 1u;
  TF_R(17) TF_R(29) TF_R(16) TF_R(24)
  x0 += ks2; x1 += k0 + 2u;
  TF_R(13) TF_R(15) TF_R(26) TF_R(6)
  x0 += k0; x1 += k1 + 3u;
  TF_R(17) TF_R(29) TF_R(16) TF_R(24)
  x0 += k1; x1 += ks2 + 4u;
  TF_R(13) TF_R(15) TF_R(26) TF_R(6)
  x0 += ks2; x1 += k0 + 5u;
#undef TF_R
  o0 = x0; o1 = x1;
}

__device__ inline float erfinv_f(float x) { // XLA f32 ErfInv (Giles)
  float w = -log1pf(-x*x);
  float p;
  if (w < 5.0f) {
    w = w - 2.5f;
    p = 2.81022636e-08f;
    p = fmaf(p, w, 3.43273939e-07f);
    p = fmaf(p, w, -3.5233877e-06f);
    p = fmaf(p, w, -4.39150654e-06f);
    p = fmaf(p, w, 0.00021858087f);
    p = fmaf(p, w, -0.00125372503f);
    p = fmaf(p, w, -0.00417768164f);
    p = fmaf(p, w, 0.246640727f);
    p = fmaf(p, w, 1.50140941f);
  } else {
    w = sqrtf(w) - 3.0f;
    p = -0.000200214257f;
    p = fmaf(p, w, 0.000100950558f);
    p = fmaf(p, w, 0.00134934322f);
    p = fmaf(p, w, -0.00367342844f);
    p = fmaf(p, w, 0.00573950773f);
    p = fmaf(p, w, -0.0076224613f);
    p = fmaf(p, w, 0.00943887047f);
    p = fmaf(p, w, 1.00167406f);
    p = fmaf(p, w, 2.83297682f);
  }
  return p*x;
}
__device__ inline float normal_from_bits(unsigned bits) {
  float f = __uint_as_float((bits >> 9) | 0x3F800000u) - 1.0f;
  float x = fmaxf(-0.99999994f, fmaf(f, 1.99999994f, -0.99999994f));
  return 1.41421356237f * erfinv_f(x);
}

__device__ inline double mel_fpt(int j) {
  double mmax = 2595.0 * log10(1.0 + 8000.0/700.0);
  return 700.0 * (pow(10.0, (mmax * (double)j / 81.0) / 2595.0) - 1.0);
}

// ---------------- init ----------------
__global__ void k_init(float* W, const float* wih, const float* w0,
                       const float* w1, const float* w2, const float* vtw, const float* nfw,
                       const float* ir) {
  long id = (long)blockIdx.x*256 + threadIdx.x;
  if (id < R_WIN) {
    double w = 0.5 - 0.5*cos(2.0*M_PI*(double)id/1024.0);
    W[oWIN+id] = (float)w; return;
  } id -= R_WIN;
  if (id < R_TW) {
    double a = -2.0*M_PI*(double)id/1024.0;
    W[oTW+2*id] = (float)cos(a); W[oTW+2*id+1] = (float)sin(a); return;
  } id -= R_TW;
  if (id < R_TWF) {
    double a = -2.0*M_PI*(double)id/262144.0;
    W[oTWF+2*id] = (float)cos(a); W[oTWF+2*id+1] = (float)sin(a); return;
  } id -= R_TWF;
  if (id < R_TWC) {
    double a = -2.0*M_PI*(double)id/512.0;
    W[oTWC+2*id] = (float)cos(a); W[oTWC+2*id+1] = (float)sin(a); return;
  } id -= R_TWC;
  if (id < R_AW) {
    double fr = (double)id*(8000.0/512.0); double fsq = fr*fr;
    double num = 12194.217*12194.217*fsq*fsq;
    double den = (fsq+20.6*20.6)*(fsq+107.7*107.7)*(fsq+737.9*737.9)*sqrt(fsq+12194.217*12194.217) + 1e-8;
    W[oAW+id] = (float)(num/den); return;
  } id -= R_AW;
  if (id < R_MELFB) {
    int k = (int)(id/80), m = (int)(id%80);
    double fk = (double)k*(8000.0/512.0);
    double f0p = mel_fpt(m), f1p = mel_fpt(m+1), f2p = mel_fpt(m+2);
    double lower = (fk - f0p)/(f1p - f0p);
    double upper = (f2p - fk)/(f2p - f1p);
    double v = fmax(0.0, fmin(lower, upper));
    W[oMELFB+id] = (float)v; return;
  } id -= R_MELFB;
  if (id < R_WSQI) {
    int t = (int)id;
    int n1 = t/256; if (n1 > 625) n1 = 625;
    int n0t = t - 1023 + 255; int n0 = (n0t > 0) ? n0t/256 : 0;
    double s = 0.0;
    for (int n = n0; n <= n1; ++n) {
      int o = t - n*256;
      double wv = 0.5 - 0.5*cos(2.0*M_PI*(double)o/1024.0);
      s += wv*wv;
    }
    float sf = (float)s;
    W[oWSQI+t] = (sf > 1e-11f) ? (1.0f/sf) : 1.0f; return;
  } id -= R_WSQI;
  if (id < R_WIHT) { long k = id/768, g = id%768; W[oWIHT+id] = wih[g*80+k];  return; } id -= R_WIHT;
  if (id < R_W0T)  { long d = id/512, j = id%512; W[oW0T+id] = w0[j*21+d];   return; } id -= R_W0T;
  if (id < R_W1T)  { long k = id/512, j = id%512; W[oW1T+id] = w1[j*512+k];  return; } id -= R_W1T;
  if (id < R_W2T)  { long k = id/512, j = id%512; W[oW2T+id] = w2[j*512+k];  return; } id -= R_W2T;
  if (id < R_VTT)  { long k = id/65,  m = id%65;  W[oVTT+id] = vtw[m*512+k]; return; } id -= R_VTT;
  if (id < R_NFT)  { long k = id/65,  m = id%65;  W[oNFT+id] = nfw[m*512+k]; return; } id -= R_NFT;
  if (id < R_IR) {
    size_t base = oCONVA + 2*((size_t)4*NCONV + id);   // ir at t=4
    W[base] = (id < 8000) ? ir[id] : 0.0f; W[base+1] = 0.0f; return;
  }
}

// ---------------- STFT of audio + loud + mel (sparse mel) ----------------
__global__ __launch_bounds__(256) void k_stft_mel(const float* audio, float* W) {
  int blk = blockIdx.x; int b = blk/FRM, f = blk%FRM; int tid = threadIdx.x;
  __shared__ float2 cb[1024];
  __shared__ float spec[513];
  __shared__ float redbuf[4];
  const float* arow = audio + (size_t)b*TLEN;
  const float2* tw = (const float2*)(W + oTW);
  for (int i = tid; i < 1024; i += 256) {
    float v = arow[mirror_idx(f*256 + i - 512)] * W[oWIN + i];
    int pos = __brev((unsigned)i) >> 22;
    cb[pos] = make_float2(v, 0.f);
  }
  __syncthreads();
  fft2<10,1>(cb, tw, tid, 256, false);
  for (int k = tid; k < 513; k += 256) { float2 z = cb[k]; spec[k] = z.x*z.x + z.y*z.y; }
  __syncthreads();
  float part = 0.f;
  for (int k = tid; k < 513; k += 256) part += (spec[k] + 1e-8f) * W[oAW + k];
  for (int off = 32; off; off >>= 1) part += __shfl_down(part, off, 64);
  if ((tid & 63) == 0) redbuf[tid >> 6] = part;
  __syncthreads();
  if (tid == 0) {
    float s = redbuf[0]+redbuf[1]+redbuf[2]+redbuf[3];
    W[oLOUD + blk] = 10.0f * log10f(s / 513.0f);
  }
  for (int m = tid; m < 80; m += 256) {
    double f0p = mel_fpt(m), f2p = mel_fpt(m + 2);
    int klo = (int)(f0p * (512.0/8000.0)); if (klo < 0) klo = 0;
    int khi = (int)(f2p * (512.0/8000.0)) + 1; if (khi > 512) khi = 512;
    float s = 0.f;
    for (int k = klo; k <= khi; ++k) s += spec[k]*W[oMELFB + (size_t)k*80 + m];
    W[oMEL + (size_t)blk*80 + m] = logf(s + 1e-5f);
  }
}

// ---------------- mel normalization over time ----------------
__global__ void k_melnorm(float* W) {
  int id = blockIdx.x*256 + threadIdx.x;
  if (id >= BB*80) return;
  int b = id/80, m = id%80;
  double s = 0.0, ss = 0.0;
  for (int f = 0; f < FRM; ++f) {
    double v = W[oMEL + ((size_t)b*FRM + f)*80 + m];
    s += v; ss += v*v;
  }
  double mean = s/FRM;
  double var = ss/FRM - mean*mean;
  float mu = (float)mean;
  float rstd = (float)(1.0/sqrt(var + 1e-5));
  for (int f = 0; f < FRM; ++f) {
    size_t idx = oMEL + ((size_t)b*FRM + f)*80 + m;
    W[idx] = (W[idx] - mu)*rstd;
  }
}

// ---------------- GRU input precompute ----------------
__global__ void k_xp(float* W, const float* bih) {
  size_t id = (size_t)blockIdx.x*256 + threadIdx.x;
  if (id >= (size_t)NFRM*768) return;
  int g = (int)(id % 768);
  size_t q = id / 768;
  const float* mrow = W + oMEL + q*80;
  float acc = bih[g];
  for (int k = 0; k < 80; ++k) acc = fmaf(mrow[k], W[oWIHT + (size_t)k*768 + g], acc);
  W[oXP + q*768 + g] = acc;
}

// ================ MEGA kernel: GRU (block 0) + f0 + noise + zacc ================
// GRU: wave w owns cols 96w..96w+95; tiles 0..4 in regs, 5 in LDS.
// A rows 8..15 are structurally zero -> LDA exec-masked to lanes cl<8 (halves LDS BW).
__global__ __launch_bounds__(512, 2) void k_mega(float* W, const float* audio,
                                                 const float* whh, const float* bhh) {
  __shared__ unsigned short sB[32768];   // 64 KB
  __shared__ unsigned short sA[2048];    // 4 KB (8 rows x 256)
  __shared__ float sGT[9216];            // 36 KB transposed gate buf [col][12]
  __shared__ float fr4[4][1032];         // 16.5 KB (f0 role)
  __shared__ float wpow[8];
  __shared__ float wmax[8];
  __shared__ int   wmaxi[8];
  int tid = threadIdx.x;
  int blk = blockIdx.x;

  if (blk == 0) {
    // ---------------- GRU role ----------------
    int w = tid >> 6, l = tid & 63;
    const float* XP = W + oXP;
    float* HS = W + oHS;

    for (int idx = tid; idx < 32768; idx += 512) {
      int lcol = idx >> 8, k = idx & 255;
      int gcol = 96*(lcol >> 4) + 80 + (lcol & 15);
      sB[lcol*256 + (k ^ ((lcol & 7) << 3))] = f2bf(whh[(size_t)gcol*256 + k]);
    }
    for (int idx = tid; idx < 2048; idx += 512) sA[idx] = 0;

    int cl = l & 15, khalf = (l >> 4) * 8;
    bf16x8 bw[40];
    #pragma unroll
    for (int t2 = 0; t2 < 5; ++t2) {
      int col = 96*w + 16*t2 + cl;
      #pragma unroll
      for (int kk = 0; kk < 8; ++kk) {
        const float* src = whh + (size_t)col*256 + kk*32 + khalf;
        short8 tmp;
        #pragma unroll
        for (int j = 0; j < 8; ++j) tmp[j] = (short)f2bf(src[j]);
        bw[t2*8 + kk] = __builtin_bit_cast(bf16x8, tmp);
      }
    }
    const short8 zzs = {0,0,0,0,0,0,0,0};
    const bf16x8 z8 = __builtin_bit_cast(bf16x8, zzs);

    int g = tid & 255, bbase = tid >> 8;   // batches 4*bbase + j
    float bh_r = bhh[g], bh_z = bhh[256 + g], bh_n = bhh[512 + g];
    float hprev[4] = {0.f, 0.f, 0.f, 0.f};
    int aXor = (cl & 7) << 3;
    int lcol5 = w*16 + cl;
    int rowg = l >> 4;
    int colb = 96*w + cl;
    int gtw = colb*12 + rowg*4;
    int gtr0 = g*12 + 4*bbase;
    int gtr1 = (256 + g)*12 + 4*bbase;
    int gtr2 = (512 + g)*12 + 4*bbase;
    bool aOK = (cl < 8);

    __syncthreads();

#define LDA(kk) (*(const bf16x8*)&sA[(cl)*256 + (((kk)*32 + khalf) ^ aXor)])
#define LDB(kk) (*(const bf16x8*)&sB[(lcol5)*256 + (((kk)*32 + khalf) ^ aXor)])
#define STEPK(A_, kk) \
      c0 = MFMA_BF16(A_, bw[0*8+(kk)], c0, 0, 0, 0); \
      c1 = MFMA_BF16(A_, bw[1*8+(kk)], c1, 0, 0, 0); \
      c2 = MFMA_BF16(A_, bw[2*8+(kk)], c2, 0, 0, 0); \
      c3 = MFMA_BF16(A_, bw[3*8+(kk)], c3, 0, 0, 0); \
      c4 = MFMA_BF16(A_, bw[4*8+(kk)], c4, 0, 0, 0); \
      c5 = MFMA_BF16(A_, LDB(kk), c5, 0, 0, 0);

    for (int t = 0; t < FRM; ++t) {
      float xr[4], xz[4], xn[4];
      #pragma unroll
      for (int j = 0; j < 4; ++j) {
        const float* xpp = XP + ((size_t)(4*bbase + j)*FRM + t)*768 + g;
        xr[j] = xpp[0]; xz[j] = xpp[256]; xn[j] = xpp[512];
      }
      f32x4 c0 = {0,0,0,0}, c1 = {0,0,0,0}, c2 = {0,0,0,0};
      f32x4 c3 = {0,0,0,0}, c4 = {0,0,0,0}, c5 = {0,0,0,0};
      bf16x8 a0 = z8, a1 = z8, a2 = z8, a3 = z8;
      if (aOK) { a0 = LDA(0); a1 = LDA(1); a2 = LDA(2); a3 = LDA(3); }
      STEPK(a0, 0) STEPK(a1, 1) STEPK(a2, 2) STEPK(a3, 3)
      if (aOK) { a0 = LDA(4); a1 = LDA(5); a2 = LDA(6); a3 = LDA(7); }
      STEPK(a0, 4) STEPK(a1, 5) STEPK(a2, 6) STEPK(a3, 7)
      if (rowg < 3) {
        *(f32x4*)&sGT[gtw + 0*192]  = c0;
        *(f32x4*)&sGT[gtw + 1*192]  = c1;
        *(f32x4*)&sGT[gtw + 2*192]  = c2;
        *(f32x4*)&sGT[gtw + 3*192]  = c3;
        *(f32x4*)&sGT[gtw + 4*192]  = c4;
        *(f32x4*)&sGT[gtw + 5*192]  = c5;
      }
      __syncthreads();
      f32x4 rv = *(const f32x4*)&sGT[gtr0];
      f32x4 zv = *(const f32x4*)&sGT[gtr1];
      f32x4 nv = *(const f32x4*)&sGT[gtr2];
      #pragma unroll
      for (int j = 0; j < 4; ++j) {
        int bb = 4*bbase + j;
        float r = 1.0f/(1.0f + __expf(-(xr[j] + rv[j] + bh_r)));
        float z = 1.0f/(1.0f + __expf(-(xz[j] + zv[j] + bh_z)));
        float nn = tanh_fast(xn[j] + r*(nv[j] + bh_n));
        float h = (1.0f - z)*nn + z*hprev[j];
        hprev[j] = h;
        HS[((size_t)bb*FRM + t)*256 + g] = h;
        sA[bb*256 + (g ^ ((bb & 7) << 3))] = f2bf(h);
      }
      __syncthreads();
    }
#undef LDA
#undef LDB
#undef STEPK
    return;
  }
  blk -= 1;

  if (blk < NFRM) {
    // ---------------- f0 role ----------------
    int b = blk/FRM, f = blk%FRM;
    const float* arow = audio + (size_t)b*TLEN;
    for (int idx = tid; idx < 4*1032; idx += 512) {
      int s = idx/1032, i = idx - s*1032;
      int j = i + s;
      fr4[s][i] = (j < 1024) ? arow[mirror_idx(f*256 + j - 512)] : 0.f;
    }
    __syncthreads();
    int lane = tid & 63, wv = tid >> 6;
    float p = 0.f;
    for (int i = tid; i < 1024; i += 512) { float x = fr4[0][i]; p += x*x; }
    for (int off = 32; off; off >>= 1) p += __shfl_down(p, off, 64);
    if (lane == 0) wpow[wv] = p;
    float vbest = -1e30f; int ibest = tid;
    if (tid < 304) {
      int lag = 16 + tid;
      int s = lag & 3, base = lag - s;
      int qmax = (1023 - lag) >> 2;
      float acc = 0.f;
      for (int q = 0; q <= qmax; ++q) {
        float4 u = *(const float4*)&fr4[0][4*q];
        float4 v = *(const float4*)&fr4[s][base + 4*q];
        acc += u.x*v.x + u.y*v.y + u.z*v.z + u.w*v.w;
      }
      vbest = acc;
    }
    for (int off = 32; off; off >>= 1) {
      float v2 = __shfl_down(vbest, off, 64);
      int i2 = __shfl_down(ibest, off, 64);
      if (v2 > vbest || (v2 == vbest && i2 < ibest)) { vbest = v2; ibest = i2; }
    }
    if (lane == 0) { wmax[wv] = vbest; wmaxi[wv] = ibest; }
    __syncthreads();
    if (tid == 0) {
      float ac0 = 0.f;
      #pragma unroll
      for (int q = 0; q < 8; ++q) ac0 += wpow[q];
      float bv = wmax[0]; int bi = wmaxi[0];
      #pragma unroll
      for (int q = 1; q < 8; ++q) {
        if (wmax[q] > bv || (wmax[q] == bv && wmaxi[q] < bi)) { bv = wmax[q]; bi = wmaxi[q]; }
      }
      float inv = 1.0f/(ac0 + 1e-8f);
      float best = bv*inv;
      W[oF0 + (size_t)blk] = (best < 0.3f) ? 0.0f : (SRF/(float)(bi + 16));
    }
    return;
  }
  blk -= NFRM;

  if (blk < NOISEB) {
    size_t base = (size_t)blk*4096;
    #pragma unroll
    for (int j = 0; j < 8; ++j) {
      size_t p = base + (size_t)j*512 + tid;
      if (p < (size_t)BB*TLEN) {
        unsigned o0, o1;
        threefry2x32(0u, 42u, 0u, (unsigned)p, o0, o1);
        W[oNOISE + p] = normal_from_bits(o0 ^ o1);
      }
    }
    return;
  }
  blk -= NOISEB;

  {
    size_t base = (size_t)blk*4096;
    #pragma unroll
    for (int j = 0; j < 8; ++j) {
      size_t p = base + (size_t)j*512 + tid;
      if (p < (size_t)BB*ACCLEN) W[oACC + p] = 0.0f;
    }
  }
}

// ---------------- MLP + heads (proj fused) ----------------
__device__ inline void ln_lrelu(float acc[8], float gj, float ej, float out[8][512],
                                float wred[8][8][2], float stat[8][2],
                                int tid, int lane, int wv, int j) {
  #pragma unroll
  for (int i = 0; i < 8; ++i) {
    float s = acc[i], ss = acc[i]*acc[i];
    for (int off = 32; off; off >>= 1) { s += __shfl_down(s, off, 64); ss += __shfl_down(ss, off, 64); }
    if (lane == 0) { wred[i][wv][0] = s; wred[i][wv][1] = ss; }
  }
  __syncthreads();
  if (tid < 8) {
    float s = 0.f, ss = 0.f;
    #pragma unroll
    for (int w = 0; w < 8; ++w) { s += wred[tid][w][0]; ss += wred[tid][w][1]; }
    float mean = s/512.0f;
    float var = ss/512.0f - mean*mean;
    stat[tid][0] = mean;
    stat[tid][1] = 1.0f/sqrtf(var + 1e-5f);
  }
  __syncthreads();
  #pragma unroll
  for (int i = 0; i < 8; ++i) {
    float v = (acc[i] - stat[i][0])*stat[i][1]*gj + ej;
    out[i][j] = (v >= 0.f) ? v : 0.1f*v;
  }
}

__global__ __launch_bounds__(512) void k_mlp(float* W, const float* gender, const float* age,
    const float* projw, const float* projb,
    const float* b0, const float* g0, const float* e0,
    const float* b1, const float* g1, const float* e1,
    const float* b2, const float* g2, const float* e2,
    const float* oqw, const float* oqb, const float* vtb, const float* nfb) {
  __shared__ float hbuf[8][256];
  __shared__ float in0[8][21];
  __shared__ float actA[8][512];
  __shared__ float actB[8][512];
  __shared__ float wred[8][8][2];
  __shared__ float stat[8][2];
  int tid = threadIdx.x; int q0 = blockIdx.x*8;
  for (int x = tid; x < 2048; x += 512) {
    int i = x >> 8, k = x & 255;
    hbuf[i][k] = W[oHS + ((size_t)(q0 + i))*256 + k];
  }
  __syncthreads();
  if (tid < 128) {
    int i = tid >> 4, zi = tid & 15;
    float a = projb[zi];
    for (int k = 0; k < 256; ++k) a = fmaf(hbuf[i][k], projw[zi*256 + k], a);
    in0[i][zi] = a;
  } else if (tid < 168) {
    int x = tid - 128; int i = x/5, d = 16 + x%5;
    int q = q0 + i; int b = q/FRM;
    float v;
    if (d == 16) v = (logf(W[oF0 + q] + 1e-5f) - 4.0f)*0.25f;
    else if (d == 17) v = W[oLOUD + q]/100.0f + 1.0f;
    else if (d == 18) v = gender[b*2];
    else if (d == 19) v = gender[b*2 + 1];
    else v = age[b];
    in0[i][d] = v;
  }
  __syncthreads();
  int j = tid, lane = tid & 63, wv = tid >> 6;
  float acc[8];
  #pragma unroll
  for (int i = 0; i < 8; ++i) acc[i] = b0[j];
  for (int d = 0; d < 21; ++d) {
    float w = W[oW0T + (size_t)d*512 + j];
    #pragma unroll
    for (int i = 0; i < 8; ++i) acc[i] = fmaf(in0[i][d], w, acc[i]);
  }
  ln_lrelu(acc, g0[j], e0[j], actA, wred, stat, tid, lane, wv, j);
  __syncthreads();
  #pragma unroll
  for (int i = 0; i < 8; ++i) acc[i] = b1[j];
  for (int k = 0; k < 512; ++k) {
    float w = W[oW1T + (size_t)k*512 + j];
    #pragma unroll
    for (int i = 0; i < 8; ++i) acc[i] = fmaf(actA[i][k], w, acc[i]);
  }
  ln_lrelu(acc, g1[j], e1[j], actB, wred, stat, tid, lane, wv, j);
  __syncthreads();
  #pragma unroll
  for (int i = 0; i < 8; ++i) acc[i] = b2[j];
  for (int k = 0; k < 512; ++k) {
    float w = W[oW2T + (size_t)k*512 + j];
    #pragma unroll
    for (int i = 0; i < 8; ++i) acc[i] = fmaf(actB[i][k], w, acc[i]);
  }
  ln_lrelu(acc, g2[j], e2[j], actA, wred, stat, tid, lane, wv, j);
  __syncthreads();
  for (int x = tid; x < 520; x += 512) {
    int i = x/65, m = x%65;
    float a = vtb[m], a2 = nfb[m];
    for (int k = 0; k < 512; ++k) {
      float h = actA[i][k];
      a  = fmaf(h, W[oVTT + (size_t)k*65 + m], a);
      a2 = fmaf(h, W[oNFT + (size_t)k*65 + m], a2);
    }
    W[oVT + (size_t)(q0+i)*65 + m] = sigm(a);
    W[oNF + (size_t)(q0+i)*65 + m] = sigm(a2);
  }
  if (tid < 8) {
    float a = oqb[0];
    for (int k = 0; k < 512; ++k) a = fmaf(actA[tid][k], oqw[k], a);
    W[oOQ + q0 + tid] = sigm(a);
  }
}

// ---------------- glottal: parallel 3-phase ----------------
__global__ __launch_bounds__(256) void k_gsum(float* W) {
  int blk = blockIdx.x; int b = blk/GCH, c = blk%GCH; int tid = threadIdx.x;
  __shared__ float ws[4];
  const float* f0r = W + oF0 + (size_t)b*FRM;
  int i0 = c*4096 + tid*16;
  float s = 0.f;
  #pragma unroll
  for (int j = 0; j < 16; ++j) {
    int i = i0 + j;
    if (i < TLEN) s += interpF(f0r, i)*(1.0f/SRF);
  }
  for (int off = 32; off; off >>= 1) s += __shfl_down(s, off, 64);
  if ((tid & 63) == 0) ws[tid >> 6] = s;
  __syncthreads();
  if (tid == 0) W[oGSUM + (size_t)b*GCH + c] = ws[0]+ws[1]+ws[2]+ws[3];
}

__global__ void k_gscan(float* W) {
  if (blockIdx.x == 0 && threadIdx.x == 0) {
    double* P = (double*)(W + oGPRE);
    for (int b = 0; b < BB; ++b) {
      double a = 0.0;
      for (int c = 0; c < GCH; ++c) {
        P[b*GCH + c] = a;
        a += (double)W[oGSUM + (size_t)b*GCH + c];
      }
    }
  }
}

__global__ __launch_bounds__(256) void k_gapply(float* W) {
  int blk = blockIdx.x; int b = blk/GCH, c = blk%GCH; int tid = threadIdx.x;
  __shared__ float wss[4];
  __shared__ float lastw[4];
  const float* f0r = W + oF0 + (size_t)b*FRM;
  const float* oqr = W + oOQ + (size_t)b*FRM;
  float* grow = W + oGLOT + (size_t)b*TLEN;
  double P = ((const double*)(W + oGPRE))[b*GCH + c];
  int i0 = c*4096 + tid*16;
  int lane = tid & 63, wv = tid >> 6;
  float v[16]; float ts = 0.f;
  #pragma unroll
  for (int j = 0; j < 16; ++j) {
    int i = i0 + j;
    float x = (i < TLEN) ? interpF(f0r, i)*(1.0f/SRF) : 0.f;
    v[j] = x; ts += x;
  }
  float sc = ts;
  #pragma unroll
  for (int off = 1; off < 64; off <<= 1) {
    float o = __shfl_up(sc, off, 64);
    if (lane >= off) sc += o;
  }
  if (lane == 63) wss[wv] = sc;
  __syncthreads();
  float wpre = 0.f;
  for (int q = 0; q < wv; ++q) wpre += wss[q];
  double ph0 = P + (double)(wpre + sc - ts);
  float run = 0.f; float gq[16];
  #pragma unroll
  for (int j = 0; j < 16; ++j) {
    int i = i0 + j;
    run += v[j];
    float ph = (float)(ph0 + (double)run);
    gq[j] = gwave(ph, interpF(oqr, min(i, TLEN-1)));
  }
  float prev = __shfl_up(gq[15], 1, 64);
  if (lane == 63) lastw[wv] = gq[15];
  __syncthreads();
  if (lane == 0) {
    if (wv > 0) prev = lastw[wv - 1];
    else if (i0 > 0) prev = gwave((float)P, interpF(oqr, i0 - 1));
    else prev = 0.f;
  }
  #pragma unroll
  for (int j = 0; j < 16; ++j) {
    int i = i0 + j;
    if (i < TLEN) {
      float gl = (j == 0) ? prev : gq[j-1];
      grow[i] = (i == 0) ? 0.f : (gq[j] - gl);
    }
  }
}

// ---------------- fused STFT->filter->ISTFT OLA (packed G+iN, 2 FFTs) ----------------
__global__ __launch_bounds__(256) void k_filtsynth(float* W) {
  int blk = blockIdx.x; int b = blk/FRM, f = blk%FRM; int tid = threadIdx.x;
  __shared__ float2 cZ[1024], cS[1024];
  __shared__ float fvt[65], fnf[65];
  const float* grow = W + oGLOT + (size_t)b*TLEN;
  const float* nrow = W + oNOISE + (size_t)b*TLEN;
  const float2* tw = (const float2*)(W + oTW);
  for (int i = tid; i < 1024; i += 256) {
    int si = mirror_idx(f*256 + i - 512);
    float wv = W[oWIN + i];
    int pos = __brev((unsigned)i) >> 22;
    cZ[pos] = make_float2(grow[si]*wv, nrow[si]*wv);
  }
  if (tid < 65) {
    fvt[tid] = W[oVT + ((size_t)b*FRM + f)*65 + tid];
    fnf[tid] = W[oNF + ((size_t)b*FRM + f)*65 + tid];
  }
  __syncthreads();
  fft2<10,1>(cZ, tw, tid, 256, false);
  // split via conj symmetry, apply filters, write S at bit-reversed slots
  for (int k = tid; k <= 512; k += 256) {
    int km = (1024 - k) & 1023;
    float2 z1 = cZ[k], z2 = cZ[km];
    float Gr = 0.5f*(z1.x + z2.x), Gi = 0.5f*(z1.y - z2.y);
    float Nr = 0.5f*(z1.y + z2.y), Ni = 0.5f*(z2.x - z1.x);
    float fv = interp65(fvt, k), fn = interp65(fnf, k);
    float Sr = Gr*fv + Nr*fn, Si = Gi*fv + Ni*fn;
    cS[__brev((unsigned)k) >> 22] = make_float2(Sr, Si);
    if (km != k) cS[__brev((unsigned)km) >> 22] = make_float2(Sr, -Si);
  }
  __syncthreads();
  fft2<10,1>(cS, tw, tid, 256, true);
  float* arow = W + oACC + (size_t)b*ACCLEN + (size_t)f*256;
  for (int i = tid; i < 1024; i += 256) {
    float xv = cS[i].x*(1.0f/1024.0f)*W[oWIN + i];
    atomicAdd(arow + i, xv);
  }
}

// ---------------- dry: pack 2 batches per complex signal ----------------
__global__ void k_dry(float* W, float* dout) {
  size_t id = (size_t)blockIdx.x*256 + threadIdx.x;
  if (id >= (size_t)4*NCONV) return;
  int t = (int)(id / NCONV);
  int n = (int)(id % NCONV);
  float dv0 = 0.f, dv1 = 0.f;
  if (n < TLEN) {
    float pos = ((float)n + 0.5f) * (626.0f/160000.0f) - 0.5f;
    pos = fminf(fmaxf(pos, 0.0f), 625.0f);
    int lo = (int)floorf(pos);
    int hi = min(lo + 1, 625);
    float wgt = pos - (float)lo;
    float wsq = W[oWSQI + 512 + n];
    #pragma unroll
    for (int q = 0; q < 2; ++q) {
      int b = 2*t + q;
      float val = W[oACC + (size_t)b*ACCLEN + 512 + n] * wsq;
      const float* lrow = W + oLOUD + (size_t)b*FRM;
      float a0 = exp10f(lrow[lo]*0.05f);
      float a1 = exp10f(lrow[hi]*0.05f);
      float dv = val*(a0*(1.0f - wgt) + a1*wgt);
      if (q == 0) dv0 = dv; else dv1 = dv;
      dout[(size_t)BB*TLEN + (size_t)b*TLEN + n] = dv;
    }
  }
  ((float2*)(W + oCONVA))[id] = make_float2(dv0, dv1);
}

// ---------------- four-step FFT (N = 512*512) ----------------
__global__ __launch_bounds__(256) void k_conv_f1(const float* in, float* out,
                                                 const float* tw, const float* twf,
                                                 const float* twc) {
  int blk = blockIdx.x; int t = blk >> 9; int bcol = blk & 511; int tid = threadIdx.x;
  __shared__ float2 cb[512];
  const float2* src = (const float2*)in + (size_t)t*NCONV;
  for (int a = tid; a < 512; a += 256) {
    int pos = __brev((unsigned)a) >> 23;
    cb[pos] = src[(size_t)a*512 + bcol];
  }
  __syncthreads();
  fft2<9,2>(cb, (const float2*)tw, tid, 256, false);
  float2* dst = (float2*)out + (size_t)t*NCONV + (size_t)bcol*512;
  for (int k1 = tid; k1 < 512; k1 += 256) {
    unsigned m = (unsigned)bcol * (unsigned)k1;   // < 262144
    float2 tc = ((const float2*)twc)[m >> 9];
    float2 tf = ((const float2*)twf)[m & 511];
    float wr = tc.x*tf.x - tc.y*tf.y;
    float wi = tc.x*tf.y + tc.y*tf.x;
    float2 v = cb[k1];
    dst[k1] = make_float2(v.x*wr - v.y*wi, v.x*wi + v.y*wr);
  }
}

__global__ __launch_bounds__(256) void k_conv_f2(const float* in, float* out, const float* tw) {
  int blk = blockIdx.x; int t = blk >> 9; int k1 = blk & 511; int tid = threadIdx.x;
  __shared__ float2 cb[512];
  const float2* src = (const float2*)in + (size_t)t*NCONV;
  for (int bb2 = tid; bb2 < 512; bb2 += 256) {
    int pos = __brev((unsigned)bb2) >> 23;
    cb[pos] = src[(size_t)bb2*512 + k1];
  }
  __syncthreads();
  fft2<9,2>(cb, (const float2*)tw, tid, 256, false);
  float2* dst = (float2*)out + (size_t)t*NCONV;
  for (int k2 = tid; k2 < 512; k2 += 256) {
    dst[(size_t)k1 + 512*(size_t)k2] = cb[k2];
  }
}

// packed spectral multiply: split X0/X1 (two real seqs), multiply by IR, repack Y=P0+iP1,
// store conj(Y) for inverse-via-forward.
__global__ void k_mul(float* W) {
  constexpr size_t HALF = NCONV/2;
  size_t id = (size_t)blockIdx.x*256 + threadIdx.x;
  if (id >= (size_t)4*(HALF + 1)) return;
  int t = (int)(id / (HALF + 1));
  size_t k = id % (HALF + 1);
  size_t km = (NCONV - k) & (NCONV - 1);
  float2* A = (float2*)(W + oCONVA);
  float2 z1 = A[(size_t)t*NCONV + k];
  float2 z2 = A[(size_t)t*NCONV + km];
  float2 c  = A[(size_t)4*NCONV + k];
  float X0r = 0.5f*(z1.x + z2.x), X0i = 0.5f*(z1.y - z2.y);
  float X1r = 0.5f*(z1.y + z2.y), X1i = 0.5f*(z2.x - z1.x);
  float P0r = X0r*c.x - X0i*c.y, P0i = X0r*c.y + X0i*c.x;
  float P1r = X1r*c.x - X1i*c.y, P1i = X1r*c.y + X1i*c.x;
  // conj(Y(k)) where Y(k)=P0+iP1
  A[(size_t)t*NCONV + k] = make_float2(P0r - P1i, -(P0i + P1r));
  if (km != k) {
    // Y(km)=conj(P0)+i*conj(P1); conj(Y(km)) = (P0r+P1i, P0i-P1r)
    A[(size_t)t*NCONV + km] = make_float2(P0r + P1i, P0i - P1r);
  }
}

__global__ void k_wet(const float* W, float* dout) {
  size_t id = (size_t)blockIdx.x*256 + threadIdx.x;
  if (id >= (size_t)BB*TLEN) return;
  size_t b = id / TLEN, n = id % TLEN;
  float2 V = ((const float2*)(W + oCONVA))[(b >> 1)*NCONV + n];
  float val = (b & 1) ? -V.y : V.x;   // y = conj(V)/N
  dout[id] = val * (1.0f/262144.0f);
}

// ---------------- launch ----------------
extern "C" void kernel_launch(void* const* d_in, const int* in_sizes, int n_in,
                              void* d_out, int out_size, void* d_ws, size_t ws_size,
                              hipStream_t stream) {
  (void)in_sizes; (void)n_in; (void)out_size; (void)ws_size;
  const float* audio  = (const float*)d_in[0];
  const float* gender = (const float*)d_in[1];
  const float* age    = (const float*)d_in[2];
  const float* wih    = (const float*)d_in[3];
  const float* whh    = (const float*)d_in[4];
  const float* bih    = (const float*)d_in[5];
  const float* bhh    = (const float*)d_in[6];
  const float* projw  = (const float*)d_in[7];
  const float* projb  = (const float*)d_in[8];
  const float* w0     = (const float*)d_in[9];
  const float* b0     = (const float*)d_in[10];
  const float* g0     = (const float*)d_in[11];
  const float* e0     = (const float*)d_in[12];
  const float* w1     = (const float*)d_in[13];
  const float* b1     = (const float*)d_in[14];
  const float* g1     = (const float*)d_in[15];
  const float* e1     = (const float*)d_in[16];
  const float* w2     = (const float*)d_in[17];
  const float* b2     = (const float*)d_in[18];
  const float* g2     = (const float*)d_in[19];
  const float* e2     = (const float*)d_in[20];
  const float* oqw    = (const float*)d_in[21];
  const float* oqb    = (const float*)d_in[22];
  const float* vtw    = (const float*)d_in[23];
  const float* vtb    = (const float*)d_in[24];
  const float* nfw    = (const float*)d_in[25];
  const float* nfb    = (const float*)d_in[26];
  const float* ir     = (const float*)d_in[27];
  float* W = (float*)d_ws;
  float* dout = (float*)d_out;

  k_init<<<(int)((INIT_TOTAL + 255)/256), 256, 0, stream>>>(W, wih, w0, w1, w2, vtw, nfw, ir);
  k_stft_mel<<<NFRM, 256, 0, stream>>>(audio, W);
  k_melnorm<<<3, 256, 0, stream>>>(W);
  k_xp<<<(int)(((size_t)NFRM*768 + 255)/256), 256, 0, stream>>>(W, bih);
  k_mega<<<MEGA_BLOCKS, 512, 0, stream>>>(W, audio, whh, bhh);
  k_mlp<<<NFRM/8, 512, 0, stream>>>(W, gender, age, projw, projb,
                                    b0, g0, e0, b1, g1, e1, b2, g2, e2, oqw, oqb, vtb, nfb);
  k_gsum<<<BB*GCH, 256, 0, stream>>>(W);
  k_gscan<<<1, 64, 0, stream>>>(W);
  k_gapply<<<BB*GCH, 256, 0, stream>>>(W);
  k_filtsynth<<<NFRM, 256, 0, stream>>>(W);
  k_dry<<<(int)(((size_t)4*NCONV + 255)/256), 256, 0, stream>>>(W, dout);
  k_conv_f1<<<5*512, 256, 0, stream>>>(W + oCONVA, W + oCONVB, W + oTW, W + oTWF, W + oTWC);
  k_conv_f2<<<5*512, 256, 0, stream>>>(W + oCONVB, W + oCONVA, W + oTW);
  k_mul<<<(int)(((size_t)4*(NCONV/2 + 1) + 255)/256), 256, 0, stream>>>(W);
  k_conv_f1<<<4*512, 256, 0, stream>>>(W + oCONVA, W + oCONVB, W + oTW, W + oTWF, W + oTWC);
  k_conv_f2<<<4*512, 256, 0, stream>>>(W + oCONVB, W + oCONVA, W + oTW);
  k_wet<<<(int)(((size_t)BB*TLEN + 255)/256), 256, 0, stream>>>(W, dout);
}

// Round 11
// 2097.546 us; speedup vs baseline: 1.3223x; 1.0482x over previous
//
#include <hip/hip_runtime.h>
#include <math.h>

#define SRF 16000.0f
#define HOP 256
#define FRM 626
#define BB 8
#define TLEN 160000
#define NFRM (BB*FRM)
#define NCONV 262144
#define ACCLEN 161024
#define GCH 40            // glottal chunks per batch (40*4096 >= 160000)

// ---------------- workspace layout (float offsets) ----------------
constexpr size_t oWIN   = 0;                       // 1024
constexpr size_t oTW    = oWIN + 1024;             // 1024 (512 complex, angle -2pi r/1024)
constexpr size_t oDIAG  = oTW + 1024;              // 16 (unused)
constexpr size_t oTWF   = oDIAG + 16;              // 1024 (512 complex, angle -2pi r/262144)
constexpr size_t oTWC   = oTWF + 1024;             // 1024 (512 complex, angle -2pi r/512)
constexpr size_t oAW    = oTWC + 1024;             // 513
constexpr size_t oMELFB = oAW + 513;               // 41040
constexpr size_t oWSQI  = oMELFB + 513*80;         // 161024
constexpr size_t oWIHT  = oWSQI + ACCLEN;          // 61440
constexpr size_t oW0T   = oWIHT + 80*768;          // 10752
constexpr size_t oW1T   = oW0T + 21*512;           // 262144
constexpr size_t oW2T   = oW1T + 512*512;          // 262144
constexpr size_t oVTT   = oW2T + 512*512;          // 33280
constexpr size_t oNFT   = oVTT + 512*65;           // 33280
constexpr size_t oF0    = oNFT + 512*65;           // 5008
constexpr size_t oLOUD  = oF0 + NFRM;              // 5008
constexpr size_t oOQ    = oLOUD + NFRM;            // 5008
constexpr size_t oVT    = oOQ + NFRM;              // 325520
constexpr size_t oNF    = oVT + (size_t)NFRM*65;   // 325520
constexpr size_t oGLOT  = oNF + (size_t)NFRM*65;   // 1280000
constexpr size_t oNOISE = oGLOT + (size_t)BB*TLEN; // 1280000
constexpr size_t oACC   = oNOISE + (size_t)BB*TLEN;// 1288192
constexpr size_t oCONVA = oACC + (size_t)BB*ACCLEN;// 5 complex signals: 4 packed dry + ir
constexpr size_t oEND   = oCONVA + (size_t)5*NCONV*2;
constexpr size_t oXP    = oEND;                    // NFRM*768 dedicated
constexpr size_t oGSUM  = oXP + (size_t)NFRM*768;  // BB*GCH
constexpr size_t oGPRE  = oGSUM + 320;             // BB*GCH doubles
constexpr size_t oEND2  = oGPRE + 640;
// overlays (lifetime-checked):
constexpr size_t oCONVB = oWSQI;                      // conv scratch; WSQI..ACC dead at conv time
constexpr size_t oMEL = oCONVA;                       // dead before k_dry packs CONVA
constexpr size_t oHS  = oMEL + (size_t)NFRM*80;       // ends well below ir slot

// init task counts
constexpr long R_WIN=1024, R_TW=512, R_TWF=512, R_TWC=512, R_AW=513, R_MELFB=41040,
  R_WSQI=161024, R_WIHT=61440, R_W0T=10752, R_W1T=262144, R_W2T=262144,
  R_VTT=33280, R_NFT=33280, R_IR=NCONV;
constexpr long INIT_TOTAL = R_WIN+R_TW+R_TWF+R_TWC+R_AW+R_MELFB+R_WSQI+R_WIHT+R_W0T+
  R_W1T+R_W2T+R_VTT+R_NFT+R_IR;

// mega-kernel block roles
constexpr int NOISEB = 313;
constexpr int ZACCB  = 315;
constexpr int MEGA_BLOCKS = 1 + NFRM + NOISEB + ZACCB;

typedef float f32x4 __attribute__((ext_vector_type(4)));
typedef __bf16 bf16x8 __attribute__((ext_vector_type(8)));
typedef short short8 __attribute__((ext_vector_type(8)));
#define MFMA_BF16 __builtin_amdgcn_mfma_f32_16x16x32_bf16

// ---------------- helpers ----------------
__device__ inline int mirror_idx(int j) {
  if (j < 0) j = -j;
  if (j >= TLEN) j = 2*TLEN - 2 - j;
  return j;
}
__device__ inline float sigm(float x) { return 1.0f/(1.0f + expf(-x)); }
__device__ inline unsigned short f2bf(float x) {
  unsigned u = __float_as_uint(x);
  return (unsigned short)((u + 0x7FFFu + ((u >> 16) & 1u)) >> 16);
}
__device__ inline float tanh_fast(float x) {
  return 1.0f - 2.0f/(__expf(2.0f*x) + 1.0f);
}

__device__ inline float interpF(const float* v, int i) {
  float pos = ((float)i + 0.5f) * (626.0f/160000.0f) - 0.5f;
  pos = fminf(fmaxf(pos, 0.0f), 625.0f);
  int lo = (int)floorf(pos);
  int hi = min(lo + 1, 625);
  float w = pos - (float)lo;
  return v[lo]*(1.0f - w) + v[hi]*w;
}
__device__ inline float interp65(const float* v, int k) {
  float pos = ((float)k + 0.5f) * (65.0f/513.0f) - 0.5f;
  pos = fminf(fmaxf(pos, 0.0f), 64.0f);
  int lo = (int)floorf(pos);
  int hi = min(lo + 1, 64);
  float w = pos - (float)lo;
  return v[lo]*(1.0f - w) + v[hi]*w;
}
__device__ inline float gwave(float ph, float oqu) {
  float p = ph - floorf(ph);
  float oqc = fminf(fmaxf(oqu, 0.1f), 0.9f);
  float pulse = 0.5f*(1.0f - cosf(3.14159265358979f * p / (oqc + 1e-8f)));
  float gs = 1.0f/(1.0f + __expf(-(oqc - p)*100.0f));
  return pulse*gs;
}

// radix-2 DIT FFT in LDS on interleaved complex; input at bit-reversed positions.
template<int LOGN, int TS>
__device__ inline void fft2(float2* c, const float2* tw, int tid, int nthr, bool inv) {
  constexpr int N = 1 << LOGN;
  for (int s = 1; s <= LOGN; ++s) {
    const int half = 1 << (s-1);
    const int tstep = (N >> s) * TS;
    for (int bf = tid; bf < (N>>1); bf += nthr) {
      int jj = bf & (half-1);
      int i0 = ((bf >> (s-1)) << s) + jj;
      int i1 = i0 + half;
      float2 wv = tw[jj*tstep];
      float wi = inv ? -wv.y : wv.y;
      float2 u = c[i0], v = c[i1];
      float tr  = v.x*wv.x - v.y*wi;
      float tci = v.x*wi  + v.y*wv.x;
      c[i0] = make_float2(u.x + tr, u.y + tci);
      c[i1] = make_float2(u.x - tr, u.y - tci);
    }
    __syncthreads();
  }
}

// threefry2x32, canonical 20-round schedule
__device__ inline void threefry2x32(unsigned k0, unsigned k1, unsigned x0, unsigned x1,
                                    unsigned& o0, unsigned& o1) {
  unsigned ks2 = k0 ^ k1 ^ 0x1BD11BDAu;
  x0 += k0; x1 += k1;
#define TF_R(r) { x0 += x1; x1 = (x1<<(r)) | (x1>>(32-(r))); x1 ^= x0; }
  TF_R(13) TF_R(15) TF_R(26) TF_R(6)
  x0 += k1; x1 += ks2 + 1u;
  TF_R(17) TF_R(29) TF_R(16) TF_R(24)
  x0 += ks2; x1 += k0 + 2u;
  TF_R(13) TF_R(15) TF_R(26) TF_R(6)
  x0 += k0; x1 += k1 + 3u;
  TF_R(17) TF_R(29) TF_R(16) TF_R(24)
  x0 += k1; x1 += ks2 + 4u;
  TF_R(13) TF_R(15) TF_R(26) TF_R(6)
  x0 += ks2; x1 += k0 + 5u;
#undef TF_R
  o0 = x0; o1 = x1;
}

__device__ inline float erfinv_f(float x) { // XLA f32 ErfInv (Giles)
  float w = -log1pf(-x*x);
  float p;
  if (w < 5.0f) {
    w = w - 2.5f;
    p = 2.81022636e-08f;
    p = fmaf(p, w, 3.43273939e-07f);
    p = fmaf(p, w, -3.5233877e-06f);
    p = fmaf(p, w, -4.39150654e-06f);
    p = fmaf(p, w, 0.00021858087f);
    p = fmaf(p, w, -0.00125372503f);
    p = fmaf(p, w, -0.00417768164f);
    p = fmaf(p, w, 0.246640727f);
    p = fmaf(p, w, 1.50140941f);
  } else {
    w = sqrtf(w) - 3.0f;
    p = -0.000200214257f;
    p = fmaf(p, w, 0.000100950558f);
    p = fmaf(p, w, 0.00134934322f);
    p = fmaf(p, w, -0.00367342844f);
    p = fmaf(p, w, 0.00573950773f);
    p = fmaf(p, w, -0.0076224613f);
    p = fmaf(p, w, 0.00943887047f);
    p = fmaf(p, w, 1.00167406f);
    p = fmaf(p, w, 2.83297682f);
  }
  return p*x;
}
__device__ inline float normal_from_bits(unsigned bits) {
  float f = __uint_as_float((bits >> 9) | 0x3F800000u) - 1.0f;
  float x = fmaxf(-0.99999994f, fmaf(f, 1.99999994f, -0.99999994f));
  return 1.41421356237f * erfinv_f(x);
}

__device__ inline double mel_fpt(int j) {
  double mmax = 2595.0 * log10(1.0 + 8000.0/700.0);
  return 700.0 * (pow(10.0, (mmax * (double)j / 81.0) / 2595.0) - 1.0);
}

// ---------------- init ----------------
__global__ void k_init(float* W, const float* wih, const float* w0,
                       const float* w1, const float* w2, const float* vtw, const float* nfw,
                       const float* ir) {
  long id = (long)blockIdx.x*256 + threadIdx.x;
  if (id < R_WIN) {
    double w = 0.5 - 0.5*cos(2.0*M_PI*(double)id/1024.0);
    W[oWIN+id] = (float)w; return;
  } id -= R_WIN;
  if (id < R_TW) {
    double a = -2.0*M_PI*(double)id/1024.0;
    W[oTW+2*id] = (float)cos(a); W[oTW+2*id+1] = (float)sin(a); return;
  } id -= R_TW;
  if (id < R_TWF) {
    double a = -2.0*M_PI*(double)id/262144.0;
    W[oTWF+2*id] = (float)cos(a); W[oTWF+2*id+1] = (float)sin(a); return;
  } id -= R_TWF;
  if (id < R_TWC) {
    double a = -2.0*M_PI*(double)id/512.0;
    W[oTWC+2*id] = (float)cos(a); W[oTWC+2*id+1] = (float)sin(a); return;
  } id -= R_TWC;
  if (id < R_AW) {
    double fr = (double)id*(8000.0/512.0); double fsq = fr*fr;
    double num = 12194.217*12194.217*fsq*fsq;
    double den = (fsq+20.6*20.6)*(fsq+107.7*107.7)*(fsq+737.9*737.9)*sqrt(fsq+12194.217*12194.217) + 1e-8;
    W[oAW+id] = (float)(num/den); return;
  } id -= R_AW;
  if (id < R_MELFB) {
    int k = (int)(id/80), m = (int)(id%80);
    double fk = (double)k*(8000.0/512.0);
    double f0p = mel_fpt(m), f1p = mel_fpt(m+1), f2p = mel_fpt(m+2);
    double lower = (fk - f0p)/(f1p - f0p);
    double upper = (f2p - fk)/(f2p - f1p);
    double v = fmax(0.0, fmin(lower, upper));
    W[oMELFB+id] = (float)v; return;
  } id -= R_MELFB;
  if (id < R_WSQI) {
    int t = (int)id;
    int n1 = t/256; if (n1 > 625) n1 = 625;
    int n0t = t - 1023 + 255; int n0 = (n0t > 0) ? n0t/256 : 0;
    double s = 0.0;
    for (int n = n0; n <= n1; ++n) {
      int o = t - n*256;
      double wv = 0.5 - 0.5*cos(2.0*M_PI*(double)o/1024.0);
      s += wv*wv;
    }
    float sf = (float)s;
    W[oWSQI+t] = (sf > 1e-11f) ? (1.0f/sf) : 1.0f; return;
  } id -= R_WSQI;
  if (id < R_WIHT) { long k = id/768, g = id%768; W[oWIHT+id] = wih[g*80+k];  return; } id -= R_WIHT;
  if (id < R_W0T)  { long d = id/512, j = id%512; W[oW0T+id] = w0[j*21+d];   return; } id -= R_W0T;
  if (id < R_W1T)  { long k = id/512, j = id%512; W[oW1T+id] = w1[j*512+k];  return; } id -= R_W1T;
  if (id < R_W2T)  { long k = id/512, j = id%512; W[oW2T+id] = w2[j*512+k];  return; } id -= R_W2T;
  if (id < R_VTT)  { long k = id/65,  m = id%65;  W[oVTT+id] = vtw[m*512+k]; return; } id -= R_VTT;
  if (id < R_NFT)  { long k = id/65,  m = id%65;  W[oNFT+id] = nfw[m*512+k]; return; } id -= R_NFT;
  if (id < R_IR) {
    size_t base = oCONVA + 2*((size_t)4*NCONV + id);   // ir at t=4
    W[base] = (id < 8000) ? ir[id] : 0.0f; W[base+1] = 0.0f; return;
  }
}

// ---------------- STFT of audio + loud + mel (sparse mel) ----------------
__global__ __launch_bounds__(256) void k_stft_mel(const float* audio, float* W) {
  int blk = blockIdx.x; int b = blk/FRM, f = blk%FRM; int tid = threadIdx.x;
  __shared__ float2 cb[1024];
  __shared__ float spec[513];
  __shared__ float redbuf[4];
  const float* arow = audio + (size_t)b*TLEN;
  const float2* tw = (const float2*)(W + oTW);
  for (int i = tid; i < 1024; i += 256) {
    float v = arow[mirror_idx(f*256 + i - 512)] * W[oWIN + i];
    int pos = __brev((unsigned)i) >> 22;
    cb[pos] = make_float2(v, 0.f);
  }
  __syncthreads();
  fft2<10,1>(cb, tw, tid, 256, false);
  for (int k = tid; k < 513; k += 256) { float2 z = cb[k]; spec[k] = z.x*z.x + z.y*z.y; }
  __syncthreads();
  float part = 0.f;
  for (int k = tid; k < 513; k += 256) part += (spec[k] + 1e-8f) * W[oAW + k];
  for (int off = 32; off; off >>= 1) part += __shfl_down(part, off, 64);
  if ((tid & 63) == 0) redbuf[tid >> 6] = part;
  __syncthreads();
  if (tid == 0) {
    float s = redbuf[0]+redbuf[1]+redbuf[2]+redbuf[3];
    W[oLOUD + blk] = 10.0f * log10f(s / 513.0f);
  }
  for (int m = tid; m < 80; m += 256) {
    double f0p = mel_fpt(m), f2p = mel_fpt(m + 2);
    int klo = (int)(f0p * (512.0/8000.0)); if (klo < 0) klo = 0;
    int khi = (int)(f2p * (512.0/8000.0)) + 1; if (khi > 512) khi = 512;
    float s = 0.f;
    for (int k = klo; k <= khi; ++k) s += spec[k]*W[oMELFB + (size_t)k*80 + m];
    W[oMEL + (size_t)blk*80 + m] = logf(s + 1e-5f);
  }
}

// ---------------- mel normalization over time ----------------
__global__ void k_melnorm(float* W) {
  int id = blockIdx.x*256 + threadIdx.x;
  if (id >= BB*80) return;
  int b = id/80, m = id%80;
  double s = 0.0, ss = 0.0;
  for (int f = 0; f < FRM; ++f) {
    double v = W[oMEL + ((size_t)b*FRM + f)*80 + m];
    s += v; ss += v*v;
  }
  double mean = s/FRM;
  double var = ss/FRM - mean*mean;
  float mu = (float)mean;
  float rstd = (float)(1.0/sqrt(var + 1e-5));
  for (int f = 0; f < FRM; ++f) {
    size_t idx = oMEL + ((size_t)b*FRM + f)*80 + m;
    W[idx] = (W[idx] - mu)*rstd;
  }
}

// ---------------- GRU input precompute ----------------
__global__ void k_xp(float* W, const float* bih) {
  size_t id = (size_t)blockIdx.x*256 + threadIdx.x;
  if (id >= (size_t)NFRM*768) return;
  int g = (int)(id % 768);
  size_t q = id / 768;
  const float* mrow = W + oMEL + q*80;
  float acc = bih[g];
  for (int k = 0; k < 80; ++k) acc = fmaf(mrow[k], W[oWIHT + (size_t)k*768 + g], acc);
  W[oXP + q*768 + g] = acc;
}

// ================ MEGA kernel: GRU (block 0) + f0 + noise + zacc ================
// GRU: wave w owns cols 96w..96w+95; tiles 0..4 in regs, 5 in LDS. (round-9 proven form)
__global__ __launch_bounds__(512, 2) void k_mega(float* W, const float* audio,
                                                 const float* whh, const float* bhh) {
  __shared__ unsigned short sB[32768];   // 64 KB
  __shared__ unsigned short sA[4096];    // 8 KB (16 rows; rows 8-15 stay zero)
  __shared__ float sGT[9216];            // 36 KB transposed gate buf [col][12]
  __shared__ float fr4[4][1032];         // 16.5 KB (f0 role)
  __shared__ float wpow[8];
  __shared__ float wmax[8];
  __shared__ int   wmaxi[8];
  int tid = threadIdx.x;
  int blk = blockIdx.x;

  if (blk == 0) {
    // ---------------- GRU role ----------------
    int w = tid >> 6, l = tid & 63;
    const float* XP = W + oXP;
    float* HS = W + oHS;

    for (int idx = tid; idx < 32768; idx += 512) {
      int lcol = idx >> 8, k = idx & 255;
      int gcol = 96*(lcol >> 4) + 80 + (lcol & 15);
      sB[lcol*256 + (k ^ ((lcol & 7) << 3))] = f2bf(whh[(size_t)gcol*256 + k]);
    }
    for (int idx = tid; idx < 4096; idx += 512) sA[idx] = 0;

    int cl = l & 15, khalf = (l >> 4) * 8;
    bf16x8 bw[40];
    #pragma unroll
    for (int t2 = 0; t2 < 5; ++t2) {
      int col = 96*w + 16*t2 + cl;
      #pragma unroll
      for (int kk = 0; kk < 8; ++kk) {
        const float* src = whh + (size_t)col*256 + kk*32 + khalf;
        short8 tmp;
        #pragma unroll
        for (int j = 0; j < 8; ++j) tmp[j] = (short)f2bf(src[j]);
        bw[t2*8 + kk] = __builtin_bit_cast(bf16x8, tmp);
      }
    }

    int g = tid & 255, bbase = tid >> 8;   // batches 4*bbase + j
    float bh_r = bhh[g], bh_z = bhh[256 + g], bh_n = bhh[512 + g];
    float hprev[4] = {0.f, 0.f, 0.f, 0.f};
    int aXor = (cl & 7) << 3;
    int lcol5 = w*16 + cl;
    int rowg = l >> 4;
    int colb = 96*w + cl;
    int gtw = colb*12 + rowg*4;
    int gtr0 = g*12 + 4*bbase;
    int gtr1 = (256 + g)*12 + 4*bbase;
    int gtr2 = (512 + g)*12 + 4*bbase;

    __syncthreads();

#define LDA(kk) (*(const bf16x8*)&sA[(cl)*256 + (((kk)*32 + khalf) ^ aXor)])
#define LDB(kk) (*(const bf16x8*)&sB[(lcol5)*256 + (((kk)*32 + khalf) ^ aXor)])
#define STEPK(A_, kk) \
      c0 = MFMA_BF16(A_, bw[0*8+(kk)], c0, 0, 0, 0); \
      c1 = MFMA_BF16(A_, bw[1*8+(kk)], c1, 0, 0, 0); \
      c2 = MFMA_BF16(A_, bw[2*8+(kk)], c2, 0, 0, 0); \
      c3 = MFMA_BF16(A_, bw[3*8+(kk)], c3, 0, 0, 0); \
      c4 = MFMA_BF16(A_, bw[4*8+(kk)], c4, 0, 0, 0); \
      c5 = MFMA_BF16(A_, LDB(kk), c5, 0, 0, 0);

    for (int t = 0; t < FRM; ++t) {
      float xr[4], xz[4], xn[4];
      #pragma unroll
      for (int j = 0; j < 4; ++j) {
        const float* xpp = XP + ((size_t)(4*bbase + j)*FRM + t)*768 + g;
        xr[j] = xpp[0]; xz[j] = xpp[256]; xn[j] = xpp[512];
      }
      f32x4 c0 = {0,0,0,0}, c1 = {0,0,0,0}, c2 = {0,0,0,0};
      f32x4 c3 = {0,0,0,0}, c4 = {0,0,0,0}, c5 = {0,0,0,0};
      bf16x8 a0 = LDA(0), a1 = LDA(1), a2 = LDA(2), a3 = LDA(3);
      STEPK(a0, 0) STEPK(a1, 1) STEPK(a2, 2) STEPK(a3, 3)
      a0 = LDA(4); a1 = LDA(5); a2 = LDA(6); a3 = LDA(7);
      STEPK(a0, 4) STEPK(a1, 5) STEPK(a2, 6) STEPK(a3, 7)
      if (rowg < 3) {
        *(f32x4*)&sGT[gtw + 0*192]  = c0;
        *(f32x4*)&sGT[gtw + 1*192]  = c1;
        *(f32x4*)&sGT[gtw + 2*192]  = c2;
        *(f32x4*)&sGT[gtw + 3*192]  = c3;
        *(f32x4*)&sGT[gtw + 4*192]  = c4;
        *(f32x4*)&sGT[gtw + 5*192]  = c5;
      }
      __syncthreads();
      f32x4 rv = *(const f32x4*)&sGT[gtr0];
      f32x4 zv = *(const f32x4*)&sGT[gtr1];
      f32x4 nv = *(const f32x4*)&sGT[gtr2];
      #pragma unroll
      for (int j = 0; j < 4; ++j) {
        int bb = 4*bbase + j;
        float r = 1.0f/(1.0f + __expf(-(xr[j] + rv[j] + bh_r)));
        float z = 1.0f/(1.0f + __expf(-(xz[j] + zv[j] + bh_z)));
        float nn = tanh_fast(xn[j] + r*(nv[j] + bh_n));
        float h = (1.0f - z)*nn + z*hprev[j];
        hprev[j] = h;
        HS[((size_t)bb*FRM + t)*256 + g] = h;
        sA[bb*256 + (g ^ ((bb & 7) << 3))] = f2bf(h);
      }
      __syncthreads();
    }
#undef LDA
#undef LDB
#undef STEPK
    return;
  }
  blk -= 1;

  if (blk < NFRM) {
    // ---------------- f0 role ----------------
    int b = blk/FRM, f = blk%FRM;
    const float* arow = audio + (size_t)b*TLEN;
    for (int idx = tid; idx < 4*1032; idx += 512) {
      int s = idx/1032, i = idx - s*1032;
      int j = i + s;
      fr4[s][i] = (j < 1024) ? arow[mirror_idx(f*256 + j - 512)] : 0.f;
    }
    __syncthreads();
    int lane = tid & 63, wv = tid >> 6;
    float p = 0.f;
    for (int i = tid; i < 1024; i += 512) { float x = fr4[0][i]; p += x*x; }
    for (int off = 32; off; off >>= 1) p += __shfl_down(p, off, 64);
    if (lane == 0) wpow[wv] = p;
    float vbest = -1e30f; int ibest = tid;
    if (tid < 304) {
      int lag = 16 + tid;
      int s = lag & 3, base = lag - s;
      int qmax = (1023 - lag) >> 2;
      float acc = 0.f;
      for (int q = 0; q <= qmax; ++q) {
        float4 u = *(const float4*)&fr4[0][4*q];
        float4 v = *(const float4*)&fr4[s][base + 4*q];
        acc += u.x*v.x + u.y*v.y + u.z*v.z + u.w*v.w;
      }
      vbest = acc;
    }
    for (int off = 32; off; off >>= 1) {
      float v2 = __shfl_down(vbest, off, 64);
      int i2 = __shfl_down(ibest, off, 64);
      if (v2 > vbest || (v2 == vbest && i2 < ibest)) { vbest = v2; ibest = i2; }
    }
    if (lane == 0) { wmax[wv] = vbest; wmaxi[wv] = ibest; }
    __syncthreads();
    if (tid == 0) {
      float ac0 = 0.f;
      #pragma unroll
      for (int q = 0; q < 8; ++q) ac0 += wpow[q];
      float bv = wmax[0]; int bi = wmaxi[0];
      #pragma unroll
      for (int q = 1; q < 8; ++q) {
        if (wmax[q] > bv || (wmax[q] == bv && wmaxi[q] < bi)) { bv = wmax[q]; bi = wmaxi[q]; }
      }
      float inv = 1.0f/(ac0 + 1e-8f);
      float best = bv*inv;
      W[oF0 + (size_t)blk] = (best < 0.3f) ? 0.0f : (SRF/(float)(bi + 16));
    }
    return;
  }
  blk -= NFRM;

  if (blk < NOISEB) {
    size_t base = (size_t)blk*4096;
    #pragma unroll
    for (int j = 0; j < 8; ++j) {
      size_t p = base + (size_t)j*512 + tid;
      if (p < (size_t)BB*TLEN) {
        unsigned o0, o1;
        threefry2x32(0u, 42u, 0u, (unsigned)p, o0, o1);
        W[oNOISE + p] = normal_from_bits(o0 ^ o1);
      }
    }
    return;
  }
  blk -= NOISEB;

  {
    size_t base = (size_t)blk*4096;
    #pragma unroll
    for (int j = 0; j < 8; ++j) {
      size_t p = base + (size_t)j*512 + tid;
      if (p < (size_t)BB*ACCLEN) W[oACC + p] = 0.0f;
    }
  }
}

// ---------------- MLP + heads (proj fused) ----------------
__device__ inline void ln_lrelu(float acc[8], float gj, float ej, float out[8][512],
                                float wred[8][8][2], float stat[8][2],
                                int tid, int lane, int wv, int j) {
  #pragma unroll
  for (int i = 0; i < 8; ++i) {
    float s = acc[i], ss = acc[i]*acc[i];
    for (int off = 32; off; off >>= 1) { s += __shfl_down(s, off, 64); ss += __shfl_down(ss, off, 64); }
    if (lane == 0) { wred[i][wv][0] = s; wred[i][wv][1] = ss; }
  }
  __syncthreads();
  if (tid < 8) {
    float s = 0.f, ss = 0.f;
    #pragma unroll
    for (int w = 0; w < 8; ++w) { s += wred[tid][w][0]; ss += wred[tid][w][1]; }
    float mean = s/512.0f;
    float var = ss/512.0f - mean*mean;
    stat[tid][0] = mean;
    stat[tid][1] = 1.0f/sqrtf(var + 1e-5f);
  }
  __syncthreads();
  #pragma unroll
  for (int i = 0; i < 8; ++i) {
    float v = (acc[i] - stat[i][0])*stat[i][1]*gj + ej;
    out[i][j] = (v >= 0.f) ? v : 0.1f*v;
  }
}

__global__ __launch_bounds__(512) void k_mlp(float* W, const float* gender, const float* age,
    const float* projw, const float* projb,
    const float* b0, const float* g0, const float* e0,
    const float* b1, const float* g1, const float* e1,
    const float* b2, const float* g2, const float* e2,
    const float* oqw, const float* oqb, const float* vtb, const float* nfb) {
  __shared__ float hbuf[8][256];
  __shared__ float in0[8][21];
  __shared__ float actA[8][512];
  __shared__ float actB[8][512];
  __shared__ float wred[8][8][2];
  __shared__ float stat[8][2];
  int tid = threadIdx.x; int q0 = blockIdx.x*8;
  for (int x = tid; x < 2048; x += 512) {
    int i = x >> 8, k = x & 255;
    hbuf[i][k] = W[oHS + ((size_t)(q0 + i))*256 + k];
  }
  __syncthreads();
  if (tid < 128) {
    int i = tid >> 4, zi = tid & 15;
    float a = projb[zi];
    for (int k = 0; k < 256; ++k) a = fmaf(hbuf[i][k], projw[zi*256 + k], a);
    in0[i][zi] = a;
  } else if (tid < 168) {
    int x = tid - 128; int i = x/5, d = 16 + x%5;
    int q = q0 + i; int b = q/FRM;
    float v;
    if (d == 16) v = (logf(W[oF0 + q] + 1e-5f) - 4.0f)*0.25f;
    else if (d == 17) v = W[oLOUD + q]/100.0f + 1.0f;
    else if (d == 18) v = gender[b*2];
    else if (d == 19) v = gender[b*2 + 1];
    else v = age[b];
    in0[i][d] = v;
  }
  __syncthreads();
  int j = tid, lane = tid & 63, wv = tid >> 6;
  float acc[8];
  #pragma unroll
  for (int i = 0; i < 8; ++i) acc[i] = b0[j];
  for (int d = 0; d < 21; ++d) {
    float w = W[oW0T + (size_t)d*512 + j];
    #pragma unroll
    for (int i = 0; i < 8; ++i) acc[i] = fmaf(in0[i][d], w, acc[i]);
  }
  ln_lrelu(acc, g0[j], e0[j], actA, wred, stat, tid, lane, wv, j);
  __syncthreads();
  #pragma unroll
  for (int i = 0; i < 8; ++i) acc[i] = b1[j];
  for (int k = 0; k < 512; ++k) {
    float w = W[oW1T + (size_t)k*512 + j];
    #pragma unroll
    for (int i = 0; i < 8; ++i) acc[i] = fmaf(actA[i][k], w, acc[i]);
  }
  ln_lrelu(acc, g1[j], e1[j], actB, wred, stat, tid, lane, wv, j);
  __syncthreads();
  #pragma unroll
  for (int i = 0; i < 8; ++i) acc[i] = b2[j];
  for (int k = 0; k < 512; ++k) {
    float w = W[oW2T + (size_t)k*512 + j];
    #pragma unroll
    for (int i = 0; i < 8; ++i) acc[i] = fmaf(actB[i][k], w, acc[i]);
  }
  ln_lrelu(acc, g2[j], e2[j], actA, wred, stat, tid, lane, wv, j);
  __syncthreads();
  for (int x = tid; x < 520; x += 512) {
    int i = x/65, m = x%65;
    float a = vtb[m], a2 = nfb[m];
    for (int k = 0; k < 512; ++k) {
      float h = actA[i][k];
      a  = fmaf(h, W[oVTT + (size_t)k*65 + m], a);
      a2 = fmaf(h, W[oNFT + (size_t)k*65 + m], a2);
    }
    W[oVT + (size_t)(q0+i)*65 + m] = sigm(a);
    W[oNF + (size_t)(q0+i)*65 + m] = sigm(a2);
  }
  if (tid < 8) {
    float a = oqb[0];
    for (int k = 0; k < 512; ++k) a = fmaf(actA[tid][k], oqw[k], a);
    W[oOQ + q0 + tid] = sigm(a);
  }
}

// ---------------- glottal: parallel 3-phase ----------------
__global__ __launch_bounds__(256) void k_gsum(float* W) {
  int blk = blockIdx.x; int b = blk/GCH, c = blk%GCH; int tid = threadIdx.x;
  __shared__ float ws[4];
  const float* f0r = W + oF0 + (size_t)b*FRM;
  int i0 = c*4096 + tid*16;
  float s = 0.f;
  #pragma unroll
  for (int j = 0; j < 16; ++j) {
    int i = i0 + j;
    if (i < TLEN) s += interpF(f0r, i)*(1.0f/SRF);
  }
  for (int off = 32; off; off >>= 1) s += __shfl_down(s, off, 64);
  if ((tid & 63) == 0) ws[tid >> 6] = s;
  __syncthreads();
  if (tid == 0) W[oGSUM + (size_t)b*GCH + c] = ws[0]+ws[1]+ws[2]+ws[3];
}

__global__ void k_gscan(float* W) {
  if (blockIdx.x == 0 && threadIdx.x == 0) {
    double* P = (double*)(W + oGPRE);
    for (int b = 0; b < BB; ++b) {
      double a = 0.0;
      for (int c = 0; c < GCH; ++c) {
        P[b*GCH + c] = a;
        a += (double)W[oGSUM + (size_t)b*GCH + c];
      }
    }
  }
}

__global__ __launch_bounds__(256) void k_gapply(float* W) {
  int blk = blockIdx.x; int b = blk/GCH, c = blk%GCH; int tid = threadIdx.x;
  __shared__ float wss[4];
  __shared__ float lastw[4];
  const float* f0r = W + oF0 + (size_t)b*FRM;
  const float* oqr = W + oOQ + (size_t)b*FRM;
  float* grow = W + oGLOT + (size_t)b*TLEN;
  double P = ((const double*)(W + oGPRE))[b*GCH + c];
  int i0 = c*4096 + tid*16;
  int lane = tid & 63, wv = tid >> 6;
  float v[16]; float ts = 0.f;
  #pragma unroll
  for (int j = 0; j < 16; ++j) {
    int i = i0 + j;
    float x = (i < TLEN) ? interpF(f0r, i)*(1.0f/SRF) : 0.f;
    v[j] = x; ts += x;
  }
  float sc = ts;
  #pragma unroll
  for (int off = 1; off < 64; off <<= 1) {
    float o = __shfl_up(sc, off, 64);
    if (lane >= off) sc += o;
  }
  if (lane == 63) wss[wv] = sc;
  __syncthreads();
  float wpre = 0.f;
  for (int q = 0; q < wv; ++q) wpre += wss[q];
  double ph0 = P + (double)(wpre + sc - ts);
  float run = 0.f; float gq[16];
  #pragma unroll
  for (int j = 0; j < 16; ++j) {
    int i = i0 + j;
    run += v[j];
    float ph = (float)(ph0 + (double)run);
    gq[j] = gwave(ph, interpF(oqr, min(i, TLEN-1)));
  }
  float prev = __shfl_up(gq[15], 1, 64);
  if (lane == 63) lastw[wv] = gq[15];
  __syncthreads();
  if (lane == 0) {
    if (wv > 0) prev = lastw[wv - 1];
    else if (i0 > 0) prev = gwave((float)P, interpF(oqr, i0 - 1));
    else prev = 0.f;
  }
  #pragma unroll
  for (int j = 0; j < 16; ++j) {
    int i = i0 + j;
    if (i < TLEN) {
      float gl = (j == 0) ? prev : gq[j-1];
      grow[i] = (i == 0) ? 0.f : (gq[j] - gl);
    }
  }
}

// ---------------- fused STFT->filter->ISTFT OLA (packed G+iN, 2 FFTs) ----------------
__global__ __launch_bounds__(256) void k_filtsynth(float* W) {
  int blk = blockIdx.x; int b = blk/FRM, f = blk%FRM; int tid = threadIdx.x;
  __shared__ float2 cZ[1024], cS[1024];
  __shared__ float fvt[65], fnf[65];
  const float* grow = W + oGLOT + (size_t)b*TLEN;
  const float* nrow = W + oNOISE + (size_t)b*TLEN;
  const float2* tw = (const float2*)(W + oTW);
  for (int i = tid; i < 1024; i += 256) {
    int si = mirror_idx(f*256 + i - 512);
    float wv = W[oWIN + i];
    int pos = __brev((unsigned)i) >> 22;
    cZ[pos] = make_float2(grow[si]*wv, nrow[si]*wv);
  }
  if (tid < 65) {
    fvt[tid] = W[oVT + ((size_t)b*FRM + f)*65 + tid];
    fnf[tid] = W[oNF + ((size_t)b*FRM + f)*65 + tid];
  }
  __syncthreads();
  fft2<10,1>(cZ, tw, tid, 256, false);
  for (int k = tid; k <= 512; k += 256) {
    int km = (1024 - k) & 1023;
    float2 z1 = cZ[k], z2 = cZ[km];
    float Gr = 0.5f*(z1.x + z2.x), Gi = 0.5f*(z1.y - z2.y);
    float Nr = 0.5f*(z1.y + z2.y), Ni = 0.5f*(z2.x - z1.x);
    float fv = interp65(fvt, k), fn = interp65(fnf, k);
    float Sr = Gr*fv + Nr*fn, Si = Gi*fv + Ni*fn;
    cS[__brev((unsigned)k) >> 22] = make_float2(Sr, Si);
    if (km != k) cS[__brev((unsigned)km) >> 22] = make_float2(Sr, -Si);
  }
  __syncthreads();
  fft2<10,1>(cS, tw, tid, 256, true);
  float* arow = W + oACC + (size_t)b*ACCLEN + (size_t)f*256;
  for (int i = tid; i < 1024; i += 256) {
    float xv = cS[i].x*(1.0f/1024.0f)*W[oWIN + i];
    atomicAdd(arow + i, xv);
  }
}

// ---------------- dry: pack 2 batches per complex signal ----------------
__global__ void k_dry(float* W, float* dout) {
  size_t id = (size_t)blockIdx.x*256 + threadIdx.x;
  if (id >= (size_t)4*NCONV) return;
  int t = (int)(id / NCONV);
  int n = (int)(id % NCONV);
  float dv0 = 0.f, dv1 = 0.f;
  if (n < TLEN) {
    float pos = ((float)n + 0.5f) * (626.0f/160000.0f) - 0.5f;
    pos = fminf(fmaxf(pos, 0.0f), 625.0f);
    int lo = (int)floorf(pos);
    int hi = min(lo + 1, 625);
    float wgt = pos - (float)lo;
    float wsq = W[oWSQI + 512 + n];
    #pragma unroll
    for (int q = 0; q < 2; ++q) {
      int b = 2*t + q;
      float val = W[oACC + (size_t)b*ACCLEN + 512 + n] * wsq;
      const float* lrow = W + oLOUD + (size_t)b*FRM;
      float a0 = exp10f(lrow[lo]*0.05f);
      float a1 = exp10f(lrow[hi]*0.05f);
      float dv = val*(a0*(1.0f - wgt) + a1*wgt);
      if (q == 0) dv0 = dv; else dv1 = dv;
      dout[(size_t)BB*TLEN + (size_t)b*TLEN + n] = dv;
    }
  }
  ((float2*)(W + oCONVA))[id] = make_float2(dv0, dv1);
}

// ---------------- four-step FFT (N = 512*512) ----------------
__global__ __launch_bounds__(256) void k_conv_f1(const float* in, float* out,
                                                 const float* tw, const float* twf,
                                                 const float* twc) {
  int blk = blockIdx.x; int t = blk >> 9; int bcol = blk & 511; int tid = threadIdx.x;
  __shared__ float2 cb[512];
  const float2* src = (const float2*)in + (size_t)t*NCONV;
  for (int a = tid; a < 512; a += 256) {
    int pos = __brev((unsigned)a) >> 23;
    cb[pos] = src[(size_t)a*512 + bcol];
  }
  __syncthreads();
  fft2<9,2>(cb, (const float2*)tw, tid, 256, false);
  float2* dst = (float2*)out + (size_t)t*NCONV + (size_t)bcol*512;
  for (int k1 = tid; k1 < 512; k1 += 256) {
    unsigned m = (unsigned)bcol * (unsigned)k1;   // < 262144
    float2 tc = ((const float2*)twc)[m >> 9];
    float2 tf = ((const float2*)twf)[m & 511];
    float wr = tc.x*tf.x - tc.y*tf.y;
    float wi = tc.x*tf.y + tc.y*tf.x;
    float2 v = cb[k1];
    dst[k1] = make_float2(v.x*wr - v.y*wi, v.x*wi + v.y*wr);
  }
}

__global__ __launch_bounds__(256) void k_conv_f2(const float* in, float* out, const float* tw) {
  int blk = blockIdx.x; int t = blk >> 9; int k1 = blk & 511; int tid = threadIdx.x;
  __shared__ float2 cb[512];
  const float2* src = (const float2*)in + (size_t)t*NCONV;
  for (int bb2 = tid; bb2 < 512; bb2 += 256) {
    int pos = __brev((unsigned)bb2) >> 23;
    cb[pos] = src[(size_t)bb2*512 + k1];
  }
  __syncthreads();
  fft2<9,2>(cb, (const float2*)tw, tid, 256, false);
  float2* dst = (float2*)out + (size_t)t*NCONV;
  for (int k2 = tid; k2 < 512; k2 += 256) {
    dst[(size_t)k1 + 512*(size_t)k2] = cb[k2];
  }
}

// inverse second pass fused with wet output: y[n] = conj(V)/N; b=2t from Re, b=2t+1 from -Im
__global__ __launch_bounds__(256) void k_conv_f2w(const float* in, float* dout, const float* tw) {
  int blk = blockIdx.x; int t = blk >> 9; int k1 = blk & 511; int tid = threadIdx.x;
  __shared__ float2 cb[512];
  const float2* src = (const float2*)in + (size_t)t*NCONV;
  for (int bb2 = tid; bb2 < 512; bb2 += 256) {
    int pos = __brev((unsigned)bb2) >> 23;
    cb[pos] = src[(size_t)bb2*512 + k1];
  }
  __syncthreads();
  fft2<9,2>(cb, (const float2*)tw, tid, 256, false);
  float* d0 = dout + (size_t)(2*t)*TLEN;
  float* d1 = dout + (size_t)(2*t + 1)*TLEN;
  for (int k2 = tid; k2 < 512; k2 += 256) {
    int n = k1 + 512*k2;
    if (n < TLEN) {
      float2 V = cb[k2];
      d0[n] = V.x * (1.0f/262144.0f);
      d1[n] = -V.y * (1.0f/262144.0f);
    }
  }
}

// packed spectral multiply
__global__ void k_mul(float* W) {
  constexpr size_t HALF = NCONV/2;
  size_t id = (size_t)blockIdx.x*256 + threadIdx.x;
  if (id >= (size_t)4*(HALF + 1)) return;
  int t = (int)(id / (HALF + 1));
  size_t k = id % (HALF + 1);
  size_t km = (NCONV - k) & (NCONV - 1);
  float2* A = (float2*)(W + oCONVA);
  float2 z1 = A[(size_t)t*NCONV + k];
  float2 z2 = A[(size_t)t*NCONV + km];
  float2 c  = A[(size_t)4*NCONV + k];
  float X0r = 0.5f*(z1.x + z2.x), X0i = 0.5f*(z1.y - z2.y);
  float X1r = 0.5f*(z1.y + z2.y), X1i = 0.5f*(z2.x - z1.x);
  float P0r = X0r*c.x - X0i*c.y, P0i = X0r*c.y + X0i*c.x;
  float P1r = X1r*c.x - X1i*c.y, P1i = X1r*c.y + X1i*c.x;
  A[(size_t)t*NCONV + k] = make_float2(P0r - P1i, -(P0i + P1r));
  if (km != k) {
    A[(size_t)t*NCONV + km] = make_float2(P0r + P1i, P0i - P1r);
  }
}

// ---------------- launch ----------------
extern "C" void kernel_launch(void* const* d_in, const int* in_sizes, int n_in,
                              void* d_out, int out_size, void* d_ws, size_t ws_size,
                              hipStream_t stream) {
  (void)in_sizes; (void)n_in; (void)out_size; (void)ws_size;
  const float* audio  = (const float*)d_in[0];
  const float* gender = (const float*)d_in[1];
  const float* age    = (const float*)d_in[2];
  const float* wih    = (const float*)d_in[3];
  const float* whh    = (const float*)d_in[4];
  const float* bih    = (const float*)d_in[5];
  const float* bhh    = (const float*)d_in[6];
  const float* projw  = (const float*)d_in[7];
  const float* projb  = (const float*)d_in[8];
  const float* w0     = (const float*)d_in[9];
  const float* b0     = (const float*)d_in[10];
  const float* g0     = (const float*)d_in[11];
  const float* e0     = (const float*)d_in[12];
  const float* w1     = (const float*)d_in[13];
  const float* b1     = (const float*)d_in[14];
  const float* g1     = (const float*)d_in[15];
  const float* e1     = (const float*)d_in[16];
  const float* w2     = (const float*)d_in[17];
  const float* b2     = (const float*)d_in[18];
  const float* g2     = (const float*)d_in[19];
  const float* e2     = (const float*)d_in[20];
  const float* oqw    = (const float*)d_in[21];
  const float* oqb    = (const float*)d_in[22];
  const float* vtw    = (const float*)d_in[23];
  const float* vtb    = (const float*)d_in[24];
  const float* nfw    = (const float*)d_in[25];
  const float* nfb    = (const float*)d_in[26];
  const float* ir     = (const float*)d_in[27];
  float* W = (float*)d_ws;
  float* dout = (float*)d_out;

  k_init<<<(int)((INIT_TOTAL + 255)/256), 256, 0, stream>>>(W, wih, w0, w1, w2, vtw, nfw, ir);
  k_stft_mel<<<NFRM, 256, 0, stream>>>(audio, W);
  k_melnorm<<<3, 256, 0, stream>>>(W);
  k_xp<<<(int)(((size_t)NFRM*768 + 255)/256), 256, 0, stream>>>(W, bih);
  k_mega<<<MEGA_BLOCKS, 512, 0, stream>>>(W, audio, whh, bhh);
  k_mlp<<<NFRM/8, 512, 0, stream>>>(W, gender, age, projw, projb,
                                    b0, g0, e0, b1, g1, e1, b2, g2, e2, oqw, oqb, vtb, nfb);
  k_gsum<<<BB*GCH, 256, 0, stream>>>(W);
  k_gscan<<<1, 64, 0, stream>>>(W);
  k_gapply<<<BB*GCH, 256, 0, stream>>>(W);
  k_filtsynth<<<NFRM, 256, 0, stream>>>(W);
  k_dry<<<(int)(((size_t)4*NCONV + 255)/256), 256, 0, stream>>>(W, dout);
  k_conv_f1<<<5*512, 256, 0, stream>>>(W + oCONVA, W + oCONVB, W + oTW, W + oTWF, W + oTWC);
  k_conv_f2<<<5*512, 256, 0, stream>>>(W + oCONVB, W + oCONVA, W + oTW);
  k_mul<<<(int)(((size_t)4*(NCONV/2 + 1) + 255)/256), 256, 0, stream>>>(W);
  k_conv_f1<<<4*512, 256, 0, stream>>>(W + oCONVA, W + oCONVB, W + oTW, W + oTWF, W + oTWC);
  k_conv_f2w<<<4*512, 256, 0, stream>>>(W + oCONVB, dout, W + oTW);
}